// Round 6
// baseline (159.809 us; speedup 1.0000x reference)
//
#include <hip/hip_runtime.h>
#include <math.h>

#define N_    64
#define T_    1024
#define E_    512
#define A_    256
#define S_    64
#define O_    80
#define HID_  1024
#define WMAX  19
#define SLOT  ((size_t)64*4096)

typedef __attribute__((ext_vector_type(8))) short bh8;
typedef __attribute__((ext_vector_type(4))) float fx4;

__device__ __forceinline__ float sigmoidf_(float x){ return 1.f/(1.f+expf(-x)); }
__device__ __forceinline__ unsigned pk2_(float a, float b){
  unsigned ua = __float_as_uint(a), ub = __float_as_uint(b);
  ua = (ua + 0x7fffu + ((ua>>16)&1u)) >> 16;
  ub = (ub + 0x7fffu + ((ub>>16)&1u)) >> 16;
  return ua | (ub<<16);
}

// =================== generic tiled GEMM body (optional enc-window gather) ===================
struct GemmS { float x_s[2][64][68]; float w_s[2][64][68]; };

__device__ void gemm_body(const float* __restrict__ X, int xStride,
                          const float* __restrict__ X2, int Ksplit,
                          const float* __restrict__ W,
                          float* __restrict__ partial,
                          int K, int C, int nMt, int nCt, int KS,
                          int bid, int t, GemmS& sm,
                          const int* __restrict__ gLo){
  int mt = bid % nMt; int rest = bid / nMt;
  int ct = rest % nCt; int ks = rest / nCt;
  int m0 = mt << 6; int c0 = ct << 6;
  int M = nMt << 6;
  int nch = (K + 63) >> 6;
  int ch0 = (ks*nch)/KS, ch1 = ((ks+1)*nch)/KS;
  int bi = t >> 4, j = t & 15;
  float4 px[4], pw[4];

  size_t xoff[4];
  #pragma unroll
  for (int i=0;i<4;i++){
    int lin = i*256+t; int bl = lin>>4;
    int row = m0 + bl;
    if (gLo){
      int n = row/19; int r = row - n*19;
      int idx = gLo[n] + r; if (idx > 1023) idx = 1023;
      xoff[i] = ((size_t)((n<<10)+idx))<<9;   // *512 floats
    } else {
      xoff[i] = (size_t)row * xStride;
    }
  }

  auto ld = [&](int ch){
    int k0 = ch << 6;
    #pragma unroll
    for (int i=0;i<4;i++){
      int lin = i*256+t; int bl = lin>>4, kq = lin&15;
      int k = k0 + (kq<<2);
      float4 v = make_float4(0.f,0.f,0.f,0.f);
      if (k < K){
        if (X2 != nullptr && k >= Ksplit){
          v = *(const float4*)&X2[(size_t)bl*1024 + (k - Ksplit)];
        } else {
          v = *(const float4*)&X[xoff[i] + k];
        }
      }
      px[i] = v;
    }
    #pragma unroll
    for (int i=0;i<4;i++){
      int lin = i*256+t; int kk = lin>>4, cq = lin&15;
      int k = k0 + kk, c = c0 + (cq<<2);
      float4 v = make_float4(0.f,0.f,0.f,0.f);
      if (k < K && c < C) v = *(const float4*)&W[(size_t)k*C + c];
      pw[i] = v;
    }
  };
  auto st = [&](int buf){
    #pragma unroll
    for (int i=0;i<4;i++){
      int lin = i*256+t; int bl = lin>>4, kq = lin&15;
      *(float4*)&sm.x_s[buf][bl][kq<<2] = px[i];
    }
    #pragma unroll
    for (int i=0;i<4;i++){
      int lin = i*256+t; int kk = lin>>4, cq = lin&15;
      *(float4*)&sm.w_s[buf][kk][cq<<2] = pw[i];
    }
  };

  float4 acc[4];
  #pragma unroll
  for (int m=0;m<4;m++) acc[m] = make_float4(0.f,0.f,0.f,0.f);

  ld(ch0); st(0); __syncthreads();
  int buf = 0;
  for (int ch = ch0; ch < ch1; ++ch){
    if (ch+1 < ch1) ld(ch+1);
    #pragma unroll
    for (int kq=0;kq<16;kq++){
      float4 xv[4], wv[4];
      #pragma unroll
      for (int bb=0;bb<4;bb++) xv[bb] = *(const float4*)&sm.x_s[buf][(bi<<2)+bb][kq<<2];
      #pragma unroll
      for (int kk=0;kk<4;kk++) wv[kk] = *(const float4*)&sm.w_s[buf][(kq<<2)+kk][j<<2];
      #pragma unroll
      for (int bb=0;bb<4;bb++){
        float s0=xv[bb].x, s1=xv[bb].y, s2=xv[bb].z, s3=xv[bb].w;
        acc[bb].x += s0*wv[0].x + s1*wv[1].x + s2*wv[2].x + s3*wv[3].x;
        acc[bb].y += s0*wv[0].y + s1*wv[1].y + s2*wv[2].y + s3*wv[3].y;
        acc[bb].z += s0*wv[0].z + s1*wv[1].z + s2*wv[2].z + s3*wv[3].z;
        acc[bb].w += s0*wv[0].w + s1*wv[1].w + s2*wv[2].w + s3*wv[3].w;
      }
    }
    if (ch+1 < ch1){ st(buf^1); __syncthreads(); }
    buf ^= 1;
  }
  int c = c0 + (j<<2);
  if (c < C){
    #pragma unroll
    for (int bb=0;bb<4;bb++){
      int bl = (bi<<2)+bb;
      *(float4*)&partial[(size_t)(ks*M + m0 + bl)*C + c] = acc[bb];
    }
  }
}

// =================== LSTM gates GEMM body (bf16 MFMA), single-source ===================
struct LstmS { uint4 WlA[2][512]; uint4 XlA[2][512]; float outb[64][68]; };

__device__ void lstm_store(int t, int wid, int lane, fx4* acc, int ks,
                           float* __restrict__ partial, LstmS& sm){
  __syncthreads();
  #pragma unroll
  for (int nt=0;nt<4;nt++){
    #pragma unroll
    for (int q=0;q<4;q++)
      sm.outb[(nt<<4)+(lane&15)][(wid<<4)+((lane>>4)<<2)+q] = acc[nt][q];
  }
  __syncthreads();
  #pragma unroll
  for (int i=0;i<4;i++){
    int idx = i*256+t; int b = idx>>4; int r4 = (idx&15)<<2;
    float4 o = *(const float4*)&sm.outb[b][r4];
    *(float4*)&partial[(size_t)((ks<<6)+b)*4096 + (blockIdx.x&0) + r4] = o; // placeholder (unused)
  }
}

__device__ void lstm_body(const float* __restrict__ x, int xStride,
                          const float* __restrict__ W, int wStride,
                          float* __restrict__ partial, int KS, int Klen,
                          int bid, int t, LstmS& sm){
  int Mblk = bid & 63;
  int ks = bid >> 6;
  int r0 = Mblk << 6;
  int nch = Klen >> 6;
  int ch0 = (ks*nch)/KS, ch1 = ((ks+1)*nch)/KS;
  int wid = t >> 6, lane = t & 63;

  float4 rw[2][2], rx[2][2];
  auto ld = [&](int ch){
    int k0 = ch << 6;
    #pragma unroll
    for (int u=0;u<2;u++){
      int g = t + (u<<8); int row = g>>3; int k = k0 + ((g&7)<<3);
      const float* sw = &W[(size_t)(r0+row)*wStride + k];
      const float* sx = &x[(size_t)row*xStride + k];
      rw[u][0] = *(const float4*)sw; rw[u][1] = *(const float4*)(sw+4);
      rx[u][0] = *(const float4*)sx; rx[u][1] = *(const float4*)(sx+4);
    }
  };
  auto cvst = [&](int buf){
    #pragma unroll
    for (int u=0;u<2;u++){
      int g = t + (u<<8); int row = g>>3, gk = g&7;
      int byte = row*128 + ((gk ^ (row&7))<<4);
      uint4 vw, vx;
      vw.x = pk2_(rw[u][0].x, rw[u][0].y); vw.y = pk2_(rw[u][0].z, rw[u][0].w);
      vw.z = pk2_(rw[u][1].x, rw[u][1].y); vw.w = pk2_(rw[u][1].z, rw[u][1].w);
      vx.x = pk2_(rx[u][0].x, rx[u][0].y); vx.y = pk2_(rx[u][0].z, rx[u][0].w);
      vx.z = pk2_(rx[u][1].x, rx[u][1].y); vx.w = pk2_(rx[u][1].z, rx[u][1].w);
      *(uint4*)((char*)&sm.WlA[buf][0] + byte) = vw;
      *(uint4*)((char*)&sm.XlA[buf][0] + byte) = vx;
    }
  };

  fx4 acc[4];
  #pragma unroll
  for (int nt=0;nt<4;nt++) acc[nt] = (fx4){0.f,0.f,0.f,0.f};

  ld(ch0); cvst(0); __syncthreads();
  int buf = 0;
  for (int ch = ch0; ch < ch1; ++ch){
    if (ch+1 < ch1) ld(ch+1);
    int rowA = (wid<<4) + (lane&15);
    #pragma unroll
    for (int s=0;s<2;s++){
      int gA = (s<<2) + (lane>>4);
      bh8 a = *(bh8*)((char*)&sm.WlA[buf][0] + rowA*128 + ((gA ^ (rowA&7))<<4));
      #pragma unroll
      for (int nt=0;nt<4;nt++){
        int rowB = (nt<<4) + (lane&15);
        bh8 bf = *(bh8*)((char*)&sm.XlA[buf][0] + rowB*128 + ((gA ^ (rowB&7))<<4));
        acc[nt] = __builtin_amdgcn_mfma_f32_16x16x32_bf16(a, bf, acc[nt], 0, 0, 0);
      }
    }
    if (ch+1 < ch1){ cvst(buf^1); __syncthreads(); }
    buf ^= 1;
  }
  __syncthreads();
  #pragma unroll
  for (int nt=0;nt<4;nt++){
    #pragma unroll
    for (int q=0;q<4;q++)
      sm.outb[(nt<<4)+(lane&15)][(wid<<4)+((lane>>4)<<2)+q] = acc[nt][q];
  }
  __syncthreads();
  #pragma unroll
  for (int i=0;i<4;i++){
    int idx = i*256+t; int b = idx>>4; int r4 = (idx&15)<<2;
    float4 o = *(const float4*)&sm.outb[b][r4];
    *(float4*)&partial[(size_t)((ks<<6)+b)*4096 + r0 + r4] = o;
  }
}

// =================== Wih0 rider part: k in [0,256) via pre2-combine + [768,832) spkr ===================
__device__ void lstmA_body(const float* __restrict__ pP2,
                           const float* __restrict__ b2,
                           const float* __restrict__ spkr,
                           const float* __restrict__ Wih0,
                           float* __restrict__ partial,
                           int bid, int t, LstmS& sm){
  int Mblk = bid & 63;
  int r0 = Mblk << 6;
  int wid = t >> 6, lane = t & 63;

  float4 rw[2][2], rx[2][2];
  auto ld = [&](int ch){
    int kw0 = (ch < 4) ? (ch<<6) : 768;
    #pragma unroll
    for (int u=0;u<2;u++){
      int g = t + (u<<8); int row = g>>3; int kl = (g&7)<<3;
      int kw = kw0 + kl;
      const float* sw = &Wih0[(size_t)(r0+row)*832 + kw];
      rw[u][0] = *(const float4*)sw; rw[u][1] = *(const float4*)(sw+4);
      if (ch < 4){
        float4 a0 = *(const float4*)&b2[kw];
        float4 a1 = *(const float4*)&b2[kw+4];
        #pragma unroll
        for (int p=0;p<4;p++){
          const float4 u0 = *(const float4*)&pP2[(size_t)((p<<6)+row)*256 + kw];
          const float4 u1 = *(const float4*)&pP2[(size_t)((p<<6)+row)*256 + kw + 4];
          a0.x+=u0.x; a0.y+=u0.y; a0.z+=u0.z; a0.w+=u0.w;
          a1.x+=u1.x; a1.y+=u1.y; a1.z+=u1.z; a1.w+=u1.w;
        }
        a0.x=fmaxf(a0.x,0.f); a0.y=fmaxf(a0.y,0.f); a0.z=fmaxf(a0.z,0.f); a0.w=fmaxf(a0.w,0.f);
        a1.x=fmaxf(a1.x,0.f); a1.y=fmaxf(a1.y,0.f); a1.z=fmaxf(a1.z,0.f); a1.w=fmaxf(a1.w,0.f);
        rx[u][0] = a0; rx[u][1] = a1;
      } else {
        rx[u][0] = *(const float4*)&spkr[(row<<6) + kl];
        rx[u][1] = *(const float4*)&spkr[(row<<6) + kl + 4];
      }
    }
  };
  auto cvst = [&](int buf){
    #pragma unroll
    for (int u=0;u<2;u++){
      int g = t + (u<<8); int row = g>>3, gk = g&7;
      int byte = row*128 + ((gk ^ (row&7))<<4);
      uint4 vw, vx;
      vw.x = pk2_(rw[u][0].x, rw[u][0].y); vw.y = pk2_(rw[u][0].z, rw[u][0].w);
      vw.z = pk2_(rw[u][1].x, rw[u][1].y); vw.w = pk2_(rw[u][1].z, rw[u][1].w);
      vx.x = pk2_(rx[u][0].x, rx[u][0].y); vx.y = pk2_(rx[u][0].z, rx[u][0].w);
      vx.z = pk2_(rx[u][1].x, rx[u][1].y); vx.w = pk2_(rx[u][1].z, rx[u][1].w);
      *(uint4*)((char*)&sm.WlA[buf][0] + byte) = vw;
      *(uint4*)((char*)&sm.XlA[buf][0] + byte) = vx;
    }
  };

  fx4 acc[4];
  #pragma unroll
  for (int nt=0;nt<4;nt++) acc[nt] = (fx4){0.f,0.f,0.f,0.f};

  ld(0); cvst(0); __syncthreads();
  int buf = 0;
  for (int ch = 0; ch < 5; ++ch){
    if (ch+1 < 5) ld(ch+1);
    int rowA = (wid<<4) + (lane&15);
    #pragma unroll
    for (int s=0;s<2;s++){
      int gA = (s<<2) + (lane>>4);
      bh8 a = *(bh8*)((char*)&sm.WlA[buf][0] + rowA*128 + ((gA ^ (rowA&7))<<4));
      #pragma unroll
      for (int nt=0;nt<4;nt++){
        int rowB = (nt<<4) + (lane&15);
        bh8 bf = *(bh8*)((char*)&sm.XlA[buf][0] + rowB*128 + ((gA ^ (rowB&7))<<4));
        acc[nt] = __builtin_amdgcn_mfma_f32_16x16x32_bf16(a, bf, acc[nt], 0, 0, 0);
      }
    }
    if (ch+1 < 5){ cvst(buf^1); __syncthreads(); }
    buf ^= 1;
  }
  __syncthreads();
  #pragma unroll
  for (int nt=0;nt<4;nt++){
    #pragma unroll
    for (int q=0;q<4;q++)
      sm.outb[(nt<<4)+(lane&15)][(wid<<4)+((lane>>4)<<2)+q] = acc[nt][q];
  }
  __syncthreads();
  #pragma unroll
  for (int i=0;i<4;i++){
    int idx = i*256+t; int b = idx>>4; int r4 = (idx&15)<<2;
    float4 o = *(const float4*)&sm.outb[b][r4];
    *(float4*)&partial[(size_t)b*4096 + r0 + r4] = o;
  }
}

// =================== K1: argmax+paw | Wdec GEMM | pre1 GEMM | Whh1 rider ===================
__global__ __launch_bounds__(256) void k_front3(
    const float* __restrict__ prev, const int* __restrict__ lens,
    const float* __restrict__ indec, const float* __restrict__ spkr,
    const float* __restrict__ W1, const float* __restrict__ b1,
    const float* __restrict__ hid, const float* __restrict__ Wdec,
    const float* __restrict__ Whh1,
    int* __restrict__ lo_out, int* __restrict__ wl_out,
    float* __restrict__ paw, float* __restrict__ pA,
    float* __restrict__ p1x, float* __restrict__ pL1,
    int* __restrict__ ctr){
  __shared__ __align__(16) char smem_raw[sizeof(GemmS)];
  int bid = blockIdx.x, t = threadIdx.x;
  if (bid == 0 && t == 0) *ctr = 0;

  if (bid < 64){
    int n = bid;
    float* sv = (float*)smem_raw;
    int*   si = (int*)(smem_raw + 1024);
    int*   meta = (int*)(smem_raw + 2048);
    const float* p = prev + n*T_;
    float bv = -1e30f; int bi2 = 0x7fffffff;
    #pragma unroll
    for (int i=0;i<4;i++){
      int idx = t + (i<<8);
      float v = p[idx];
      if (v > bv || (v == bv && idx < bi2)){ bv = v; bi2 = idx; }
    }
    sv[t]=bv; si[t]=bi2; __syncthreads();
    for (int s=128; s>0; s>>=1){
      if (t < s){
        float v2 = sv[t+s]; int i2 = si[t+s];
        if (v2 > sv[t] || (v2 == sv[t] && i2 < si[t])){ sv[t]=v2; si[t]=i2; }
      }
      __syncthreads();
    }
    if (t==0){
      int len = lens[n]; len = len < 1 ? 1 : (len > T_ ? T_ : len);
      int idx = si[0];
      int lo = idx - 9; lo = lo < 0 ? 0 : lo; if (lo > len-1) lo = len-1;
      int hi = idx + 9; hi = hi < 0 ? 0 : hi; if (hi > len-1) hi = len-1;
      meta[0] = lo;
      lo_out[n] = lo; wl_out[n] = hi - lo + 1;
    }
    __syncthreads();
    int lo = meta[0];
    if (t < 49){
      int tt = lo - 15 + t;
      paw[n*49 + t] = (tt >= 0 && tt < T_) ? prev[(n<<10)+tt] : 0.f;
    }

  } else if (bid < 96){
    gemm_body(hid, 1024, hid + 64*1024, 1024, Wdec,
              pA, 2048, 256, 1, 4, 8, bid - 64, t, *(GemmS*)smem_raw, nullptr);

  } else if (bid < 104){
    // pre1 GEMM (8 blocks)
    int d = bid - 96;
    float* xs = (float*)smem_raw;
    #pragma unroll
    for (int i=0;i<9;i++){
      int q = i*256 + t;
      if (q < 2304){
        int b = q/36; int k4 = (q - b*36) << 2;
        float4 v;
        if (k4 < O_) v = *(const float4*)&indec[b*O_ + k4];
        else         v = *(const float4*)&spkr[(b<<6) + (k4-O_)];
        *(float4*)&xs[b*144 + k4] = v;
      }
    }
    __syncthreads();
    int bi = t >> 4, j = t & 15;
    int c0 = (d<<6) + (j<<2);
    float4 acc[4];
    #pragma unroll
    for (int rr=0;rr<4;rr++) acc[rr] = make_float4(0.f,0.f,0.f,0.f);
    #pragma unroll 4
    for (int k=0;k<144;k++){
      float4 wv = *(const float4*)&W1[(size_t)k*512 + c0];
      #pragma unroll
      for (int rr=0;rr<4;rr++){
        float xv = xs[((bi<<2)+rr)*144 + k];
        acc[rr].x += xv*wv.x; acc[rr].y += xv*wv.y; acc[rr].z += xv*wv.z; acc[rr].w += xv*wv.w;
      }
    }
    float4 bv = *(const float4*)&b1[c0];
    #pragma unroll
    for (int rr=0;rr<4;rr++){
      float4 o;
      o.x = fmaxf(acc[rr].x + bv.x, 0.f);
      o.y = fmaxf(acc[rr].y + bv.y, 0.f);
      o.z = fmaxf(acc[rr].z + bv.z, 0.f);
      o.w = fmaxf(acc[rr].w + bv.w, 0.f);
      *(float4*)&p1x[(size_t)((bi<<2)+rr)*512 + c0] = o;
    }

  } else {
    // Whh1 * hid1 rider (128 blocks, KS=2 -> pL1 slots 0-1)
    lstm_body(hid + 64*1024, 1024, Whh1, 1024,
              pL1, 2, 1024, bid - 104, t, *(LstmS*)smem_raw);
  }
}

// =================== K2: enc GEMM (gathered) | pre2 GEMM | Whh0 rider ===================
__global__ __launch_bounds__(256) void k_gemmB(const float* __restrict__ enc,
                                               const int* __restrict__ lo_w,
                                               const float* __restrict__ Wenc,
                                               float* __restrict__ pE,
                                               const float* __restrict__ p1x,
                                               const float* __restrict__ W2,
                                               float* __restrict__ pP2,
                                               const float* __restrict__ hid,
                                               const float* __restrict__ Whh0,
                                               float* __restrict__ pL0){
  __shared__ __align__(16) char smem_raw[sizeof(GemmS)];
  int bid = blockIdx.x, t = threadIdx.x;
  if (bid < 304)
    gemm_body(enc, 512, nullptr, 0, Wenc, pE, 512, 256, 19, 4, 4,
              bid, t, *(GemmS*)smem_raw, lo_w);
  else if (bid < 320)
    gemm_body(p1x, 512, nullptr, 0, W2, pP2, 512, 256, 1, 4, 4,
              bid - 304, t, *(GemmS*)smem_raw, nullptr);
  else
    lstm_body(hid, 1024, Whh0, 1024,
              pL0, 2, 1024, bid - 320, t, *(LstmS*)smem_raw);
}

// =================== K3: attention | Wih0 rider A ===================
struct AttS {
  float cw[256*31];
  float cv[WMAX*256];
  float attb[256];
  float pa[52];
  float wlog[WMAX];
  float w[WMAX+1];
};

__global__ __launch_bounds__(256) void k_att3(const float* __restrict__ pE,
    const float* __restrict__ pA, const float* __restrict__ benc,
    const float* __restrict__ convw, const float* __restrict__ Wproj,
    const float* __restrict__ spkr, const float* __restrict__ Wspkr,
    const float* __restrict__ paw, const int* __restrict__ wl_w,
    const int* __restrict__ lo_w, const float* __restrict__ enc,
    const float* __restrict__ pP2, const float* __restrict__ b2,
    const float* __restrict__ Wih0,
    float* __restrict__ ctxb, float* __restrict__ pL0A){
  __shared__ __align__(16) char smem_raw[(sizeof(AttS) > sizeof(LstmS)) ? sizeof(AttS) : sizeof(LstmS)];
  int t = threadIdx.x;

  if (blockIdx.x >= 64){
    lstmA_body(pP2, b2, spkr, Wih0, pL0A, blockIdx.x - 64, t, *(LstmS*)smem_raw);
    return;
  }

  AttS& s = *(AttS*)smem_raw;
  int n = blockIdx.x;
  int wl = wl_w[n];
  int lo = lo_w[n];
  for (int lin = t; lin < 256*31; lin += 256) s.cw[lin] = convw[lin];
  if (t < 49) s.pa[t] = paw[n*49 + t];
  {
    float v = 0.f;
    #pragma unroll
    for (int p=0;p<8;p++) v += pA[(size_t)((p<<6)+n)*A_ + t];
    float sd = 0.f;
    #pragma unroll 16
    for (int si=0;si<S_;si++) sd += spkr[(n<<6)+si]*Wspkr[(si<<8)+t];
    s.attb[t] = v + sd/(1.f+fabsf(sd));
  }
  __syncthreads();
  for (int r=0; r<wl; ++r){
    float cv = 0.f;
    #pragma unroll
    for (int k=0;k<31;k++) cv += s.cw[t*31+k]*s.pa[r+k];
    s.cv[(r<<8)+t] = cv;
  }
  __syncthreads();
  int wid = t>>6, lane = t&63, a0 = lane<<2;
  float4 be4 = *(const float4*)&benc[a0];
  float4 wp4 = *(const float4*)&Wproj[a0];
  float4 ab4 = *(const float4*)&s.attb[a0];
  for (int r = wid; r < wl; r += 4){
    float4 sv = make_float4(0.f,0.f,0.f,0.f);
    #pragma unroll
    for (int ks=0;ks<4;ks++){
      const float4 u = *(const float4*)&pE[(size_t)(ks*1216 + n*WMAX + r)*A_ + a0];
      sv.x+=u.x; sv.y+=u.y; sv.z+=u.z; sv.w+=u.w;
    }
    sv.x += be4.x; sv.y += be4.y; sv.z += be4.z; sv.w += be4.w;
    const float4 cv4 = *(const float4*)&s.cv[(r<<8)+a0];
    float e0 = sv.x/(1.f+fabsf(sv.x)) + ab4.x + cv4.x;
    float e1 = sv.y/(1.f+fabsf(sv.y)) + ab4.y + cv4.y;
    float e2 = sv.z/(1.f+fabsf(sv.z)) + ab4.z + cv4.z;
    float e3 = sv.w/(1.f+fabsf(sv.w)) + ab4.w + cv4.w;
    float vv = tanhf(e0)*wp4.x + tanhf(e1)*wp4.y + tanhf(e2)*wp4.z + tanhf(e3)*wp4.w;
    #pragma unroll
    for (int off=32; off; off >>= 1) vv += __shfl_xor(vv, off, 64);
    if (lane == 0) s.wlog[r] = vv;
  }
  __syncthreads();
  if (t < 32){
    float l = (t < wl) ? s.wlog[t] : -1e30f;
    float mx = l;
    #pragma unroll
    for (int off=16; off; off >>= 1) mx = fmaxf(mx, __shfl_xor(mx, off, 32));
    float ex = (t < wl) ? expf(l - mx) : 0.f;
    float sm = ex;
    #pragma unroll
    for (int off=16; off; off >>= 1) sm += __shfl_xor(sm, off, 32);
    if (t < wl) s.w[t] = ex / sm;
  }
  __syncthreads();
  if (t < 128){
    float4 a = make_float4(0.f,0.f,0.f,0.f);
    for (int r=0; r<wl; ++r){
      float wv = s.w[r];
      const float4 ev = *(const float4*)&enc[(size_t)((n<<10)+lo+r)*E_ + (t<<2)];
      a.x += wv*ev.x; a.y += wv*ev.y; a.z += wv*ev.z; a.w += wv*ev.w;
    }
    *(float4*)&ctxb[(n<<10) + (t<<2)] = a;
  }
}

// =================== K4: Wih0 ctx part (k in [256,768)) ===================
__global__ __launch_bounds__(256) void k_lstmI(const float* __restrict__ x, int xStride,
                                               const float* __restrict__ W, int wStride,
                                               float* __restrict__ partial,
                                               int KS, int Klen){
  __shared__ LstmS sm;
  lstm_body(x, xStride, W, wStride, partial, KS, Klen,
            blockIdx.x, threadIdx.x, sm);
}

// =================== LSTM combine: gates -> h ===================
__global__ __launch_bounds__(256) void k_comb(const float* __restrict__ pL, int NS,
                                              const float* __restrict__ bih,
                                              const float* __restrict__ bhh,
                                              const float* __restrict__ cprev,
                                              float* __restrict__ dst){
  int bid = blockIdx.x, t = threadIdx.x;
  int b = bid >> 2; int u = ((bid & 3) << 8) + t;
  float g[4];
  #pragma unroll
  for (int gi=0; gi<4; ++gi){
    int col = (gi<<10) + u;
    float s = bih[col] + bhh[col];
    for (int q=0; q<NS; ++q) s += pL[(size_t)((q<<6)+b)*4096 + col];
    g[gi] = s;
  }
  float c = cprev[(b<<10)+u];
  float cn = sigmoidf_(g[1])*c + sigmoidf_(g[0])*tanhf(g[2]);
  dst[(b<<10)+u] = sigmoidf_(g[3])*tanhf(cn);
}

// =================== K8: out GEMM + last-block final combine ===================
__global__ __launch_bounds__(256) void k_out(const float* __restrict__ h2b,
                                             const float* __restrict__ ctxb,
                                             const float* __restrict__ Wout,
                                             float* __restrict__ pO,
                                             const float* __restrict__ bout,
                                             float* __restrict__ out,
                                             int* __restrict__ ctr){
  __shared__ GemmS sm;
  int t = threadIdx.x;
  gemm_body(h2b, 1024, ctxb, 1024, Wout, pO, 1536, 160, 1, 3, 8,
            blockIdx.x, t, sm, nullptr);
  __threadfence();
  __shared__ int isLast;
  if (t == 0){
    int old = atomicAdd(ctr, 1);
    isLast = (old == 23) ? 1 : 0;
  }
  __syncthreads();
  if (isLast){
    __threadfence();
    for (int i = t; i < 10240; i += 256){
      int b = i/160; int c = i - b*160;
      float s = bout[c];
      #pragma unroll
      for (int ks=0; ks<8; ++ks) s += pO[(size_t)((ks<<6)+b)*160 + c];
      out[i] = s;
    }
  }
}

extern "C" void kernel_launch(void* const* d_in, const int* in_sizes, int n_in,
                              void* d_out, int out_size, void* d_ws, size_t ws_size,
                              hipStream_t stream){
  const float* enc   = (const float*)d_in[0];
  const float* indec = (const float*)d_in[1];
  const float* spkr  = (const float*)d_in[2];
  const float* prev  = (const float*)d_in[3];
  const float* hid   = (const float*)d_in[4];
  const float* cell  = (const float*)d_in[5];
  const int*   lens  = (const int*)d_in[6];
  const float* Wenc  = (const float*)d_in[7];
  const float* benc  = (const float*)d_in[8];
  const float* Wspkr = (const float*)d_in[9];
  const float* convw = (const float*)d_in[10];
  const float* Wdec  = (const float*)d_in[11];
  const float* Wproj = (const float*)d_in[12];
  /* d_in[13] = b_proj: uniform shift, cancels in normalized attention weights */
  const float* Wpre1 = (const float*)d_in[14];
  const float* bpre1 = (const float*)d_in[15];
  const float* Wpre2 = (const float*)d_in[16];
  const float* bpre2 = (const float*)d_in[17];
  const float* Wih0  = (const float*)d_in[18];
  const float* Whh0  = (const float*)d_in[19];
  const float* bih0  = (const float*)d_in[20];
  const float* bhh0  = (const float*)d_in[21];
  const float* Wih1  = (const float*)d_in[22];
  const float* Whh1  = (const float*)d_in[23];
  const float* bih1  = (const float*)d_in[24];
  const float* bhh1  = (const float*)d_in[25];
  const float* Wout  = (const float*)d_in[26];
  const float* bout  = (const float*)d_in[27];
  (void)in_sizes; (void)n_in; (void)out_size; (void)ws_size;

  float* ws = (float*)d_ws;
  size_t off = 0;
  auto alloc = [&](size_t nf){ float* p = ws + off; off += nf; return p; };
  float* pA     = alloc((size_t)8*64*256);
  float* p1x    = alloc((size_t)64*512);
  float* pP2    = alloc((size_t)4*64*256);
  float* ctxb   = alloc((size_t)64*1024);
  float* h1     = alloc((size_t)64*1024);
  float* h2b    = alloc((size_t)64*1024);
  float* pO     = alloc((size_t)8*64*160);
  float* paw    = alloc(64*49 + 15);
  int*   lo_w   = (int*)alloc(64);
  int*   wl_w   = (int*)alloc(64);
  int*   ctr    = (int*)alloc(16);
  float* pE     = alloc((size_t)4*1216*256);
  float* pL0    = alloc(5*SLOT);   // 0-1: Whh0 (KS=2), 2: Wih0 riderA, 3-4: Wih0 ctx (KS=2)
  float* pL1    = alloc(6*SLOT);   // 0-1: Whh1 (KS=2), 2-5: Wih1 (KS=4)
  float* out    = (float*)d_out;

  // K1: front (0-63) | Wdec (64-95) | pre1 (96-103) | Whh1*hid1 (104-231)
  k_front3<<<232,256,0,stream>>>(prev, lens, indec, spkr,
                                 Wpre1, bpre1, hid, Wdec, Whh1,
                                 lo_w, wl_w, paw, pA, p1x, pL1, ctr);
  // K2: enc GEMM gathered (0-303) | pre2 (304-319) | Whh0*hid0 (320-447)
  k_gemmB<<<448,256,0,stream>>>(enc, lo_w, Wenc, pE, p1x, Wpre2, pP2,
                                hid, Whh0, pL0);
  // K3: attention (0-63) | Wih0 rider A (64-127) -> pL0 slot 2
  k_att3<<<128,256,0,stream>>>(pE, pA, benc, convw, Wproj, spkr, Wspkr,
                               paw, wl_w, lo_w, enc, pP2, bpre2, Wih0,
                               ctxb, pL0 + 2*SLOT);
  // K4: Wih0 ctx part, W cols [256,768), x = ctxb -> pL0 slots 3-4
  k_lstmI<<<128,256,0,stream>>>(ctxb, 1024, Wih0 + 256, 832,
                                pL0 + 3*SLOT, 2, 512);
  // K5: combine layer 0 -> h1 (5 slots)
  k_comb<<<256,256,0,stream>>>(pL0, 5, bih0, bhh0, cell, h1);
  // K6: Wih1 * h1 -> pL1 slots 2-5
  k_lstmI<<<256,256,0,stream>>>(h1, 1024, Wih1, 1024,
                                pL1 + 2*SLOT, 4, 1024);
  // K7: combine layer 1 -> h2b (6 slots)
  k_comb<<<256,256,0,stream>>>(pL1, 6, bih1, bhh1, cell + 64*1024, h2b);
  // K8: out GEMM + last-block final combine
  k_out<<<24,256,0,stream>>>(h2b, ctxb, Wout, pO, bout, out, ctr);
}

// Round 7
// 153.603 us; speedup vs baseline: 1.0404x; 1.0404x over previous
//
#include <hip/hip_runtime.h>
#include <math.h>

#define N_    64
#define T_    1024
#define E_    512
#define A_    256
#define S_    64
#define O_    80
#define HID_  1024
#define WMAX  19
#define SLOT  ((size_t)64*4096)

typedef __attribute__((ext_vector_type(8))) short bh8;
typedef __attribute__((ext_vector_type(4))) float fx4;

__device__ __forceinline__ float sigmoidf_(float x){ return 1.f/(1.f+expf(-x)); }
__device__ __forceinline__ unsigned pk2_(float a, float b){
  unsigned ua = __float_as_uint(a), ub = __float_as_uint(b);
  ua = (ua + 0x7fffu + ((ua>>16)&1u)) >> 16;
  ub = (ub + 0x7fffu + ((ub>>16)&1u)) >> 16;
  return ua | (ub<<16);
}

// =================== generic tiled GEMM body ===================
struct GemmS { float x_s[2][64][68]; float w_s[2][64][68]; };

__device__ void gemm_body(const float* __restrict__ X, int xStride,
                          const float* __restrict__ X2, int Ksplit,
                          const float* __restrict__ W,
                          float* __restrict__ partial,
                          int K, int C, int nMt, int nCt, int KS,
                          int bid, int t, GemmS& sm){
  int mt = bid % nMt; int rest = bid / nMt;
  int ct = rest % nCt; int ks = rest / nCt;
  int m0 = mt << 6; int c0 = ct << 6;
  int M = nMt << 6;
  int nch = (K + 63) >> 6;
  int ch0 = (ks*nch)/KS, ch1 = ((ks+1)*nch)/KS;
  int bi = t >> 4, j = t & 15;
  float4 px[4], pw[4];

  auto ld = [&](int ch){
    int k0 = ch << 6;
    #pragma unroll
    for (int i=0;i<4;i++){
      int lin = i*256+t; int bl = lin>>4, kq = lin&15;
      int k = k0 + (kq<<2);
      float4 v = make_float4(0.f,0.f,0.f,0.f);
      if (k < K){
        if (X2 != nullptr && k >= Ksplit){
          v = *(const float4*)&X2[(size_t)bl*1024 + (k - Ksplit)];
        } else {
          v = *(const float4*)&X[(size_t)(m0+bl)*xStride + k];
        }
      }
      px[i] = v;
    }
    #pragma unroll
    for (int i=0;i<4;i++){
      int lin = i*256+t; int kk = lin>>4, cq = lin&15;
      int k = k0 + kk, c = c0 + (cq<<2);
      float4 v = make_float4(0.f,0.f,0.f,0.f);
      if (k < K && c < C) v = *(const float4*)&W[(size_t)k*C + c];
      pw[i] = v;
    }
  };
  auto st = [&](int buf){
    #pragma unroll
    for (int i=0;i<4;i++){
      int lin = i*256+t; int bl = lin>>4, kq = lin&15;
      *(float4*)&sm.x_s[buf][bl][kq<<2] = px[i];
    }
    #pragma unroll
    for (int i=0;i<4;i++){
      int lin = i*256+t; int kk = lin>>4, cq = lin&15;
      *(float4*)&sm.w_s[buf][kk][cq<<2] = pw[i];
    }
  };

  float4 acc[4];
  #pragma unroll
  for (int m=0;m<4;m++) acc[m] = make_float4(0.f,0.f,0.f,0.f);

  ld(ch0); st(0); __syncthreads();
  int buf = 0;
  for (int ch = ch0; ch < ch1; ++ch){
    if (ch+1 < ch1) ld(ch+1);
    #pragma unroll
    for (int kq=0;kq<16;kq++){
      float4 xv[4], wv[4];
      #pragma unroll
      for (int bb=0;bb<4;bb++) xv[bb] = *(const float4*)&sm.x_s[buf][(bi<<2)+bb][kq<<2];
      #pragma unroll
      for (int kk=0;kk<4;kk++) wv[kk] = *(const float4*)&sm.w_s[buf][(kq<<2)+kk][j<<2];
      #pragma unroll
      for (int bb=0;bb<4;bb++){
        float s0=xv[bb].x, s1=xv[bb].y, s2=xv[bb].z, s3=xv[bb].w;
        acc[bb].x += s0*wv[0].x + s1*wv[1].x + s2*wv[2].x + s3*wv[3].x;
        acc[bb].y += s0*wv[0].y + s1*wv[1].y + s2*wv[2].y + s3*wv[3].y;
        acc[bb].z += s0*wv[0].z + s1*wv[1].z + s2*wv[2].z + s3*wv[3].z;
        acc[bb].w += s0*wv[0].w + s1*wv[1].w + s2*wv[2].w + s3*wv[3].w;
      }
    }
    if (ch+1 < ch1){ st(buf^1); __syncthreads(); }
    buf ^= 1;
  }
  int c = c0 + (j<<2);
  if (c < C){
    #pragma unroll
    for (int bb=0;bb<4;bb++){
      int bl = (bi<<2)+bb;
      *(float4*)&partial[(size_t)(ks*M + m0 + bl)*C + c] = acc[bb];
    }
  }
}

// =================== LSTM gates GEMM body (bf16 MFMA) ===================
struct LstmS { uint4 WlA[2][512]; uint4 XlA[2][512]; float outb[64][68]; };

__device__ void lstm_body(const float* __restrict__ xA, int KxA,
                          const float* __restrict__ xB,
                          const float* __restrict__ Wih,
                          const float* __restrict__ Whh,
                          float* __restrict__ partial, int KS, int Klen,
                          int bid, int t, LstmS& sm){
  int Mblk = bid & 63;
  int ks = bid >> 6;
  int r0 = Mblk << 6;
  int nch = Klen >> 6;
  int ch0 = (ks*nch)/KS, ch1 = ((ks+1)*nch)/KS;
  int wid = t >> 6, lane = t & 63;

  float4 rw[2][2], rx[2][2];
  auto ld = [&](int ch){
    int k0 = ch << 6;
    #pragma unroll
    for (int u=0;u<2;u++){
      int g = t + (u<<8); int row = g>>3; int k = k0 + ((g&7)<<3);
      const float* sw;
      const float* sx;
      if (k < KxA){ sw = &Wih[(size_t)(r0+row)*KxA + k]; sx = &xA[(size_t)row*KxA + k]; }
      else        { sw = &Whh[((size_t)(r0+row)<<10) + (k - KxA)]; sx = &xB[((size_t)row<<10) + (k - KxA)]; }
      rw[u][0] = *(const float4*)sw; rw[u][1] = *(const float4*)(sw+4);
      rx[u][0] = *(const float4*)sx; rx[u][1] = *(const float4*)(sx+4);
    }
  };
  auto cvst = [&](int buf){
    #pragma unroll
    for (int u=0;u<2;u++){
      int g = t + (u<<8); int row = g>>3, gk = g&7;
      int byte = row*128 + ((gk ^ (row&7))<<4);
      uint4 vw, vx;
      vw.x = pk2_(rw[u][0].x, rw[u][0].y); vw.y = pk2_(rw[u][0].z, rw[u][0].w);
      vw.z = pk2_(rw[u][1].x, rw[u][1].y); vw.w = pk2_(rw[u][1].z, rw[u][1].w);
      vx.x = pk2_(rx[u][0].x, rx[u][0].y); vx.y = pk2_(rx[u][0].z, rx[u][0].w);
      vx.z = pk2_(rx[u][1].x, rx[u][1].y); vx.w = pk2_(rx[u][1].z, rx[u][1].w);
      *(uint4*)((char*)&sm.WlA[buf][0] + byte) = vw;
      *(uint4*)((char*)&sm.XlA[buf][0] + byte) = vx;
    }
  };

  fx4 acc[4];
  #pragma unroll
  for (int nt=0;nt<4;nt++) acc[nt] = (fx4){0.f,0.f,0.f,0.f};

  ld(ch0); cvst(0); __syncthreads();
  int buf = 0;
  for (int ch = ch0; ch < ch1; ++ch){
    if (ch+1 < ch1) ld(ch+1);
    int rowA = (wid<<4) + (lane&15);
    #pragma unroll
    for (int s=0;s<2;s++){
      int gA = (s<<2) + (lane>>4);
      bh8 a = *(bh8*)((char*)&sm.WlA[buf][0] + rowA*128 + ((gA ^ (rowA&7))<<4));
      #pragma unroll
      for (int nt=0;nt<4;nt++){
        int rowB = (nt<<4) + (lane&15);
        bh8 bf = *(bh8*)((char*)&sm.XlA[buf][0] + rowB*128 + ((gA ^ (rowB&7))<<4));
        acc[nt] = __builtin_amdgcn_mfma_f32_16x16x32_bf16(a, bf, acc[nt], 0, 0, 0);
      }
    }
    if (ch+1 < ch1){ cvst(buf^1); __syncthreads(); }
    buf ^= 1;
  }
  __syncthreads();
  #pragma unroll
  for (int nt=0;nt<4;nt++){
    #pragma unroll
    for (int q=0;q<4;q++)
      sm.outb[(nt<<4)+(lane&15)][(wid<<4)+((lane>>4)<<2)+q] = acc[nt][q];
  }
  __syncthreads();
  #pragma unroll
  for (int i=0;i<4;i++){
    int idx = i*256+t; int b = idx>>4; int r4 = (idx&15)<<2;
    float4 o = *(const float4*)&sm.outb[b][r4];
    *(float4*)&partial[(size_t)((ks<<6)+b)*4096 + r0 + r4] = o;
  }
}

// I-part standalone kernel (Wih * x only)
__global__ __launch_bounds__(256) void k_lstmI(const float* __restrict__ xA, int KxA,
                                               const float* __restrict__ Wih,
                                               float* __restrict__ partial,
                                               int KS, int Klen){
  __shared__ LstmS sm;
  lstm_body(xA, KxA, nullptr, Wih, nullptr, partial, KS, Klen,
            blockIdx.x, threadIdx.x, sm);
}

// =================== K1: argmax+gather | Wdec GEMM | pre1 GEMM | Whh1 rider ===================
__global__ __launch_bounds__(256) void k_front3(
    const float* __restrict__ prev, const int* __restrict__ lens,
    const float* __restrict__ enc, const float* __restrict__ indec,
    const float* __restrict__ spkr,
    const float* __restrict__ W1, const float* __restrict__ b1,
    const float* __restrict__ hid, const float* __restrict__ Wdec,
    const float* __restrict__ Whh1,
    int* __restrict__ lo_out, int* __restrict__ wl_out,
    float* __restrict__ encw, float* __restrict__ paw,
    float* __restrict__ x0, float* __restrict__ pA,
    float* __restrict__ p1x, float* __restrict__ pL1,
    int* __restrict__ ctr){
  __shared__ __align__(16) char smem_raw[sizeof(GemmS)];
  int bid = blockIdx.x, t = threadIdx.x;
  if (bid == 0 && t == 0) *ctr = 0;

  if (bid < 64){
    int n = bid;
    float* sv = (float*)smem_raw;
    int*   si = (int*)(smem_raw + 1024);
    int*   meta = (int*)(smem_raw + 2048);
    const float* p = prev + n*T_;
    float bv = -1e30f; int bi2 = 0x7fffffff;
    #pragma unroll
    for (int i=0;i<4;i++){
      int idx = t + (i<<8);
      float v = p[idx];
      if (v > bv || (v == bv && idx < bi2)){ bv = v; bi2 = idx; }
    }
    sv[t]=bv; si[t]=bi2; __syncthreads();
    for (int s=128; s>0; s>>=1){
      if (t < s){
        float v2 = sv[t+s]; int i2 = si[t+s];
        if (v2 > sv[t] || (v2 == sv[t] && i2 < si[t])){ sv[t]=v2; si[t]=i2; }
      }
      __syncthreads();
    }
    if (t==0){
      int len = lens[n]; len = len < 1 ? 1 : (len > T_ ? T_ : len);
      int idx = si[0];
      int lo = idx - 9; lo = lo < 0 ? 0 : lo; if (lo > len-1) lo = len-1;
      int hi = idx + 9; hi = hi < 0 ? 0 : hi; if (hi > len-1) hi = len-1;
      meta[0] = lo; meta[1] = hi - lo + 1;
      lo_out[n] = lo; wl_out[n] = hi - lo + 1;
    }
    __syncthreads();
    int lo = meta[0], wl = meta[1];
    #pragma unroll
    for (int i=0;i<10;i++){
      int lin = i*256 + t;
      int r = lin >> 7, e4 = (lin & 127) << 2;
      if (r < WMAX){
        float4 v = make_float4(0.f,0.f,0.f,0.f);
        if (r < wl) v = *(const float4*)&enc[(size_t)((n<<10)+lo+r)*E_ + e4];
        *(float4*)&encw[(size_t)(n*WMAX + r)*E_ + e4] = v;
      }
    }
    if (t < 49){
      int tt = lo - 15 + t;
      paw[n*49 + t] = (tt >= 0 && tt < T_) ? prev[(n<<10)+tt] : 0.f;
    }
    if (t < 16)
      *(float4*)&x0[n*832 + 768 + (t<<2)] = *(const float4*)&spkr[(n<<6) + (t<<2)];

  } else if (bid < 96){
    gemm_body(hid, 1024, hid + 64*1024, 1024, Wdec,
              pA, 2048, 256, 1, 4, 8, bid - 64, t, *(GemmS*)smem_raw);

  } else if (bid < 104){
    // pre1 GEMM (8 blocks)
    int d = bid - 96;
    float* xs = (float*)smem_raw;
    #pragma unroll
    for (int i=0;i<9;i++){
      int q = i*256 + t;
      if (q < 2304){
        int b = q/36; int k4 = (q - b*36) << 2;
        float4 v;
        if (k4 < O_) v = *(const float4*)&indec[b*O_ + k4];
        else         v = *(const float4*)&spkr[(b<<6) + (k4-O_)];
        *(float4*)&xs[b*144 + k4] = v;
      }
    }
    __syncthreads();
    int bi = t >> 4, j = t & 15;
    int c0 = (d<<6) + (j<<2);
    float4 acc[4];
    #pragma unroll
    for (int rr=0;rr<4;rr++) acc[rr] = make_float4(0.f,0.f,0.f,0.f);
    #pragma unroll 4
    for (int k=0;k<144;k++){
      float4 wv = *(const float4*)&W1[(size_t)k*512 + c0];
      #pragma unroll
      for (int rr=0;rr<4;rr++){
        float xv = xs[((bi<<2)+rr)*144 + k];
        acc[rr].x += xv*wv.x; acc[rr].y += xv*wv.y; acc[rr].z += xv*wv.z; acc[rr].w += xv*wv.w;
      }
    }
    float4 bv = *(const float4*)&b1[c0];
    #pragma unroll
    for (int rr=0;rr<4;rr++){
      float4 o;
      o.x = fmaxf(acc[rr].x + bv.x, 0.f);
      o.y = fmaxf(acc[rr].y + bv.y, 0.f);
      o.z = fmaxf(acc[rr].z + bv.z, 0.f);
      o.w = fmaxf(acc[rr].w + bv.w, 0.f);
      *(float4*)&p1x[(size_t)((bi<<2)+rr)*512 + c0] = o;
    }

  } else {
    // Whh1 * hid1 rider (128 blocks, KS=2 -> pL1 slots 0-1)
    lstm_body(nullptr, 0, hid + 64*1024, nullptr, Whh1,
              pL1, 2, 1024, bid - 104, t, *(LstmS*)smem_raw);
  }
}

// =================== K2: enc GEMM | pre2 GEMM | Whh0 rider ===================
__global__ __launch_bounds__(256) void k_gemmB(const float* __restrict__ encw,
                                               const float* __restrict__ Wenc,
                                               float* __restrict__ pE,
                                               const float* __restrict__ p1x,
                                               const float* __restrict__ W2,
                                               float* __restrict__ pP2,
                                               const float* __restrict__ hid,
                                               const float* __restrict__ Whh0,
                                               float* __restrict__ pL0){
  __shared__ __align__(16) char smem_raw[sizeof(GemmS)];
  int bid = blockIdx.x, t = threadIdx.x;
  if (bid < 304)
    gemm_body(encw, 512, nullptr, 0, Wenc, pE, 512, 256, 19, 4, 4,
              bid, t, *(GemmS*)smem_raw);
  else if (bid < 320)
    gemm_body(p1x, 512, nullptr, 0, W2, pP2, 512, 256, 1, 4, 4,
              bid - 304, t, *(GemmS*)smem_raw);
  else
    lstm_body(nullptr, 0, hid, nullptr, Whh0,
              pL0, 2, 1024, bid - 320, t, *(LstmS*)smem_raw);
}

// =================== K3: attention epilogue+softmax+ctx | pre2 combine ===================
__global__ __launch_bounds__(256) void k_att2(const float* __restrict__ pE,
    const float* __restrict__ pA, const float* __restrict__ benc,
    const float* __restrict__ convw, const float* __restrict__ Wproj,
    const float* __restrict__ spkr, const float* __restrict__ Wspkr,
    const float* __restrict__ paw, const int* __restrict__ wl_w,
    const float* __restrict__ encw,
    const float* __restrict__ pP2, const float* __restrict__ b2,
    float* __restrict__ x0, float* __restrict__ ctxb){
  __shared__ float cw_s[256*31];
  __shared__ float cv_s[WMAX*256];
  __shared__ float attb_s[256];
  __shared__ float pa_s[49];
  __shared__ float wlog_s[WMAX];
  __shared__ float w_s[WMAX];
  int t = threadIdx.x;

  if (blockIdx.x >= 64){
    int idx = (blockIdx.x - 64)*256 + t;
    int b = idx >> 6; int c4 = (idx & 63) << 2;
    float4 v = *(const float4*)&b2[c4];
    #pragma unroll
    for (int p=0;p<4;p++){
      float4 u = *(const float4*)&pP2[(size_t)((p<<6)+b)*A_ + c4];
      v.x+=u.x; v.y+=u.y; v.z+=u.z; v.w+=u.w;
    }
    v.x=fmaxf(v.x,0.f); v.y=fmaxf(v.y,0.f); v.z=fmaxf(v.z,0.f); v.w=fmaxf(v.w,0.f);
    *(float4*)&x0[b*832 + c4] = v;
    return;
  }

  int n = blockIdx.x;
  int wl = wl_w[n];
  for (int lin = t; lin < 256*31; lin += 256) cw_s[lin] = convw[lin];
  if (t < 49) pa_s[t] = paw[n*49 + t];
  {
    float v = 0.f;
    #pragma unroll
    for (int p=0;p<8;p++) v += pA[(size_t)((p<<6)+n)*A_ + t];
    float sd = 0.f;
    #pragma unroll 16
    for (int s=0;s<S_;s++) sd += spkr[(n<<6)+s]*Wspkr[(s<<8)+t];
    attb_s[t] = v + sd/(1.f+fabsf(sd));
  }
  __syncthreads();
  for (int r=0; r<wl; ++r){
    float cv = 0.f;
    #pragma unroll
    for (int k=0;k<31;k++) cv += cw_s[t*31+k]*pa_s[r+k];
    cv_s[(r<<8)+t] = cv;
  }
  __syncthreads();
  int wid = t>>6, lane = t&63, a0 = lane<<2;
  float4 be4 = *(const float4*)&benc[a0];
  float4 wp4 = *(const float4*)&Wproj[a0];
  float4 ab4 = *(const float4*)&attb_s[a0];
  for (int r = wid; r < wl; r += 4){
    float4 sv = make_float4(0.f,0.f,0.f,0.f);
    #pragma unroll
    for (int ks=0;ks<4;ks++){
      const float4 u = *(const float4*)&pE[(size_t)(ks*1216 + n*WMAX + r)*A_ + a0];
      sv.x+=u.x; sv.y+=u.y; sv.z+=u.z; sv.w+=u.w;
    }
    sv.x += be4.x; sv.y += be4.y; sv.z += be4.z; sv.w += be4.w;
    const float4 cv4 = *(const float4*)&cv_s[(r<<8)+a0];
    float e0 = sv.x/(1.f+fabsf(sv.x)) + ab4.x + cv4.x;
    float e1 = sv.y/(1.f+fabsf(sv.y)) + ab4.y + cv4.y;
    float e2 = sv.z/(1.f+fabsf(sv.z)) + ab4.z + cv4.z;
    float e3 = sv.w/(1.f+fabsf(sv.w)) + ab4.w + cv4.w;
    float vv = tanhf(e0)*wp4.x + tanhf(e1)*wp4.y + tanhf(e2)*wp4.z + tanhf(e3)*wp4.w;
    #pragma unroll
    for (int off=32; off; off >>= 1) vv += __shfl_xor(vv, off, 64);
    if (lane == 0) wlog_s[r] = vv;
  }
  __syncthreads();
  if (t < 32){
    float l = (t < wl) ? wlog_s[t] : -1e30f;
    float mx = l;
    #pragma unroll
    for (int off=16; off; off >>= 1) mx = fmaxf(mx, __shfl_xor(mx, off, 32));
    float ex = (t < wl) ? expf(l - mx) : 0.f;
    float sm = ex;
    #pragma unroll
    for (int off=16; off; off >>= 1) sm += __shfl_xor(sm, off, 32);
    if (t < wl) w_s[t] = ex / sm;
  }
  __syncthreads();
  if (t < 128){
    float4 a = make_float4(0.f,0.f,0.f,0.f);
    for (int r=0; r<wl; ++r){
      float wv = w_s[r];
      const float4 ev = *(const float4*)&encw[(size_t)(n*WMAX + r)*E_ + (t<<2)];
      a.x += wv*ev.x; a.y += wv*ev.y; a.z += wv*ev.z; a.w += wv*ev.w;
    }
    *(float4*)&x0[n*832 + 256 + (t<<2)] = a;
    *(float4*)&ctxb[(n<<10) + (t<<2)] = a;
  }
}

// =================== LSTM combine: gates -> h (256 blocks) ===================
__global__ __launch_bounds__(256) void k_comb(const float* __restrict__ pL, int NS,
                                              const float* __restrict__ bih,
                                              const float* __restrict__ bhh,
                                              const float* __restrict__ cprev,
                                              float* __restrict__ dst){
  int bid = blockIdx.x, t = threadIdx.x;
  int b = bid >> 2; int u = ((bid & 3) << 8) + t;
  float g[4];
  #pragma unroll
  for (int gi=0; gi<4; ++gi){
    int col = (gi<<10) + u;
    float s = bih[col] + bhh[col];
    for (int q=0; q<NS; ++q) s += pL[(size_t)((q<<6)+b)*4096 + col];
    g[gi] = s;
  }
  float c = cprev[(b<<10)+u];
  float cn = sigmoidf_(g[1])*c + sigmoidf_(g[0])*tanhf(g[2]);
  dst[(b<<10)+u] = sigmoidf_(g[3])*tanhf(cn);
}

// =================== K8: out GEMM + last-block final combine ===================
__global__ __launch_bounds__(256) void k_out(const float* __restrict__ h2b,
                                             const float* __restrict__ ctxb,
                                             const float* __restrict__ Wout,
                                             float* __restrict__ pO,
                                             const float* __restrict__ bout,
                                             float* __restrict__ out,
                                             int* __restrict__ ctr){
  __shared__ GemmS sm;
  int t = threadIdx.x;
  gemm_body(h2b, 1024, ctxb, 1024, Wout, pO, 1536, 160, 1, 3, 8,
            blockIdx.x, t, sm);
  __threadfence();
  __shared__ int isLast;
  if (t == 0){
    int old = atomicAdd(ctr, 1);
    isLast = (old == 23) ? 1 : 0;
  }
  __syncthreads();
  if (isLast){
    __threadfence();
    for (int i = t; i < 10240; i += 256){
      int b = i/160; int c = i - b*160;
      float s = bout[c];
      #pragma unroll
      for (int ks=0; ks<8; ++ks) s += pO[(size_t)((ks<<6)+b)*160 + c];
      out[i] = s;
    }
  }
}

extern "C" void kernel_launch(void* const* d_in, const int* in_sizes, int n_in,
                              void* d_out, int out_size, void* d_ws, size_t ws_size,
                              hipStream_t stream){
  const float* enc   = (const float*)d_in[0];
  const float* indec = (const float*)d_in[1];
  const float* spkr  = (const float*)d_in[2];
  const float* prev  = (const float*)d_in[3];
  const float* hid   = (const float*)d_in[4];
  const float* cell  = (const float*)d_in[5];
  const int*   lens  = (const int*)d_in[6];
  const float* Wenc  = (const float*)d_in[7];
  const float* benc  = (const float*)d_in[8];
  const float* Wspkr = (const float*)d_in[9];
  const float* convw = (const float*)d_in[10];
  const float* Wdec  = (const float*)d_in[11];
  const float* Wproj = (const float*)d_in[12];
  /* d_in[13] = b_proj: uniform shift, cancels in normalized attention weights */
  const float* Wpre1 = (const float*)d_in[14];
  const float* bpre1 = (const float*)d_in[15];
  const float* Wpre2 = (const float*)d_in[16];
  const float* bpre2 = (const float*)d_in[17];
  const float* Wih0  = (const float*)d_in[18];
  const float* Whh0  = (const float*)d_in[19];
  const float* bih0  = (const float*)d_in[20];
  const float* bhh0  = (const float*)d_in[21];
  const float* Wih1  = (const float*)d_in[22];
  const float* Whh1  = (const float*)d_in[23];
  const float* bih1  = (const float*)d_in[24];
  const float* bhh1  = (const float*)d_in[25];
  const float* Wout  = (const float*)d_in[26];
  const float* bout  = (const float*)d_in[27];
  (void)in_sizes; (void)n_in; (void)out_size; (void)ws_size;

  float* ws = (float*)d_ws;
  size_t off = 0;
  auto alloc = [&](size_t nf){ float* p = ws + off; off += nf; return p; };
  float* pA     = alloc((size_t)8*64*256);
  float* p1x    = alloc((size_t)64*512);
  float* pP2    = alloc((size_t)4*64*256);
  float* x0     = alloc(64*832);
  float* ctxb   = alloc((size_t)64*1024);
  float* h1     = alloc((size_t)64*1024);
  float* h2b    = alloc((size_t)64*1024);
  float* pO     = alloc((size_t)8*64*160);
  float* paw    = alloc(64*49 + 15);
  int*   lo_w   = (int*)alloc(64);
  int*   wl_w   = (int*)alloc(64);
  int*   ctr    = (int*)alloc(16);
  float* encw   = alloc((size_t)64*WMAX*512);
  float* pE     = alloc((size_t)4*1216*256);
  float* pL0    = alloc(6*SLOT);   // slots 0-1: Whh0 (KS=2), slots 2-5: Wih0 (KS=4)
  float* pL1    = alloc(6*SLOT);   // slots 0-1: Whh1 (KS=2), slots 2-5: Wih1 (KS=4)
  float* out    = (float*)d_out;

  // K1: front (0-63) | Wdec (64-95) | pre1 (96-103) | Whh1*hid1 (104-231)
  k_front3<<<232,256,0,stream>>>(prev, lens, enc, indec, spkr,
                                 Wpre1, bpre1, hid, Wdec, Whh1,
                                 lo_w, wl_w, encw, paw, x0, pA, p1x, pL1, ctr);
  // K2: enc GEMM (0-303) | pre2 (304-319) | Whh0*hid0 (320-447)
  k_gemmB<<<448,256,0,stream>>>(encw, Wenc, pE, p1x, Wpre2, pP2,
                                hid, Whh0, pL0);
  // K3: attention (0-63) | pre2 combine (64-79)
  k_att2<<<80,256,0,stream>>>(pE, pA, benc, convw, Wproj, spkr, Wspkr,
                              paw, wl_w, encw, pP2, bpre2, x0, ctxb);
  // K4: Wih0 * x0 (K=832) -> pL0 slots 2-5
  k_lstmI<<<256,256,0,stream>>>(x0, 832, Wih0, pL0 + 2*SLOT, 4, 832);
  // K5: combine layer 0 -> h1 (6 slots)
  k_comb<<<256,256,0,stream>>>(pL0, 6, bih0, bhh0, cell, h1);
  // K6: Wih1 * h1 (K=1024) -> pL1 slots 2-5
  k_lstmI<<<256,256,0,stream>>>(h1, 1024, Wih1, pL1 + 2*SLOT, 4, 1024);
  // K7: combine layer 1 -> h2b (6 slots)
  k_comb<<<256,256,0,stream>>>(pL1, 6, bih1, bhh1, cell + 64*1024, h2b);
  // K8: out GEMM + last-block final combine
  k_out<<<24,256,0,stream>>>(h2b, ctxb, Wout, pO, bout, out, ctr);
}

// Round 8
// 150.321 us; speedup vs baseline: 1.0631x; 1.0218x over previous
//
#include <hip/hip_runtime.h>
#include <math.h>

#define N_    64
#define T_    1024
#define E_    512
#define A_    256
#define S_    64
#define O_    80
#define HID_  1024
#define WMAX  19
#define SLOT  ((size_t)64*4096)

typedef __attribute__((ext_vector_type(8))) short bh8;
typedef __attribute__((ext_vector_type(4))) float fx4;

__device__ __forceinline__ float sigmoidf_(float x){ return 1.f/(1.f+expf(-x)); }
__device__ __forceinline__ unsigned pk2_(float a, float b){
  unsigned ua = __float_as_uint(a), ub = __float_as_uint(b);
  ua = (ua + 0x7fffu + ((ua>>16)&1u)) >> 16;
  ub = (ub + 0x7fffu + ((ub>>16)&1u)) >> 16;
  return ua | (ub<<16);
}

// =================== generic tiled GEMM body ===================
struct GemmS { float x_s[2][64][68]; float w_s[2][64][68]; };

__device__ void gemm_body(const float* __restrict__ X, int xStride,
                          const float* __restrict__ X2, int Ksplit,
                          const float* __restrict__ W,
                          float* __restrict__ partial,
                          int K, int C, int nMt, int nCt, int KS,
                          int bid, int t, GemmS& sm){
  int mt = bid % nMt; int rest = bid / nMt;
  int ct = rest % nCt; int ks = rest / nCt;
  int m0 = mt << 6; int c0 = ct << 6;
  int M = nMt << 6;
  int nch = (K + 63) >> 6;
  int ch0 = (ks*nch)/KS, ch1 = ((ks+1)*nch)/KS;
  int bi = t >> 4, j = t & 15;
  float4 px[4], pw[4];

  auto ld = [&](int ch){
    int k0 = ch << 6;
    #pragma unroll
    for (int i=0;i<4;i++){
      int lin = i*256+t; int bl = lin>>4, kq = lin&15;
      int k = k0 + (kq<<2);
      float4 v = make_float4(0.f,0.f,0.f,0.f);
      if (k < K){
        if (X2 != nullptr && k >= Ksplit){
          v = *(const float4*)&X2[(size_t)bl*1024 + (k - Ksplit)];
        } else {
          v = *(const float4*)&X[(size_t)(m0+bl)*xStride + k];
        }
      }
      px[i] = v;
    }
    #pragma unroll
    for (int i=0;i<4;i++){
      int lin = i*256+t; int kk = lin>>4, cq = lin&15;
      int k = k0 + kk, c = c0 + (cq<<2);
      float4 v = make_float4(0.f,0.f,0.f,0.f);
      if (k < K && c < C) v = *(const float4*)&W[(size_t)k*C + c];
      pw[i] = v;
    }
  };
  auto st = [&](int buf){
    #pragma unroll
    for (int i=0;i<4;i++){
      int lin = i*256+t; int bl = lin>>4, kq = lin&15;
      *(float4*)&sm.x_s[buf][bl][kq<<2] = px[i];
    }
    #pragma unroll
    for (int i=0;i<4;i++){
      int lin = i*256+t; int kk = lin>>4, cq = lin&15;
      *(float4*)&sm.w_s[buf][kk][cq<<2] = pw[i];
    }
  };

  float4 acc[4];
  #pragma unroll
  for (int m=0;m<4;m++) acc[m] = make_float4(0.f,0.f,0.f,0.f);

  ld(ch0); st(0); __syncthreads();
  int buf = 0;
  for (int ch = ch0; ch < ch1; ++ch){
    if (ch+1 < ch1) ld(ch+1);
    #pragma unroll
    for (int kq=0;kq<16;kq++){
      float4 xv[4], wv[4];
      #pragma unroll
      for (int bb=0;bb<4;bb++) xv[bb] = *(const float4*)&sm.x_s[buf][(bi<<2)+bb][kq<<2];
      #pragma unroll
      for (int kk=0;kk<4;kk++) wv[kk] = *(const float4*)&sm.w_s[buf][(kq<<2)+kk][j<<2];
      #pragma unroll
      for (int bb=0;bb<4;bb++){
        float s0=xv[bb].x, s1=xv[bb].y, s2=xv[bb].z, s3=xv[bb].w;
        acc[bb].x += s0*wv[0].x + s1*wv[1].x + s2*wv[2].x + s3*wv[3].x;
        acc[bb].y += s0*wv[0].y + s1*wv[1].y + s2*wv[2].y + s3*wv[3].y;
        acc[bb].z += s0*wv[0].z + s1*wv[1].z + s2*wv[2].z + s3*wv[3].z;
        acc[bb].w += s0*wv[0].w + s1*wv[1].w + s2*wv[2].w + s3*wv[3].w;
      }
    }
    if (ch+1 < ch1){ st(buf^1); __syncthreads(); }
    buf ^= 1;
  }
  int c = c0 + (j<<2);
  if (c < C){
    #pragma unroll
    for (int bb=0;bb<4;bb++){
      int bl = (bi<<2)+bb;
      *(float4*)&partial[(size_t)(ks*M + m0 + bl)*C + c] = acc[bb];
    }
  }
}

__global__ __launch_bounds__(256) void k_gemmA(const float* __restrict__ X, int xStride,
                                               const float* __restrict__ X2, int Ksplit,
                                               const float* __restrict__ W,
                                               float* __restrict__ partial,
                                               int K, int C, int nMt, int nCt, int KS){
  __shared__ GemmS sm;
  gemm_body(X,xStride,X2,Ksplit,W,partial,K,C,nMt,nCt,KS,blockIdx.x,threadIdx.x,sm);
}

// =================== LSTM gates GEMM body (bf16 MFMA) ===================
struct LstmS { uint4 WlA[2][512]; uint4 XlA[2][512]; float outb[64][68]; };

__device__ void lstm_body(const float* __restrict__ xA, int KxA,
                          const float* __restrict__ xB,
                          const float* __restrict__ Wih,
                          const float* __restrict__ Whh,
                          float* __restrict__ partial, int KS, int Klen,
                          int bid, int t, LstmS& sm){
  int Mblk = bid & 63;
  int ks = bid >> 6;
  int r0 = Mblk << 6;
  int nch = Klen >> 6;
  int ch0 = (ks*nch)/KS, ch1 = ((ks+1)*nch)/KS;
  int wid = t >> 6, lane = t & 63;

  float4 rw[2][2], rx[2][2];
  auto ld = [&](int ch){
    int k0 = ch << 6;
    #pragma unroll
    for (int u=0;u<2;u++){
      int g = t + (u<<8); int row = g>>3; int k = k0 + ((g&7)<<3);
      const float* sw;
      const float* sx;
      if (k < KxA){ sw = &Wih[(size_t)(r0+row)*KxA + k]; sx = &xA[(size_t)row*KxA + k]; }
      else        { sw = &Whh[((size_t)(r0+row)<<10) + (k - KxA)]; sx = &xB[((size_t)row<<10) + (k - KxA)]; }
      rw[u][0] = *(const float4*)sw; rw[u][1] = *(const float4*)(sw+4);
      rx[u][0] = *(const float4*)sx; rx[u][1] = *(const float4*)(sx+4);
    }
  };
  auto cvst = [&](int buf){
    #pragma unroll
    for (int u=0;u<2;u++){
      int g = t + (u<<8); int row = g>>3, gk = g&7;
      int byte = row*128 + ((gk ^ (row&7))<<4);
      uint4 vw, vx;
      vw.x = pk2_(rw[u][0].x, rw[u][0].y); vw.y = pk2_(rw[u][0].z, rw[u][0].w);
      vw.z = pk2_(rw[u][1].x, rw[u][1].y); vw.w = pk2_(rw[u][1].z, rw[u][1].w);
      vx.x = pk2_(rx[u][0].x, rx[u][0].y); vx.y = pk2_(rx[u][0].z, rx[u][0].w);
      vx.z = pk2_(rx[u][1].x, rx[u][1].y); vx.w = pk2_(rx[u][1].z, rx[u][1].w);
      *(uint4*)((char*)&sm.WlA[buf][0] + byte) = vw;
      *(uint4*)((char*)&sm.XlA[buf][0] + byte) = vx;
    }
  };

  fx4 acc[4];
  #pragma unroll
  for (int nt=0;nt<4;nt++) acc[nt] = (fx4){0.f,0.f,0.f,0.f};

  ld(ch0); cvst(0); __syncthreads();
  int buf = 0;
  for (int ch = ch0; ch < ch1; ++ch){
    if (ch+1 < ch1) ld(ch+1);
    int rowA = (wid<<4) + (lane&15);
    #pragma unroll
    for (int s=0;s<2;s++){
      int gA = (s<<2) + (lane>>4);
      bh8 a = *(bh8*)((char*)&sm.WlA[buf][0] + rowA*128 + ((gA ^ (rowA&7))<<4));
      #pragma unroll
      for (int nt=0;nt<4;nt++){
        int rowB = (nt<<4) + (lane&15);
        bh8 bf = *(bh8*)((char*)&sm.XlA[buf][0] + rowB*128 + ((gA ^ (rowB&7))<<4));
        acc[nt] = __builtin_amdgcn_mfma_f32_16x16x32_bf16(a, bf, acc[nt], 0, 0, 0);
      }
    }
    if (ch+1 < ch1){ cvst(buf^1); __syncthreads(); }
    buf ^= 1;
  }
  __syncthreads();
  #pragma unroll
  for (int nt=0;nt<4;nt++){
    #pragma unroll
    for (int q=0;q<4;q++)
      sm.outb[(nt<<4)+(lane&15)][(wid<<4)+((lane>>4)<<2)+q] = acc[nt][q];
  }
  __syncthreads();
  #pragma unroll
  for (int i=0;i<4;i++){
    int idx = i*256+t; int b = idx>>4; int r4 = (idx&15)<<2;
    float4 o = *(const float4*)&sm.outb[b][r4];
    *(float4*)&partial[(size_t)((ks<<6)+b)*4096 + r0 + r4] = o;
  }
}

// I-part standalone kernel (Wih * x only)
__global__ __launch_bounds__(256) void k_lstmI(const float* __restrict__ xA, int KxA,
                                               const float* __restrict__ Wih,
                                               float* __restrict__ partial,
                                               int KS, int Klen){
  __shared__ LstmS sm;
  lstm_body(xA, KxA, nullptr, Wih, nullptr, partial, KS, Klen,
            blockIdx.x, threadIdx.x, sm);
}

// =================== K1: argmax+gather | Wdec GEMM | pre1 GEMM ===================
__global__ __launch_bounds__(256) void k_front3(
    const float* __restrict__ prev, const int* __restrict__ lens,
    const float* __restrict__ enc, const float* __restrict__ indec,
    const float* __restrict__ spkr,
    const float* __restrict__ W1, const float* __restrict__ b1,
    const float* __restrict__ hid, const float* __restrict__ Wdec,
    int* __restrict__ lo_out, int* __restrict__ wl_out,
    float* __restrict__ encw, float* __restrict__ paw,
    float* __restrict__ x0, float* __restrict__ pA,
    float* __restrict__ p1x){
  __shared__ __align__(16) char smem_raw[sizeof(GemmS)];
  int bid = blockIdx.x, t = threadIdx.x;

  if (bid < 64){
    int n = bid;
    float* sv = (float*)smem_raw;
    int*   si = (int*)(smem_raw + 1024);
    int*   meta = (int*)(smem_raw + 2048);
    const float* p = prev + n*T_;
    float bv = -1e30f; int bi2 = 0x7fffffff;
    #pragma unroll
    for (int i=0;i<4;i++){
      int idx = t + (i<<8);
      float v = p[idx];
      if (v > bv || (v == bv && idx < bi2)){ bv = v; bi2 = idx; }
    }
    sv[t]=bv; si[t]=bi2; __syncthreads();
    for (int s=128; s>0; s>>=1){
      if (t < s){
        float v2 = sv[t+s]; int i2 = si[t+s];
        if (v2 > sv[t] || (v2 == sv[t] && i2 < si[t])){ sv[t]=v2; si[t]=i2; }
      }
      __syncthreads();
    }
    if (t==0){
      int len = lens[n]; len = len < 1 ? 1 : (len > T_ ? T_ : len);
      int idx = si[0];
      int lo = idx - 9; lo = lo < 0 ? 0 : lo; if (lo > len-1) lo = len-1;
      int hi = idx + 9; hi = hi < 0 ? 0 : hi; if (hi > len-1) hi = len-1;
      meta[0] = lo; meta[1] = hi - lo + 1;
      lo_out[n] = lo; wl_out[n] = hi - lo + 1;
    }
    __syncthreads();
    int lo = meta[0], wl = meta[1];
    #pragma unroll
    for (int i=0;i<10;i++){
      int lin = i*256 + t;
      int r = lin >> 7, e4 = (lin & 127) << 2;
      if (r < WMAX){
        float4 v = make_float4(0.f,0.f,0.f,0.f);
        if (r < wl) v = *(const float4*)&enc[(size_t)((n<<10)+lo+r)*E_ + e4];
        *(float4*)&encw[(size_t)(n*WMAX + r)*E_ + e4] = v;
      }
    }
    if (t < 49){
      int tt = lo - 15 + t;
      paw[n*49 + t] = (tt >= 0 && tt < T_) ? prev[(n<<10)+tt] : 0.f;
    }
    if (t < 16)
      *(float4*)&x0[n*832 + 768 + (t<<2)] = *(const float4*)&spkr[(n<<6) + (t<<2)];

  } else if (bid < 96){
    gemm_body(hid, 1024, hid + 64*1024, 1024, Wdec,
              pA, 2048, 256, 1, 4, 8, bid - 64, t, *(GemmS*)smem_raw);

  } else {
    // pre1 GEMM (8 blocks)
    int d = bid - 96;
    float* xs = (float*)smem_raw;
    #pragma unroll
    for (int i=0;i<9;i++){
      int q = i*256 + t;
      if (q < 2304){
        int b = q/36; int k4 = (q - b*36) << 2;
        float4 v;
        if (k4 < O_) v = *(const float4*)&indec[b*O_ + k4];
        else         v = *(const float4*)&spkr[(b<<6) + (k4-O_)];
        *(float4*)&xs[b*144 + k4] = v;
      }
    }
    __syncthreads();
    int bi = t >> 4, j = t & 15;
    int c0 = (d<<6) + (j<<2);
    float4 acc[4];
    #pragma unroll
    for (int rr=0;rr<4;rr++) acc[rr] = make_float4(0.f,0.f,0.f,0.f);
    #pragma unroll 4
    for (int k=0;k<144;k++){
      float4 wv = *(const float4*)&W1[(size_t)k*512 + c0];
      #pragma unroll
      for (int rr=0;rr<4;rr++){
        float xv = xs[((bi<<2)+rr)*144 + k];
        acc[rr].x += xv*wv.x; acc[rr].y += xv*wv.y; acc[rr].z += xv*wv.z; acc[rr].w += xv*wv.w;
      }
    }
    float4 bv = *(const float4*)&b1[c0];
    #pragma unroll
    for (int rr=0;rr<4;rr++){
      float4 o;
      o.x = fmaxf(acc[rr].x + bv.x, 0.f);
      o.y = fmaxf(acc[rr].y + bv.y, 0.f);
      o.z = fmaxf(acc[rr].z + bv.z, 0.f);
      o.w = fmaxf(acc[rr].w + bv.w, 0.f);
      *(float4*)&p1x[(size_t)((bi<<2)+rr)*512 + c0] = o;
    }
  }
}

// =================== K2: enc GEMM | pre2 GEMM ===================
__global__ __launch_bounds__(256) void k_gemmB(const float* __restrict__ encw,
                                               const float* __restrict__ Wenc,
                                               float* __restrict__ pE,
                                               const float* __restrict__ p1x,
                                               const float* __restrict__ W2,
                                               float* __restrict__ pP2){
  __shared__ GemmS sm;
  if (blockIdx.x < 304)
    gemm_body(encw, 512, nullptr, 0, Wenc, pE, 512, 256, 19, 4, 4,
              blockIdx.x, threadIdx.x, sm);
  else
    gemm_body(p1x, 512, nullptr, 0, W2, pP2, 512, 256, 1, 4, 4,
              blockIdx.x - 304, threadIdx.x, sm);
}

// =================== K3: attention | pre2 combine | Whh0 rider | Whh1 rider ===================
struct AttS {
  float cw[256*31];
  float cv[WMAX*256];
  float attb[256];
  float pa[52];
  float wlog[WMAX];
  float w[WMAX+1];
};

__global__ __launch_bounds__(256) void k_att3(const float* __restrict__ pE,
    const float* __restrict__ pA, const float* __restrict__ benc,
    const float* __restrict__ convw, const float* __restrict__ Wproj,
    const float* __restrict__ spkr, const float* __restrict__ Wspkr,
    const float* __restrict__ paw, const int* __restrict__ wl_w,
    const float* __restrict__ encw,
    const float* __restrict__ pP2, const float* __restrict__ b2,
    const float* __restrict__ hid,
    const float* __restrict__ Whh0, const float* __restrict__ Whh1,
    float* __restrict__ x0, float* __restrict__ ctxb,
    float* __restrict__ pL0, float* __restrict__ pL1){
  __shared__ __align__(16) char smem_raw[(sizeof(AttS) > sizeof(LstmS)) ? sizeof(AttS) : sizeof(LstmS)];
  int t = threadIdx.x;
  int bid = blockIdx.x;

  if (bid >= 208){
    // Whh1 * hid1 rider (128 blocks, KS=2 -> pL1 slots 0-1)
    lstm_body(nullptr, 0, hid + 64*1024, nullptr, Whh1,
              pL1, 2, 1024, bid - 208, t, *(LstmS*)smem_raw);
    return;
  }
  if (bid >= 80){
    // Whh0 * hid0 rider (128 blocks, KS=2 -> pL0 slots 0-1)
    lstm_body(nullptr, 0, hid, nullptr, Whh0,
              pL0, 2, 1024, bid - 80, t, *(LstmS*)smem_raw);
    return;
  }
  if (bid >= 64){
    // pre2 combine -> x0[:,0:256)
    int idx = (bid - 64)*256 + t;
    int b = idx >> 6; int c4 = (idx & 63) << 2;
    float4 v = *(const float4*)&b2[c4];
    #pragma unroll
    for (int p=0;p<4;p++){
      float4 u = *(const float4*)&pP2[(size_t)((p<<6)+b)*A_ + c4];
      v.x+=u.x; v.y+=u.y; v.z+=u.z; v.w+=u.w;
    }
    v.x=fmaxf(v.x,0.f); v.y=fmaxf(v.y,0.f); v.z=fmaxf(v.z,0.f); v.w=fmaxf(v.w,0.f);
    *(float4*)&x0[b*832 + c4] = v;
    return;
  }

  AttS& s = *(AttS*)smem_raw;
  int n = bid;
  int wl = wl_w[n];
  for (int lin = t; lin < 256*31; lin += 256) s.cw[lin] = convw[lin];
  if (t < 49) s.pa[t] = paw[n*49 + t];
  {
    float v = 0.f;
    #pragma unroll
    for (int p=0;p<8;p++) v += pA[(size_t)((p<<6)+n)*A_ + t];
    float sd = 0.f;
    #pragma unroll 16
    for (int si=0;si<S_;si++) sd += spkr[(n<<6)+si]*Wspkr[(si<<8)+t];
    s.attb[t] = v + sd/(1.f+fabsf(sd));
  }
  __syncthreads();
  for (int r=0; r<wl; ++r){
    float cv = 0.f;
    #pragma unroll
    for (int k=0;k<31;k++) cv += s.cw[t*31+k]*s.pa[r+k];
    s.cv[(r<<8)+t] = cv;
  }
  __syncthreads();
  int wid = t>>6, lane = t&63, a0 = lane<<2;
  float4 be4 = *(const float4*)&benc[a0];
  float4 wp4 = *(const float4*)&Wproj[a0];
  float4 ab4 = *(const float4*)&s.attb[a0];
  for (int r = wid; r < wl; r += 4){
    float4 sv = make_float4(0.f,0.f,0.f,0.f);
    #pragma unroll
    for (int ks=0;ks<4;ks++){
      const float4 u = *(const float4*)&pE[(size_t)(ks*1216 + n*WMAX + r)*A_ + a0];
      sv.x+=u.x; sv.y+=u.y; sv.z+=u.z; sv.w+=u.w;
    }
    sv.x += be4.x; sv.y += be4.y; sv.z += be4.z; sv.w += be4.w;
    const float4 cv4 = *(const float4*)&s.cv[(r<<8)+a0];
    float e0 = sv.x/(1.f+fabsf(sv.x)) + ab4.x + cv4.x;
    float e1 = sv.y/(1.f+fabsf(sv.y)) + ab4.y + cv4.y;
    float e2 = sv.z/(1.f+fabsf(sv.z)) + ab4.z + cv4.z;
    float e3 = sv.w/(1.f+fabsf(sv.w)) + ab4.w + cv4.w;
    float vv = tanhf(e0)*wp4.x + tanhf(e1)*wp4.y + tanhf(e2)*wp4.z + tanhf(e3)*wp4.w;
    #pragma unroll
    for (int off=32; off; off >>= 1) vv += __shfl_xor(vv, off, 64);
    if (lane == 0) s.wlog[r] = vv;
  }
  __syncthreads();
  if (t < 32){
    float l = (t < wl) ? s.wlog[t] : -1e30f;
    float mx = l;
    #pragma unroll
    for (int off=16; off; off >>= 1) mx = fmaxf(mx, __shfl_xor(mx, off, 32));
    float ex = (t < wl) ? expf(l - mx) : 0.f;
    float sm = ex;
    #pragma unroll
    for (int off=16; off; off >>= 1) sm += __shfl_xor(sm, off, 32);
    if (t < wl) s.w[t] = ex / sm;
  }
  __syncthreads();
  if (t < 128){
    float4 a = make_float4(0.f,0.f,0.f,0.f);
    for (int r=0; r<wl; ++r){
      float wv = s.w[r];
      const float4 ev = *(const float4*)&encw[(size_t)(n*WMAX + r)*E_ + (t<<2)];
      a.x += wv*ev.x; a.y += wv*ev.y; a.z += wv*ev.z; a.w += wv*ev.w;
    }
    *(float4*)&x0[n*832 + 256 + (t<<2)] = a;
    *(float4*)&ctxb[(n<<10) + (t<<2)] = a;
  }
}

// =================== LSTM combine: gates -> h (256 blocks) ===================
__global__ __launch_bounds__(256) void k_comb(const float* __restrict__ pL, int NS,
                                              const float* __restrict__ bih,
                                              const float* __restrict__ bhh,
                                              const float* __restrict__ cprev,
                                              float* __restrict__ dst){
  int bid = blockIdx.x, t = threadIdx.x;
  int b = bid >> 2; int u = ((bid & 3) << 8) + t;
  float g[4];
  #pragma unroll
  for (int gi=0; gi<4; ++gi){
    int col = (gi<<10) + u;
    float s = bih[col] + bhh[col];
    for (int q=0; q<NS; ++q) s += pL[(size_t)((q<<6)+b)*4096 + col];
    g[gi] = s;
  }
  float c = cprev[(b<<10)+u];
  float cn = sigmoidf_(g[1])*c + sigmoidf_(g[0])*tanhf(g[2]);
  dst[(b<<10)+u] = sigmoidf_(g[3])*tanhf(cn);
}

// =================== output combine ===================
__global__ __launch_bounds__(256) void k_comb_out(const float* __restrict__ pO,
                                                  const float* __restrict__ bout,
                                                  float* __restrict__ out){
  int idx = blockIdx.x*256 + threadIdx.x;
  int b = idx / 160; int c = idx - b*160;
  float s = bout[c];
  #pragma unroll
  for (int ks=0; ks<8; ++ks) s += pO[(size_t)((ks<<6)+b)*160 + c];
  out[idx] = s;
}

extern "C" void kernel_launch(void* const* d_in, const int* in_sizes, int n_in,
                              void* d_out, int out_size, void* d_ws, size_t ws_size,
                              hipStream_t stream){
  const float* enc   = (const float*)d_in[0];
  const float* indec = (const float*)d_in[1];
  const float* spkr  = (const float*)d_in[2];
  const float* prev  = (const float*)d_in[3];
  const float* hid   = (const float*)d_in[4];
  const float* cell  = (const float*)d_in[5];
  const int*   lens  = (const int*)d_in[6];
  const float* Wenc  = (const float*)d_in[7];
  const float* benc  = (const float*)d_in[8];
  const float* Wspkr = (const float*)d_in[9];
  const float* convw = (const float*)d_in[10];
  const float* Wdec  = (const float*)d_in[11];
  const float* Wproj = (const float*)d_in[12];
  /* d_in[13] = b_proj: uniform shift, cancels in normalized attention weights */
  const float* Wpre1 = (const float*)d_in[14];
  const float* bpre1 = (const float*)d_in[15];
  const float* Wpre2 = (const float*)d_in[16];
  const float* bpre2 = (const float*)d_in[17];
  const float* Wih0  = (const float*)d_in[18];
  const float* Whh0  = (const float*)d_in[19];
  const float* bih0  = (const float*)d_in[20];
  const float* bhh0  = (const float*)d_in[21];
  const float* Wih1  = (const float*)d_in[22];
  const float* Whh1  = (const float*)d_in[23];
  const float* bih1  = (const float*)d_in[24];
  const float* bhh1  = (const float*)d_in[25];
  const float* Wout  = (const float*)d_in[26];
  const float* bout  = (const float*)d_in[27];
  (void)in_sizes; (void)n_in; (void)out_size; (void)ws_size;

  float* ws = (float*)d_ws;
  size_t off = 0;
  auto alloc = [&](size_t nf){ float* p = ws + off; off += nf; return p; };
  float* pA     = alloc((size_t)8*64*256);
  float* p1x    = alloc((size_t)64*512);
  float* pP2    = alloc((size_t)4*64*256);
  float* x0     = alloc(64*832);
  float* ctxb   = alloc((size_t)64*1024);
  float* h1     = alloc((size_t)64*1024);
  float* h2b    = alloc((size_t)64*1024);
  float* pO     = alloc((size_t)8*64*160);
  float* paw    = alloc(64*49 + 15);
  int*   lo_w   = (int*)alloc(64);
  int*   wl_w   = (int*)alloc(64);
  float* encw   = alloc((size_t)64*WMAX*512);
  float* pE     = alloc((size_t)4*1216*256);
  float* pL0    = alloc(6*SLOT);   // slots 0-1: Whh0 (KS=2), slots 2-5: Wih0 (KS=4)
  float* pL1    = alloc(6*SLOT);   // slots 0-1: Whh1 (KS=2), slots 2-5: Wih1 (KS=4)
  float* out    = (float*)d_out;

  // K1: front (0-63) | Wdec (64-95) | pre1 (96-103)
  k_front3<<<104,256,0,stream>>>(prev, lens, enc, indec, spkr,
                                 Wpre1, bpre1, hid, Wdec,
                                 lo_w, wl_w, encw, paw, x0, pA, p1x);
  // K2: enc GEMM (0-303) | pre2 (304-319)
  k_gemmB<<<320,256,0,stream>>>(encw, Wenc, pE, p1x, Wpre2, pP2);
  // K3: attention (0-63) | pre2 combine (64-79) | Whh0 (80-207) | Whh1 (208-335)
  k_att3<<<336,256,0,stream>>>(pE, pA, benc, convw, Wproj, spkr, Wspkr,
                               paw, wl_w, encw, pP2, bpre2,
                               hid, Whh0, Whh1,
                               x0, ctxb, pL0, pL1);
  // K4: Wih0 * x0 (K=832) -> pL0 slots 2-5
  k_lstmI<<<256,256,0,stream>>>(x0, 832, Wih0, pL0 + 2*SLOT, 4, 832);
  // K5: combine layer 0 -> h1 (6 slots)
  k_comb<<<256,256,0,stream>>>(pL0, 6, bih0, bhh0, cell, h1);
  // K6: Wih1 * h1 (K=1024) -> pL1 slots 2-5
  k_lstmI<<<256,256,0,stream>>>(h1, 1024, Wih1, pL1 + 2*SLOT, 4, 1024);
  // K7: combine layer 1 -> h2b (6 slots)
  k_comb<<<256,256,0,stream>>>(pL1, 6, bih1, bhh1, cell + 64*1024, h2b);
  // K8: out GEMM (tiled, Wout read once) -> partials
  k_gemmA<<<1*3*8,256,0,stream>>>(h2b, 1024, ctxb, 1024, Wout,
                                  pO, 1536, 160, 1, 3, 8);
  // K9: output combine
  k_comb_out<<<40,256,0,stream>>>(pO, bout, out);
}

// Round 9
// 131.591 us; speedup vs baseline: 1.2144x; 1.1423x over previous
//
#include <hip/hip_runtime.h>
#include <math.h>

#define N_    64
#define T_    1024
#define E_    512
#define A_    256
#define S_    64
#define O_    80
#define HID_  1024
#define WMAX  19
#define SLOT  ((size_t)64*4096)

typedef __attribute__((ext_vector_type(8))) short bh8;
typedef __attribute__((ext_vector_type(4))) float fx4;

__device__ __forceinline__ float sigmoidf_(float x){ return 1.f/(1.f+expf(-x)); }
__device__ __forceinline__ unsigned pk2_(float a, float b){
  unsigned ua = __float_as_uint(a), ub = __float_as_uint(b);
  ua = (ua + 0x7fffu + ((ua>>16)&1u)) >> 16;
  ub = (ub + 0x7fffu + ((ub>>16)&1u)) >> 16;
  return ua | (ub<<16);
}

// =================== generic tiled GEMM body ===================
struct GemmS { float x_s[2][64][68]; float w_s[2][64][68]; };

__device__ void gemm_body(const float* __restrict__ X, int xStride,
                          const float* __restrict__ X2, int Ksplit,
                          const float* __restrict__ W,
                          float* __restrict__ partial,
                          int K, int C, int nMt, int nCt, int KS,
                          int bid, int t, GemmS& sm){
  int mt = bid % nMt; int rest = bid / nMt;
  int ct = rest % nCt; int ks = rest / nCt;
  int m0 = mt << 6; int c0 = ct << 6;
  int M = nMt << 6;
  int nch = (K + 63) >> 6;
  int ch0 = (ks*nch)/KS, ch1 = ((ks+1)*nch)/KS;
  int bi = t >> 4, j = t & 15;
  float4 px[4], pw[4];

  auto ld = [&](int ch){
    int k0 = ch << 6;
    #pragma unroll
    for (int i=0;i<4;i++){
      int lin = i*256+t; int bl = lin>>4, kq = lin&15;
      int k = k0 + (kq<<2);
      float4 v = make_float4(0.f,0.f,0.f,0.f);
      if (k < K){
        if (X2 != nullptr && k >= Ksplit){
          v = *(const float4*)&X2[(size_t)bl*1024 + (k - Ksplit)];
        } else {
          v = *(const float4*)&X[(size_t)(m0+bl)*xStride + k];
        }
      }
      px[i] = v;
    }
    #pragma unroll
    for (int i=0;i<4;i++){
      int lin = i*256+t; int kk = lin>>4, cq = lin&15;
      int k = k0 + kk, c = c0 + (cq<<2);
      float4 v = make_float4(0.f,0.f,0.f,0.f);
      if (k < K && c < C) v = *(const float4*)&W[(size_t)k*C + c];
      pw[i] = v;
    }
  };
  auto st = [&](int buf){
    #pragma unroll
    for (int i=0;i<4;i++){
      int lin = i*256+t; int bl = lin>>4, kq = lin&15;
      *(float4*)&sm.x_s[buf][bl][kq<<2] = px[i];
    }
    #pragma unroll
    for (int i=0;i<4;i++){
      int lin = i*256+t; int kk = lin>>4, cq = lin&15;
      *(float4*)&sm.w_s[buf][kk][cq<<2] = pw[i];
    }
  };

  float4 acc[4];
  #pragma unroll
  for (int m=0;m<4;m++) acc[m] = make_float4(0.f,0.f,0.f,0.f);

  ld(ch0); st(0); __syncthreads();
  int buf = 0;
  for (int ch = ch0; ch < ch1; ++ch){
    if (ch+1 < ch1) ld(ch+1);
    #pragma unroll
    for (int kq=0;kq<16;kq++){
      float4 xv[4], wv[4];
      #pragma unroll
      for (int bb=0;bb<4;bb++) xv[bb] = *(const float4*)&sm.x_s[buf][(bi<<2)+bb][kq<<2];
      #pragma unroll
      for (int kk=0;kk<4;kk++) wv[kk] = *(const float4*)&sm.w_s[buf][(kq<<2)+kk][j<<2];
      #pragma unroll
      for (int bb=0;bb<4;bb++){
        float s0=xv[bb].x, s1=xv[bb].y, s2=xv[bb].z, s3=xv[bb].w;
        acc[bb].x += s0*wv[0].x + s1*wv[1].x + s2*wv[2].x + s3*wv[3].x;
        acc[bb].y += s0*wv[0].y + s1*wv[1].y + s2*wv[2].y + s3*wv[3].y;
        acc[bb].z += s0*wv[0].z + s1*wv[1].z + s2*wv[2].z + s3*wv[3].z;
        acc[bb].w += s0*wv[0].w + s1*wv[1].w + s2*wv[2].w + s3*wv[3].w;
      }
    }
    if (ch+1 < ch1){ st(buf^1); __syncthreads(); }
    buf ^= 1;
  }
  int c = c0 + (j<<2);
  if (c < C){
    #pragma unroll
    for (int bb=0;bb<4;bb++){
      int bl = (bi<<2)+bb;
      *(float4*)&partial[(size_t)(ks*M + m0 + bl)*C + c] = acc[bb];
    }
  }
}

__global__ __launch_bounds__(256) void k_gemmA(const float* __restrict__ X, int xStride,
                                               const float* __restrict__ X2, int Ksplit,
                                               const float* __restrict__ W,
                                               float* __restrict__ partial,
                                               int K, int C, int nMt, int nCt, int KS){
  __shared__ GemmS sm;
  gemm_body(X,xStride,X2,Ksplit,W,partial,K,C,nMt,nCt,KS,blockIdx.x,threadIdx.x,sm);
}

// =================== LSTM gates GEMM body (bf16 MFMA) ===================
struct LstmS { uint4 WlA[2][512]; uint4 XlA[2][512]; float outb[64][68]; };

__device__ void lstm_body(const float* __restrict__ xA, int KxA,
                          const float* __restrict__ xB,
                          const float* __restrict__ Wih,
                          const float* __restrict__ Whh,
                          float* __restrict__ partial, int KS, int Klen,
                          int bid, int t, LstmS& sm){
  int Mblk = bid & 63;
  int ks = bid >> 6;
  int r0 = Mblk << 6;
  int nch = Klen >> 6;
  int ch0 = (ks*nch)/KS, ch1 = ((ks+1)*nch)/KS;
  int wid = t >> 6, lane = t & 63;

  float4 rw[2][2], rx[2][2];
  auto ld = [&](int ch){
    int k0 = ch << 6;
    #pragma unroll
    for (int u=0;u<2;u++){
      int g = t + (u<<8); int row = g>>3; int k = k0 + ((g&7)<<3);
      const float* sw;
      const float* sx;
      if (k < KxA){ sw = &Wih[(size_t)(r0+row)*KxA + k]; sx = &xA[(size_t)row*KxA + k]; }
      else        { sw = &Whh[((size_t)(r0+row)<<10) + (k - KxA)]; sx = &xB[((size_t)row<<10) + (k - KxA)]; }
      rw[u][0] = *(const float4*)sw; rw[u][1] = *(const float4*)(sw+4);
      rx[u][0] = *(const float4*)sx; rx[u][1] = *(const float4*)(sx+4);
    }
  };
  auto cvst = [&](int buf){
    #pragma unroll
    for (int u=0;u<2;u++){
      int g = t + (u<<8); int row = g>>3, gk = g&7;
      int byte = row*128 + ((gk ^ (row&7))<<4);
      uint4 vw, vx;
      vw.x = pk2_(rw[u][0].x, rw[u][0].y); vw.y = pk2_(rw[u][0].z, rw[u][0].w);
      vw.z = pk2_(rw[u][1].x, rw[u][1].y); vw.w = pk2_(rw[u][1].z, rw[u][1].w);
      vx.x = pk2_(rx[u][0].x, rx[u][0].y); vx.y = pk2_(rx[u][0].z, rx[u][0].w);
      vx.z = pk2_(rx[u][1].x, rx[u][1].y); vx.w = pk2_(rx[u][1].z, rx[u][1].w);
      *(uint4*)((char*)&sm.WlA[buf][0] + byte) = vw;
      *(uint4*)((char*)&sm.XlA[buf][0] + byte) = vx;
    }
  };

  fx4 acc[4];
  #pragma unroll
  for (int nt=0;nt<4;nt++) acc[nt] = (fx4){0.f,0.f,0.f,0.f};

  ld(ch0); cvst(0); __syncthreads();
  int buf = 0;
  for (int ch = ch0; ch < ch1; ++ch){
    if (ch+1 < ch1) ld(ch+1);
    int rowA = (wid<<4) + (lane&15);
    #pragma unroll
    for (int s=0;s<2;s++){
      int gA = (s<<2) + (lane>>4);
      bh8 a = *(bh8*)((char*)&sm.WlA[buf][0] + rowA*128 + ((gA ^ (rowA&7))<<4));
      #pragma unroll
      for (int nt=0;nt<4;nt++){
        int rowB = (nt<<4) + (lane&15);
        bh8 bf = *(bh8*)((char*)&sm.XlA[buf][0] + rowB*128 + ((gA ^ (rowB&7))<<4));
        acc[nt] = __builtin_amdgcn_mfma_f32_16x16x32_bf16(a, bf, acc[nt], 0, 0, 0);
      }
    }
    if (ch+1 < ch1){ cvst(buf^1); __syncthreads(); }
    buf ^= 1;
  }
  __syncthreads();
  #pragma unroll
  for (int nt=0;nt<4;nt++){
    #pragma unroll
    for (int q=0;q<4;q++)
      sm.outb[(nt<<4)+(lane&15)][(wid<<4)+((lane>>4)<<2)+q] = acc[nt][q];
  }
  __syncthreads();
  #pragma unroll
  for (int i=0;i<4;i++){
    int idx = i*256+t; int b = idx>>4; int r4 = (idx&15)<<2;
    float4 o = *(const float4*)&sm.outb[b][r4];
    *(float4*)&partial[(size_t)((ks<<6)+b)*4096 + r0 + r4] = o;
  }
}

// I-part standalone kernel (Wih * x only)
__global__ __launch_bounds__(256) void k_lstmI(const float* __restrict__ xA, int KxA,
                                               const float* __restrict__ Wih,
                                               float* __restrict__ partial,
                                               int KS, int Klen){
  __shared__ LstmS sm;
  lstm_body(xA, KxA, nullptr, Wih, nullptr, partial, KS, Klen,
            blockIdx.x, threadIdx.x, sm);
}

// =================== K1: argmax+gather | Wdec GEMM | pre1 GEMM | Whh1 rider ===================
__global__ __launch_bounds__(256) void k_front3(
    const float* __restrict__ prev, const int* __restrict__ lens,
    const float* __restrict__ enc, const float* __restrict__ indec,
    const float* __restrict__ spkr,
    const float* __restrict__ W1, const float* __restrict__ b1,
    const float* __restrict__ hid, const float* __restrict__ Wdec,
    const float* __restrict__ Whh1,
    int* __restrict__ lo_out, int* __restrict__ wl_out,
    float* __restrict__ encw, float* __restrict__ paw,
    float* __restrict__ x0, float* __restrict__ pA,
    float* __restrict__ p1x, float* __restrict__ pL1){
  __shared__ __align__(16) char smem_raw[sizeof(GemmS)];
  int bid = blockIdx.x, t = threadIdx.x;

  if (bid < 64){
    int n = bid;
    float* sv = (float*)smem_raw;
    int*   si = (int*)(smem_raw + 1024);
    int*   meta = (int*)(smem_raw + 2048);
    const float* p = prev + n*T_;
    float bv = -1e30f; int bi2 = 0x7fffffff;
    #pragma unroll
    for (int i=0;i<4;i++){
      int idx = t + (i<<8);
      float v = p[idx];
      if (v > bv || (v == bv && idx < bi2)){ bv = v; bi2 = idx; }
    }
    sv[t]=bv; si[t]=bi2; __syncthreads();
    for (int s=128; s>0; s>>=1){
      if (t < s){
        float v2 = sv[t+s]; int i2 = si[t+s];
        if (v2 > sv[t] || (v2 == sv[t] && i2 < si[t])){ sv[t]=v2; si[t]=i2; }
      }
      __syncthreads();
    }
    if (t==0){
      int len = lens[n]; len = len < 1 ? 1 : (len > T_ ? T_ : len);
      int idx = si[0];
      int lo = idx - 9; lo = lo < 0 ? 0 : lo; if (lo > len-1) lo = len-1;
      int hi = idx + 9; hi = hi < 0 ? 0 : hi; if (hi > len-1) hi = len-1;
      meta[0] = lo; meta[1] = hi - lo + 1;
      lo_out[n] = lo; wl_out[n] = hi - lo + 1;
    }
    __syncthreads();
    int lo = meta[0], wl = meta[1];
    #pragma unroll
    for (int i=0;i<10;i++){
      int lin = i*256 + t;
      int r = lin >> 7, e4 = (lin & 127) << 2;
      if (r < WMAX){
        float4 v = make_float4(0.f,0.f,0.f,0.f);
        if (r < wl) v = *(const float4*)&enc[(size_t)((n<<10)+lo+r)*E_ + e4];
        *(float4*)&encw[(size_t)(n*WMAX + r)*E_ + e4] = v;
      }
    }
    if (t < 49){
      int tt = lo - 15 + t;
      paw[n*49 + t] = (tt >= 0 && tt < T_) ? prev[(n<<10)+tt] : 0.f;
    }
    if (t < 16)
      *(float4*)&x0[n*832 + 768 + (t<<2)] = *(const float4*)&spkr[(n<<6) + (t<<2)];

  } else if (bid < 96){
    gemm_body(hid, 1024, hid + 64*1024, 1024, Wdec,
              pA, 2048, 256, 1, 4, 8, bid - 64, t, *(GemmS*)smem_raw);

  } else if (bid < 104){
    // pre1 GEMM (8 blocks)
    int d = bid - 96;
    float* xs = (float*)smem_raw;
    #pragma unroll
    for (int i=0;i<9;i++){
      int q = i*256 + t;
      if (q < 2304){
        int b = q/36; int k4 = (q - b*36) << 2;
        float4 v;
        if (k4 < O_) v = *(const float4*)&indec[b*O_ + k4];
        else         v = *(const float4*)&spkr[(b<<6) + (k4-O_)];
        *(float4*)&xs[b*144 + k4] = v;
      }
    }
    __syncthreads();
    int bi = t >> 4, j = t & 15;
    int c0 = (d<<6) + (j<<2);
    float4 acc[4];
    #pragma unroll
    for (int rr=0;rr<4;rr++) acc[rr] = make_float4(0.f,0.f,0.f,0.f);
    #pragma unroll 4
    for (int k=0;k<144;k++){
      float4 wv = *(const float4*)&W1[(size_t)k*512 + c0];
      #pragma unroll
      for (int rr=0;rr<4;rr++){
        float xv = xs[((bi<<2)+rr)*144 + k];
        acc[rr].x += xv*wv.x; acc[rr].y += xv*wv.y; acc[rr].z += xv*wv.z; acc[rr].w += xv*wv.w;
      }
    }
    float4 bv = *(const float4*)&b1[c0];
    #pragma unroll
    for (int rr=0;rr<4;rr++){
      float4 o;
      o.x = fmaxf(acc[rr].x + bv.x, 0.f);
      o.y = fmaxf(acc[rr].y + bv.y, 0.f);
      o.z = fmaxf(acc[rr].z + bv.z, 0.f);
      o.w = fmaxf(acc[rr].w + bv.w, 0.f);
      *(float4*)&p1x[(size_t)((bi<<2)+rr)*512 + c0] = o;
    }

  } else {
    // Whh1 * hid1 rider (128 blocks, KS=2 -> pL1 slots 0-1)
    lstm_body(nullptr, 0, hid + 64*1024, nullptr, Whh1,
              pL1, 2, 1024, bid - 104, t, *(LstmS*)smem_raw);
  }
}

// =================== K2: enc GEMM (KS=2) | pre2 GEMM | Whh0 rider ===================
__global__ __launch_bounds__(256) void k_gemmB(const float* __restrict__ encw,
                                               const float* __restrict__ Wenc,
                                               float* __restrict__ pE,
                                               const float* __restrict__ p1x,
                                               const float* __restrict__ W2,
                                               float* __restrict__ pP2,
                                               const float* __restrict__ hid,
                                               const float* __restrict__ Whh0,
                                               float* __restrict__ pL0){
  __shared__ __align__(16) char smem_raw[sizeof(GemmS)];
  int bid = blockIdx.x, t = threadIdx.x;
  if (bid < 152)
    gemm_body(encw, 512, nullptr, 0, Wenc, pE, 512, 256, 19, 4, 2,
              bid, t, *(GemmS*)smem_raw);
  else if (bid < 168)
    gemm_body(p1x, 512, nullptr, 0, W2, pP2, 512, 256, 1, 4, 4,
              bid - 152, t, *(GemmS*)smem_raw);
  else
    lstm_body(nullptr, 0, hid, nullptr, Whh0,
              pL0, 2, 1024, bid - 168, t, *(LstmS*)smem_raw);
}

// =================== K3: attention epilogue+softmax+ctx | pre2 combine ===================
__global__ __launch_bounds__(256) void k_att2(const float* __restrict__ pE,
    const float* __restrict__ pA, const float* __restrict__ benc,
    const float* __restrict__ convw, const float* __restrict__ Wproj,
    const float* __restrict__ spkr, const float* __restrict__ Wspkr,
    const float* __restrict__ paw, const int* __restrict__ wl_w,
    const float* __restrict__ encw,
    const float* __restrict__ pP2, const float* __restrict__ b2,
    float* __restrict__ x0, float* __restrict__ ctxb){
  __shared__ float cw_s[256*31];
  __shared__ float cv_s[WMAX*256];
  __shared__ float attb_s[256];
  __shared__ float pa_s[49];
  __shared__ float wlog_s[WMAX];
  __shared__ float w_s[WMAX];
  int t = threadIdx.x;

  if (blockIdx.x >= 64){
    int idx = (blockIdx.x - 64)*256 + t;
    int b = idx >> 6; int c4 = (idx & 63) << 2;
    float4 v = *(const float4*)&b2[c4];
    #pragma unroll
    for (int p=0;p<4;p++){
      float4 u = *(const float4*)&pP2[(size_t)((p<<6)+b)*A_ + c4];
      v.x+=u.x; v.y+=u.y; v.z+=u.z; v.w+=u.w;
    }
    v.x=fmaxf(v.x,0.f); v.y=fmaxf(v.y,0.f); v.z=fmaxf(v.z,0.f); v.w=fmaxf(v.w,0.f);
    *(float4*)&x0[b*832 + c4] = v;
    return;
  }

  int n = blockIdx.x;
  int wl = wl_w[n];
  for (int lin = t; lin < 256*31; lin += 256) cw_s[lin] = convw[lin];
  if (t < 49) pa_s[t] = paw[n*49 + t];
  {
    float v = 0.f;
    #pragma unroll
    for (int p=0;p<8;p++) v += pA[(size_t)((p<<6)+n)*A_ + t];
    float sd = 0.f;
    #pragma unroll 16
    for (int s=0;s<S_;s++) sd += spkr[(n<<6)+s]*Wspkr[(s<<8)+t];
    attb_s[t] = v + sd/(1.f+fabsf(sd));
  }
  __syncthreads();
  for (int r=0; r<wl; ++r){
    float cv = 0.f;
    #pragma unroll
    for (int k=0;k<31;k++) cv += cw_s[t*31+k]*pa_s[r+k];
    cv_s[(r<<8)+t] = cv;
  }
  __syncthreads();
  int wid = t>>6, lane = t&63, a0 = lane<<2;
  float4 be4 = *(const float4*)&benc[a0];
  float4 wp4 = *(const float4*)&Wproj[a0];
  float4 ab4 = *(const float4*)&attb_s[a0];
  for (int r = wid; r < wl; r += 4){
    float4 sv = make_float4(0.f,0.f,0.f,0.f);
    #pragma unroll
    for (int ks=0;ks<2;ks++){
      const float4 u = *(const float4*)&pE[(size_t)(ks*1216 + n*WMAX + r)*A_ + a0];
      sv.x+=u.x; sv.y+=u.y; sv.z+=u.z; sv.w+=u.w;
    }
    sv.x += be4.x; sv.y += be4.y; sv.z += be4.z; sv.w += be4.w;
    const float4 cv4 = *(const float4*)&cv_s[(r<<8)+a0];
    float e0 = sv.x/(1.f+fabsf(sv.x)) + ab4.x + cv4.x;
    float e1 = sv.y/(1.f+fabsf(sv.y)) + ab4.y + cv4.y;
    float e2 = sv.z/(1.f+fabsf(sv.z)) + ab4.z + cv4.z;
    float e3 = sv.w/(1.f+fabsf(sv.w)) + ab4.w + cv4.w;
    float vv = tanhf(e0)*wp4.x + tanhf(e1)*wp4.y + tanhf(e2)*wp4.z + tanhf(e3)*wp4.w;
    #pragma unroll
    for (int off=32; off; off >>= 1) vv += __shfl_xor(vv, off, 64);
    if (lane == 0) wlog_s[r] = vv;
  }
  __syncthreads();
  if (t < 32){
    float l = (t < wl) ? wlog_s[t] : -1e30f;
    float mx = l;
    #pragma unroll
    for (int off=16; off; off >>= 1) mx = fmaxf(mx, __shfl_xor(mx, off, 32));
    float ex = (t < wl) ? expf(l - mx) : 0.f;
    float sm = ex;
    #pragma unroll
    for (int off=16; off; off >>= 1) sm += __shfl_xor(sm, off, 32);
    if (t < wl) w_s[t] = ex / sm;
  }
  __syncthreads();
  if (t < 128){
    float4 a = make_float4(0.f,0.f,0.f,0.f);
    for (int r=0; r<wl; ++r){
      float wv = w_s[r];
      const float4 ev = *(const float4*)&encw[(size_t)(n*WMAX + r)*E_ + (t<<2)];
      a.x += wv*ev.x; a.y += wv*ev.y; a.z += wv*ev.z; a.w += wv*ev.w;
    }
    *(float4*)&x0[n*832 + 256 + (t<<2)] = a;
    *(float4*)&ctxb[(n<<10) + (t<<2)] = a;
  }
}

// =================== LSTM combine: gates -> h (256 blocks) ===================
__global__ __launch_bounds__(256) void k_comb(const float* __restrict__ pL, int NS,
                                              const float* __restrict__ bih,
                                              const float* __restrict__ bhh,
                                              const float* __restrict__ cprev,
                                              float* __restrict__ dst){
  int bid = blockIdx.x, t = threadIdx.x;
  int b = bid >> 2; int u = ((bid & 3) << 8) + t;
  float g[4];
  #pragma unroll
  for (int gi=0; gi<4; ++gi){
    int col = (gi<<10) + u;
    float s = bih[col] + bhh[col];
    for (int q=0; q<NS; ++q) s += pL[(size_t)((q<<6)+b)*4096 + col];
    g[gi] = s;
  }
  float c = cprev[(b<<10)+u];
  float cn = sigmoidf_(g[1])*c + sigmoidf_(g[0])*tanhf(g[2]);
  dst[(b<<10)+u] = sigmoidf_(g[3])*tanhf(cn);
}

// =================== output combine ===================
__global__ __launch_bounds__(256) void k_comb_out(const float* __restrict__ pO,
                                                  const float* __restrict__ bout,
                                                  float* __restrict__ out){
  int idx = blockIdx.x*256 + threadIdx.x;
  int b = idx / 160; int c = idx - b*160;
  float s = bout[c];
  #pragma unroll
  for (int ks=0; ks<8; ++ks) s += pO[(size_t)((ks<<6)+b)*160 + c];
  out[idx] = s;
}

extern "C" void kernel_launch(void* const* d_in, const int* in_sizes, int n_in,
                              void* d_out, int out_size, void* d_ws, size_t ws_size,
                              hipStream_t stream){
  const float* enc   = (const float*)d_in[0];
  const float* indec = (const float*)d_in[1];
  const float* spkr  = (const float*)d_in[2];
  const float* prev  = (const float*)d_in[3];
  const float* hid   = (const float*)d_in[4];
  const float* cell  = (const float*)d_in[5];
  const int*   lens  = (const int*)d_in[6];
  const float* Wenc  = (const float*)d_in[7];
  const float* benc  = (const float*)d_in[8];
  const float* Wspkr = (const float*)d_in[9];
  const float* convw = (const float*)d_in[10];
  const float* Wdec  = (const float*)d_in[11];
  const float* Wproj = (const float*)d_in[12];
  /* d_in[13] = b_proj: uniform shift, cancels in normalized attention weights */
  const float* Wpre1 = (const float*)d_in[14];
  const float* bpre1 = (const float*)d_in[15];
  const float* Wpre2 = (const float*)d_in[16];
  const float* bpre2 = (const float*)d_in[17];
  const float* Wih0  = (const float*)d_in[18];
  const float* Whh0  = (const float*)d_in[19];
  const float* bih0  = (const float*)d_in[20];
  const float* bhh0  = (const float*)d_in[21];
  const float* Wih1  = (const float*)d_in[22];
  const float* Whh1  = (const float*)d_in[23];
  const float* bih1  = (const float*)d_in[24];
  const float* bhh1  = (const float*)d_in[25];
  const float* Wout  = (const float*)d_in[26];
  const float* bout  = (const float*)d_in[27];
  (void)in_sizes; (void)n_in; (void)out_size; (void)ws_size;

  float* ws = (float*)d_ws;
  size_t off = 0;
  auto alloc = [&](size_t nf){ float* p = ws + off; off += nf; return p; };
  float* pA     = alloc((size_t)8*64*256);
  float* p1x    = alloc((size_t)64*512);
  float* pP2    = alloc((size_t)4*64*256);
  float* x0     = alloc(64*832);
  float* ctxb   = alloc((size_t)64*1024);
  float* h1     = alloc((size_t)64*1024);
  float* h2b    = alloc((size_t)64*1024);
  float* pO     = alloc((size_t)8*64*160);
  float* paw    = alloc(64*49 + 15);
  int*   lo_w   = (int*)alloc(64);
  int*   wl_w   = (int*)alloc(64);
  float* encw   = alloc((size_t)64*WMAX*512);
  float* pE     = alloc((size_t)2*1216*256);
  float* pL0    = alloc(6*SLOT);   // slots 0-1: Whh0 (KS=2), slots 2-5: Wih0 (KS=4)
  float* pL1    = alloc(6*SLOT);   // slots 0-1: Whh1 (KS=2), slots 2-5: Wih1 (KS=4)
  float* out    = (float*)d_out;

  // K1: front (0-63) | Wdec (64-95) | pre1 (96-103) | Whh1*hid1 (104-231)
  k_front3<<<232,256,0,stream>>>(prev, lens, enc, indec, spkr,
                                 Wpre1, bpre1, hid, Wdec, Whh1,
                                 lo_w, wl_w, encw, paw, x0, pA, p1x, pL1);
  // K2: enc GEMM KS=2 (0-151) | pre2 (152-167) | Whh0*hid0 (168-295)
  k_gemmB<<<296,256,0,stream>>>(encw, Wenc, pE, p1x, Wpre2, pP2,
                                hid, Whh0, pL0);
  // K3: attention (0-63) | pre2 combine (64-79)
  k_att2<<<80,256,0,stream>>>(pE, pA, benc, convw, Wproj, spkr, Wspkr,
                              paw, wl_w, encw, pP2, bpre2, x0, ctxb);
  // K4: Wih0 * x0 (K=832) -> pL0 slots 2-5
  k_lstmI<<<256,256,0,stream>>>(x0, 832, Wih0, pL0 + 2*SLOT, 4, 832);
  // K5: combine layer 0 -> h1 (6 slots)
  k_comb<<<256,256,0,stream>>>(pL0, 6, bih0, bhh0, cell, h1);
  // K6: Wih1 * h1 (K=1024) -> pL1 slots 2-5
  k_lstmI<<<256,256,0,stream>>>(h1, 1024, Wih1, pL1 + 2*SLOT, 4, 1024);
  // K7: combine layer 1 -> h2b (6 slots)
  k_comb<<<256,256,0,stream>>>(pL1, 6, bih1, bhh1, cell + 64*1024, h2b);
  // K8: out GEMM (tiled, Wout read once) -> partials
  k_gemmA<<<1*3*8,256,0,stream>>>(h2b, 1024, ctxb, 1024, Wout,
                                  pO, 1536, 160, 1, 3, 8);
  // K9: output combine
  k_comb_out<<<40,256,0,stream>>>(pO, bout, out);
}

// Round 10
// 122.055 us; speedup vs baseline: 1.3093x; 1.0781x over previous
//
#include <hip/hip_runtime.h>
#include <math.h>

#define N_    64
#define T_    1024
#define E_    512
#define A_    256
#define S_    64
#define O_    80
#define HID_  1024
#define WMAX  19
#define SLOT  ((size_t)64*4096)

typedef __attribute__((ext_vector_type(8))) short bh8;
typedef __attribute__((ext_vector_type(4))) float fx4;

__device__ __forceinline__ float sigmoidf_(float x){ return 1.f/(1.f+expf(-x)); }
__device__ __forceinline__ unsigned pk2_(float a, float b){
  unsigned ua = __float_as_uint(a), ub = __float_as_uint(b);
  ua = (ua + 0x7fffu + ((ua>>16)&1u)) >> 16;
  ub = (ub + 0x7fffu + ((ub>>16)&1u)) >> 16;
  return ua | (ub<<16);
}

// =================== generic tiled GEMM body (fp32) ===================
struct GemmS { float x_s[2][64][68]; float w_s[2][64][68]; };

__device__ void gemm_body(const float* __restrict__ X, int xStride,
                          const float* __restrict__ X2, int Ksplit,
                          const float* __restrict__ W,
                          float* __restrict__ partial,
                          int K, int C, int nMt, int nCt, int KS,
                          int bid, int t, GemmS& sm){
  int mt = bid % nMt; int rest = bid / nMt;
  int ct = rest % nCt; int ks = rest / nCt;
  int m0 = mt << 6; int c0 = ct << 6;
  int M = nMt << 6;
  int nch = (K + 63) >> 6;
  int ch0 = (ks*nch)/KS, ch1 = ((ks+1)*nch)/KS;
  int bi = t >> 4, j = t & 15;
  float4 px[4], pw[4];

  auto ld = [&](int ch){
    int k0 = ch << 6;
    #pragma unroll
    for (int i=0;i<4;i++){
      int lin = i*256+t; int bl = lin>>4, kq = lin&15;
      int k = k0 + (kq<<2);
      float4 v = make_float4(0.f,0.f,0.f,0.f);
      if (k < K){
        if (X2 != nullptr && k >= Ksplit){
          v = *(const float4*)&X2[(size_t)bl*1024 + (k - Ksplit)];
        } else {
          v = *(const float4*)&X[(size_t)(m0+bl)*xStride + k];
        }
      }
      px[i] = v;
    }
    #pragma unroll
    for (int i=0;i<4;i++){
      int lin = i*256+t; int kk = lin>>4, cq = lin&15;
      int k = k0 + kk, c = c0 + (cq<<2);
      float4 v = make_float4(0.f,0.f,0.f,0.f);
      if (k < K && c < C) v = *(const float4*)&W[(size_t)k*C + c];
      pw[i] = v;
    }
  };
  auto st = [&](int buf){
    #pragma unroll
    for (int i=0;i<4;i++){
      int lin = i*256+t; int bl = lin>>4, kq = lin&15;
      *(float4*)&sm.x_s[buf][bl][kq<<2] = px[i];
    }
    #pragma unroll
    for (int i=0;i<4;i++){
      int lin = i*256+t; int kk = lin>>4, cq = lin&15;
      *(float4*)&sm.w_s[buf][kk][cq<<2] = pw[i];
    }
  };

  float4 acc[4];
  #pragma unroll
  for (int m=0;m<4;m++) acc[m] = make_float4(0.f,0.f,0.f,0.f);

  ld(ch0); st(0); __syncthreads();
  int buf = 0;
  for (int ch = ch0; ch < ch1; ++ch){
    if (ch+1 < ch1) ld(ch+1);
    #pragma unroll
    for (int kq=0;kq<16;kq++){
      float4 xv[4], wv[4];
      #pragma unroll
      for (int bb=0;bb<4;bb++) xv[bb] = *(const float4*)&sm.x_s[buf][(bi<<2)+bb][kq<<2];
      #pragma unroll
      for (int kk=0;kk<4;kk++) wv[kk] = *(const float4*)&sm.w_s[buf][(kq<<2)+kk][j<<2];
      #pragma unroll
      for (int bb=0;bb<4;bb++){
        float s0=xv[bb].x, s1=xv[bb].y, s2=xv[bb].z, s3=xv[bb].w;
        acc[bb].x += s0*wv[0].x + s1*wv[1].x + s2*wv[2].x + s3*wv[3].x;
        acc[bb].y += s0*wv[0].y + s1*wv[1].y + s2*wv[2].y + s3*wv[3].y;
        acc[bb].z += s0*wv[0].z + s1*wv[1].z + s2*wv[2].z + s3*wv[3].z;
        acc[bb].w += s0*wv[0].w + s1*wv[1].w + s2*wv[2].w + s3*wv[3].w;
      }
    }
    if (ch+1 < ch1){ st(buf^1); __syncthreads(); }
    buf ^= 1;
  }
  int c = c0 + (j<<2);
  if (c < C){
    #pragma unroll
    for (int bb=0;bb<4;bb++){
      int bl = (bi<<2)+bb;
      *(float4*)&partial[(size_t)(ks*M + m0 + bl)*C + c] = acc[bb];
    }
  }
}

__global__ __launch_bounds__(256) void k_gemmA(const float* __restrict__ X, int xStride,
                                               const float* __restrict__ X2, int Ksplit,
                                               const float* __restrict__ W,
                                               float* __restrict__ partial,
                                               int K, int C, int nMt, int nCt, int KS){
  __shared__ GemmS sm;
  gemm_body(X,xStride,X2,Ksplit,W,partial,K,C,nMt,nCt,KS,blockIdx.x,threadIdx.x,sm);
}

// =================== LSTM gates GEMM body (bf16 MFMA) ===================
struct LstmS { uint4 WlA[2][512]; uint4 XlA[2][512]; float outb[64][68]; };

__device__ void lstm_body(const float* __restrict__ xA, int KxA,
                          const float* __restrict__ xB,
                          const float* __restrict__ Wih,
                          const float* __restrict__ Whh,
                          float* __restrict__ partial, int KS, int Klen,
                          int bid, int t, LstmS& sm){
  int Mblk = bid & 63;
  int ks = bid >> 6;
  int r0 = Mblk << 6;
  int nch = Klen >> 6;
  int ch0 = (ks*nch)/KS, ch1 = ((ks+1)*nch)/KS;
  int wid = t >> 6, lane = t & 63;

  float4 rw[2][2], rx[2][2];
  auto ld = [&](int ch){
    int k0 = ch << 6;
    #pragma unroll
    for (int u=0;u<2;u++){
      int g = t + (u<<8); int row = g>>3; int k = k0 + ((g&7)<<3);
      const float* sw;
      const float* sx;
      if (k < KxA){ sw = &Wih[(size_t)(r0+row)*KxA + k]; sx = &xA[(size_t)row*KxA + k]; }
      else        { sw = &Whh[((size_t)(r0+row)<<10) + (k - KxA)]; sx = &xB[((size_t)row<<10) + (k - KxA)]; }
      rw[u][0] = *(const float4*)sw; rw[u][1] = *(const float4*)(sw+4);
      rx[u][0] = *(const float4*)sx; rx[u][1] = *(const float4*)(sx+4);
    }
  };
  auto cvst = [&](int buf){
    #pragma unroll
    for (int u=0;u<2;u++){
      int g = t + (u<<8); int row = g>>3, gk = g&7;
      int byte = row*128 + ((gk ^ (row&7))<<4);
      uint4 vw, vx;
      vw.x = pk2_(rw[u][0].x, rw[u][0].y); vw.y = pk2_(rw[u][0].z, rw[u][0].w);
      vw.z = pk2_(rw[u][1].x, rw[u][1].y); vw.w = pk2_(rw[u][1].z, rw[u][1].w);
      vx.x = pk2_(rx[u][0].x, rx[u][0].y); vx.y = pk2_(rx[u][0].z, rx[u][0].w);
      vx.z = pk2_(rx[u][1].x, rx[u][1].y); vx.w = pk2_(rx[u][1].z, rx[u][1].w);
      *(uint4*)((char*)&sm.WlA[buf][0] + byte) = vw;
      *(uint4*)((char*)&sm.XlA[buf][0] + byte) = vx;
    }
  };

  fx4 acc[4];
  #pragma unroll
  for (int nt=0;nt<4;nt++) acc[nt] = (fx4){0.f,0.f,0.f,0.f};

  ld(ch0); cvst(0); __syncthreads();
  int buf = 0;
  for (int ch = ch0; ch < ch1; ++ch){
    if (ch+1 < ch1) ld(ch+1);
    int rowA = (wid<<4) + (lane&15);
    #pragma unroll
    for (int s=0;s<2;s++){
      int gA = (s<<2) + (lane>>4);
      bh8 a = *(bh8*)((char*)&sm.WlA[buf][0] + rowA*128 + ((gA ^ (rowA&7))<<4));
      #pragma unroll
      for (int nt=0;nt<4;nt++){
        int rowB = (nt<<4) + (lane&15);
        bh8 bf = *(bh8*)((char*)&sm.XlA[buf][0] + rowB*128 + ((gA ^ (rowB&7))<<4));
        acc[nt] = __builtin_amdgcn_mfma_f32_16x16x32_bf16(a, bf, acc[nt], 0, 0, 0);
      }
    }
    if (ch+1 < ch1){ cvst(buf^1); __syncthreads(); }
    buf ^= 1;
  }
  __syncthreads();
  #pragma unroll
  for (int nt=0;nt<4;nt++){
    #pragma unroll
    for (int q=0;q<4;q++)
      sm.outb[(nt<<4)+(lane&15)][(wid<<4)+((lane>>4)<<2)+q] = acc[nt][q];
  }
  __syncthreads();
  #pragma unroll
  for (int i=0;i<4;i++){
    int idx = i*256+t; int b = idx>>4; int r4 = (idx&15)<<2;
    float4 o = *(const float4*)&sm.outb[b][r4];
    *(float4*)&partial[(size_t)((ks<<6)+b)*4096 + r0 + r4] = o;
  }
}

// =================== M-tiled MFMA GEMM: out[m][c] = X[m][k]·WT[c][k] ===================
__device__ void mfma_mt_body(const float* __restrict__ X, int xStride,
                             const float* __restrict__ WT, int wStride,
                             float* __restrict__ partial, int M, int Cout,
                             int nMt, int nRt, int KS, int Klen,
                             int bid, int t, LstmS& sm){
  int mt = bid % nMt; int rest = bid / nMt;
  int rt = rest % nRt; int ks = rest / nRt;
  int m0 = mt << 6; int r0 = rt << 6;
  int nch = Klen >> 6;
  int ch0 = (ks*nch)/KS, ch1 = ((ks+1)*nch)/KS;
  int wid = t >> 6, lane = t & 63;

  float4 rw[2][2], rx[2][2];
  auto ld = [&](int ch){
    int k0 = ch << 6;
    #pragma unroll
    for (int u=0;u<2;u++){
      int g = t + (u<<8); int row = g>>3; int k = k0 + ((g&7)<<3);
      const float* sw = &WT[(size_t)(r0+row)*wStride + k];
      const float* sx = &X[(size_t)(m0+row)*xStride + k];
      rw[u][0] = *(const float4*)sw; rw[u][1] = *(const float4*)(sw+4);
      rx[u][0] = *(const float4*)sx; rx[u][1] = *(const float4*)(sx+4);
    }
  };
  auto cvst = [&](int buf){
    #pragma unroll
    for (int u=0;u<2;u++){
      int g = t + (u<<8); int row = g>>3, gk = g&7;
      int byte = row*128 + ((gk ^ (row&7))<<4);
      uint4 vw, vx;
      vw.x = pk2_(rw[u][0].x, rw[u][0].y); vw.y = pk2_(rw[u][0].z, rw[u][0].w);
      vw.z = pk2_(rw[u][1].x, rw[u][1].y); vw.w = pk2_(rw[u][1].z, rw[u][1].w);
      vx.x = pk2_(rx[u][0].x, rx[u][0].y); vx.y = pk2_(rx[u][0].z, rx[u][0].w);
      vx.z = pk2_(rx[u][1].x, rx[u][1].y); vx.w = pk2_(rx[u][1].z, rx[u][1].w);
      *(uint4*)((char*)&sm.WlA[buf][0] + byte) = vw;
      *(uint4*)((char*)&sm.XlA[buf][0] + byte) = vx;
    }
  };

  fx4 acc[4];
  #pragma unroll
  for (int nt=0;nt<4;nt++) acc[nt] = (fx4){0.f,0.f,0.f,0.f};

  ld(ch0); cvst(0); __syncthreads();
  int buf = 0;
  for (int ch = ch0; ch < ch1; ++ch){
    if (ch+1 < ch1) ld(ch+1);
    int rowA = (wid<<4) + (lane&15);
    #pragma unroll
    for (int s=0;s<2;s++){
      int gA = (s<<2) + (lane>>4);
      bh8 a = *(bh8*)((char*)&sm.WlA[buf][0] + rowA*128 + ((gA ^ (rowA&7))<<4));
      #pragma unroll
      for (int nt=0;nt<4;nt++){
        int rowB = (nt<<4) + (lane&15);
        bh8 bf = *(bh8*)((char*)&sm.XlA[buf][0] + rowB*128 + ((gA ^ (rowB&7))<<4));
        acc[nt] = __builtin_amdgcn_mfma_f32_16x16x32_bf16(a, bf, acc[nt], 0, 0, 0);
      }
    }
    if (ch+1 < ch1){ cvst(buf^1); __syncthreads(); }
    buf ^= 1;
  }
  __syncthreads();
  #pragma unroll
  for (int nt=0;nt<4;nt++){
    #pragma unroll
    for (int q=0;q<4;q++)
      sm.outb[(nt<<4)+(lane&15)][(wid<<4)+((lane>>4)<<2)+q] = acc[nt][q];
  }
  __syncthreads();
  #pragma unroll
  for (int i=0;i<4;i++){
    int idx = i*256+t; int b = idx>>4; int r4 = (idx&15)<<2;
    float4 o = *(const float4*)&sm.outb[b][r4];
    *(float4*)&partial[(size_t)(ks*M + m0 + b)*Cout + r0 + r4] = o;
  }
}

// I-part standalone kernel (Wih * x only)
__global__ __launch_bounds__(256) void k_lstmI(const float* __restrict__ xA, int KxA,
                                               const float* __restrict__ Wih,
                                               float* __restrict__ partial,
                                               int KS, int Klen){
  __shared__ LstmS sm;
  lstm_body(xA, KxA, nullptr, Wih, nullptr, partial, KS, Klen,
            blockIdx.x, threadIdx.x, sm);
}

// =================== K1: argmax+gather | Wdec GEMM | pre1 | WencT transpose | Whh1 rider ===================
__global__ __launch_bounds__(256) void k_front3(
    const float* __restrict__ prev, const int* __restrict__ lens,
    const float* __restrict__ enc, const float* __restrict__ indec,
    const float* __restrict__ spkr,
    const float* __restrict__ W1, const float* __restrict__ b1,
    const float* __restrict__ hid, const float* __restrict__ Wdec,
    const float* __restrict__ Wenc, const float* __restrict__ Whh1,
    int* __restrict__ lo_out, int* __restrict__ wl_out,
    float* __restrict__ encw, float* __restrict__ paw,
    float* __restrict__ x0, float* __restrict__ pA,
    float* __restrict__ p1x, float* __restrict__ WencT,
    float* __restrict__ pL1){
  __shared__ __align__(16) char smem_raw[sizeof(GemmS)];
  int bid = blockIdx.x, t = threadIdx.x;

  if (bid < 64){
    int n = bid;
    float* sv = (float*)smem_raw;
    int*   si = (int*)(smem_raw + 1024);
    int*   meta = (int*)(smem_raw + 2048);
    const float* p = prev + n*T_;
    float bv = -1e30f; int bi2 = 0x7fffffff;
    #pragma unroll
    for (int i=0;i<4;i++){
      int idx = t + (i<<8);
      float v = p[idx];
      if (v > bv || (v == bv && idx < bi2)){ bv = v; bi2 = idx; }
    }
    sv[t]=bv; si[t]=bi2; __syncthreads();
    for (int s=128; s>0; s>>=1){
      if (t < s){
        float v2 = sv[t+s]; int i2 = si[t+s];
        if (v2 > sv[t] || (v2 == sv[t] && i2 < si[t])){ sv[t]=v2; si[t]=i2; }
      }
      __syncthreads();
    }
    if (t==0){
      int len = lens[n]; len = len < 1 ? 1 : (len > T_ ? T_ : len);
      int idx = si[0];
      int lo = idx - 9; lo = lo < 0 ? 0 : lo; if (lo > len-1) lo = len-1;
      int hi = idx + 9; hi = hi < 0 ? 0 : hi; if (hi > len-1) hi = len-1;
      meta[0] = lo; meta[1] = hi - lo + 1;
      lo_out[n] = lo; wl_out[n] = hi - lo + 1;
    }
    __syncthreads();
    int lo = meta[0], wl = meta[1];
    #pragma unroll
    for (int i=0;i<10;i++){
      int lin = i*256 + t;
      int r = lin >> 7, e4 = (lin & 127) << 2;
      if (r < WMAX){
        float4 v = make_float4(0.f,0.f,0.f,0.f);
        if (r < wl) v = *(const float4*)&enc[(size_t)((n<<10)+lo+r)*E_ + e4];
        *(float4*)&encw[(size_t)(n*WMAX + r)*E_ + e4] = v;
      }
    }
    if (t < 49){
      int tt = lo - 15 + t;
      paw[n*49 + t] = (tt >= 0 && tt < T_) ? prev[(n<<10)+tt] : 0.f;
    }
    if (t < 16)
      *(float4*)&x0[n*832 + 768 + (t<<2)] = *(const float4*)&spkr[(n<<6) + (t<<2)];

  } else if (bid < 96){
    gemm_body(hid, 1024, hid + 64*1024, 1024, Wdec,
              pA, 2048, 256, 1, 4, 8, bid - 64, t, *(GemmS*)smem_raw);

  } else if (bid < 104){
    // pre1 GEMM (8 blocks)
    int d = bid - 96;
    float* xs = (float*)smem_raw;
    #pragma unroll
    for (int i=0;i<9;i++){
      int q = i*256 + t;
      if (q < 2304){
        int b = q/36; int k4 = (q - b*36) << 2;
        float4 v;
        if (k4 < O_) v = *(const float4*)&indec[b*O_ + k4];
        else         v = *(const float4*)&spkr[(b<<6) + (k4-O_)];
        *(float4*)&xs[b*144 + k4] = v;
      }
    }
    __syncthreads();
    int bi = t >> 4, j = t & 15;
    int c0 = (d<<6) + (j<<2);
    float4 acc[4];
    #pragma unroll
    for (int rr=0;rr<4;rr++) acc[rr] = make_float4(0.f,0.f,0.f,0.f);
    #pragma unroll 4
    for (int k=0;k<144;k++){
      float4 wv = *(const float4*)&W1[(size_t)k*512 + c0];
      #pragma unroll
      for (int rr=0;rr<4;rr++){
        float xv = xs[((bi<<2)+rr)*144 + k];
        acc[rr].x += xv*wv.x; acc[rr].y += xv*wv.y; acc[rr].z += xv*wv.z; acc[rr].w += xv*wv.w;
      }
    }
    float4 bv = *(const float4*)&b1[c0];
    #pragma unroll
    for (int rr=0;rr<4;rr++){
      float4 o;
      o.x = fmaxf(acc[rr].x + bv.x, 0.f);
      o.y = fmaxf(acc[rr].y + bv.y, 0.f);
      o.z = fmaxf(acc[rr].z + bv.z, 0.f);
      o.w = fmaxf(acc[rr].w + bv.w, 0.f);
      *(float4*)&p1x[(size_t)((bi<<2)+rr)*512 + c0] = o;
    }

  } else if (bid < 136){
    // WencT transpose: Wenc [512][256] -> WencT [256][512]  (32 blocks of 64x64 tiles)
    int ti = bid - 104;
    int kt = ti & 7, ct = ti >> 3;
    int k0 = kt<<6, c0 = ct<<6;
    float* tile = (float*)smem_raw;   // [64][65]
    #pragma unroll
    for (int i=0;i<16;i++){
      int lin = i*256+t; int kk = lin>>6, cc = lin&63;
      tile[kk*65+cc] = Wenc[(size_t)(k0+kk)*256 + c0+cc];
    }
    __syncthreads();
    #pragma unroll
    for (int i=0;i<16;i++){
      int lin = i*256+t; int cc = lin>>6, kk = lin&63;
      WencT[(size_t)(c0+cc)*512 + k0+kk] = tile[kk*65+cc];
    }

  } else {
    // Whh1 * hid1 rider (128 blocks, KS=2 -> pL1 slots 0-1)
    lstm_body(nullptr, 0, hid + 64*1024, nullptr, Whh1,
              pL1, 2, 1024, bid - 136, t, *(LstmS*)smem_raw);
  }
}

// =================== K2: enc MFMA GEMM (KS=2) | pre2 GEMM | Whh0 rider ===================
__global__ __launch_bounds__(256) void k_gemmB(const float* __restrict__ encw,
                                               const float* __restrict__ WencT,
                                               float* __restrict__ pE,
                                               const float* __restrict__ p1x,
                                               const float* __restrict__ W2,
                                               float* __restrict__ pP2,
                                               const float* __restrict__ hid,
                                               const float* __restrict__ Whh0,
                                               float* __restrict__ pL0){
  __shared__ __align__(16) char smem_raw[sizeof(GemmS)];
  int bid = blockIdx.x, t = threadIdx.x;
  if (bid < 152)
    mfma_mt_body(encw, 512, WencT, 512, pE, 1216, 256, 19, 4, 2, 512,
                 bid, t, *(LstmS*)smem_raw);
  else if (bid < 168)
    gemm_body(p1x, 512, nullptr, 0, W2, pP2, 512, 256, 1, 4, 4,
              bid - 152, t, *(GemmS*)smem_raw);
  else
    lstm_body(nullptr, 0, hid, nullptr, Whh0,
              pL0, 2, 1024, bid - 168, t, *(LstmS*)smem_raw);
}

// =================== K3: attention epilogue+softmax+ctx | pre2 combine ===================
__global__ __launch_bounds__(256) void k_att2(const float* __restrict__ pE,
    const float* __restrict__ pA, const float* __restrict__ benc,
    const float* __restrict__ convw, const float* __restrict__ Wproj,
    const float* __restrict__ spkr, const float* __restrict__ Wspkr,
    const float* __restrict__ paw, const int* __restrict__ wl_w,
    const float* __restrict__ encw,
    const float* __restrict__ pP2, const float* __restrict__ b2,
    float* __restrict__ x0, float* __restrict__ ctxb){
  __shared__ float cw_s[256*31];
  __shared__ float cv_s[WMAX*256];
  __shared__ float attb_s[256];
  __shared__ float pa_s[49];
  __shared__ float wlog_s[WMAX];
  __shared__ float w_s[WMAX];
  int t = threadIdx.x;

  if (blockIdx.x >= 64){
    int idx = (blockIdx.x - 64)*256 + t;
    int b = idx >> 6; int c4 = (idx & 63) << 2;
    float4 v = *(const float4*)&b2[c4];
    #pragma unroll
    for (int p=0;p<4;p++){
      float4 u = *(const float4*)&pP2[(size_t)((p<<6)+b)*A_ + c4];
      v.x+=u.x; v.y+=u.y; v.z+=u.z; v.w+=u.w;
    }
    v.x=fmaxf(v.x,0.f); v.y=fmaxf(v.y,0.f); v.z=fmaxf(v.z,0.f); v.w=fmaxf(v.w,0.f);
    *(float4*)&x0[b*832 + c4] = v;
    return;
  }

  int n = blockIdx.x;
  int wl = wl_w[n];
  for (int lin = t; lin < 256*31; lin += 256) cw_s[lin] = convw[lin];
  if (t < 49) pa_s[t] = paw[n*49 + t];
  {
    float v = 0.f;
    #pragma unroll
    for (int p=0;p<8;p++) v += pA[(size_t)((p<<6)+n)*A_ + t];
    float sd = 0.f;
    #pragma unroll 16
    for (int s=0;s<S_;s++) sd += spkr[(n<<6)+s]*Wspkr[(s<<8)+t];
    attb_s[t] = v + sd/(1.f+fabsf(sd));
  }
  __syncthreads();
  for (int r=0; r<wl; ++r){
    float cv = 0.f;
    #pragma unroll
    for (int k=0;k<31;k++) cv += cw_s[t*31+k]*pa_s[r+k];
    cv_s[(r<<8)+t] = cv;
  }
  __syncthreads();
  int wid = t>>6, lane = t&63, a0 = lane<<2;
  float4 be4 = *(const float4*)&benc[a0];
  float4 wp4 = *(const float4*)&Wproj[a0];
  float4 ab4 = *(const float4*)&attb_s[a0];
  for (int r = wid; r < wl; r += 4){
    float4 sv = make_float4(0.f,0.f,0.f,0.f);
    #pragma unroll
    for (int ks=0;ks<2;ks++){
      const float4 u = *(const float4*)&pE[(size_t)(ks*1216 + n*WMAX + r)*A_ + a0];
      sv.x+=u.x; sv.y+=u.y; sv.z+=u.z; sv.w+=u.w;
    }
    sv.x += be4.x; sv.y += be4.y; sv.z += be4.z; sv.w += be4.w;
    const float4 cv4 = *(const float4*)&cv_s[(r<<8)+a0];
    float e0 = sv.x/(1.f+fabsf(sv.x)) + ab4.x + cv4.x;
    float e1 = sv.y/(1.f+fabsf(sv.y)) + ab4.y + cv4.y;
    float e2 = sv.z/(1.f+fabsf(sv.z)) + ab4.z + cv4.z;
    float e3 = sv.w/(1.f+fabsf(sv.w)) + ab4.w + cv4.w;
    float vv = tanhf(e0)*wp4.x + tanhf(e1)*wp4.y + tanhf(e2)*wp4.z + tanhf(e3)*wp4.w;
    #pragma unroll
    for (int off=32; off; off >>= 1) vv += __shfl_xor(vv, off, 64);
    if (lane == 0) wlog_s[r] = vv;
  }
  __syncthreads();
  if (t < 32){
    float l = (t < wl) ? wlog_s[t] : -1e30f;
    float mx = l;
    #pragma unroll
    for (int off=16; off; off >>= 1) mx = fmaxf(mx, __shfl_xor(mx, off, 32));
    float ex = (t < wl) ? expf(l - mx) : 0.f;
    float sm = ex;
    #pragma unroll
    for (int off=16; off; off >>= 1) sm += __shfl_xor(sm, off, 32);
    if (t < wl) w_s[t] = ex / sm;
  }
  __syncthreads();
  if (t < 128){
    float4 a = make_float4(0.f,0.f,0.f,0.f);
    for (int r=0; r<wl; ++r){
      float wv = w_s[r];
      const float4 ev = *(const float4*)&encw[(size_t)(n*WMAX + r)*E_ + (t<<2)];
      a.x += wv*ev.x; a.y += wv*ev.y; a.z += wv*ev.z; a.w += wv*ev.w;
    }
    *(float4*)&x0[n*832 + 256 + (t<<2)] = a;
    *(float4*)&ctxb[(n<<10) + (t<<2)] = a;
  }
}

// =================== LSTM combine: gates -> h (256 blocks) ===================
__global__ __launch_bounds__(256) void k_comb(const float* __restrict__ pL, int NS,
                                              const float* __restrict__ bih,
                                              const float* __restrict__ bhh,
                                              const float* __restrict__ cprev,
                                              float* __restrict__ dst){
  int bid = blockIdx.x, t = threadIdx.x;
  int b = bid >> 2; int u = ((bid & 3) << 8) + t;
  float g[4];
  #pragma unroll
  for (int gi=0; gi<4; ++gi){
    int col = (gi<<10) + u;
    float s = bih[col] + bhh[col];
    for (int q=0; q<NS; ++q) s += pL[(size_t)((q<<6)+b)*4096 + col];
    g[gi] = s;
  }
  float c = cprev[(b<<10)+u];
  float cn = sigmoidf_(g[1])*c + sigmoidf_(g[0])*tanhf(g[2]);
  dst[(b<<10)+u] = sigmoidf_(g[3])*tanhf(cn);
}

// =================== output combine ===================
__global__ __launch_bounds__(256) void k_comb_out(const float* __restrict__ pO,
                                                  const float* __restrict__ bout,
                                                  float* __restrict__ out){
  int idx = blockIdx.x*256 + threadIdx.x;
  int b = idx / 160; int c = idx - b*160;
  float s = bout[c];
  #pragma unroll
  for (int ks=0; ks<8; ++ks) s += pO[(size_t)((ks<<6)+b)*160 + c];
  out[idx] = s;
}

extern "C" void kernel_launch(void* const* d_in, const int* in_sizes, int n_in,
                              void* d_out, int out_size, void* d_ws, size_t ws_size,
                              hipStream_t stream){
  const float* enc   = (const float*)d_in[0];
  const float* indec = (const float*)d_in[1];
  const float* spkr  = (const float*)d_in[2];
  const float* prev  = (const float*)d_in[3];
  const float* hid   = (const float*)d_in[4];
  const float* cell  = (const float*)d_in[5];
  const int*   lens  = (const int*)d_in[6];
  const float* Wenc  = (const float*)d_in[7];
  const float* benc  = (const float*)d_in[8];
  const float* Wspkr = (const float*)d_in[9];
  const float* convw = (const float*)d_in[10];
  const float* Wdec  = (const float*)d_in[11];
  const float* Wproj = (const float*)d_in[12];
  /* d_in[13] = b_proj: uniform shift, cancels in normalized attention weights */
  const float* Wpre1 = (const float*)d_in[14];
  const float* bpre1 = (const float*)d_in[15];
  const float* Wpre2 = (const float*)d_in[16];
  const float* bpre2 = (const float*)d_in[17];
  const float* Wih0  = (const float*)d_in[18];
  const float* Whh0  = (const float*)d_in[19];
  const float* bih0  = (const float*)d_in[20];
  const float* bhh0  = (const float*)d_in[21];
  const float* Wih1  = (const float*)d_in[22];
  const float* Whh1  = (const float*)d_in[23];
  const float* bih1  = (const float*)d_in[24];
  const float* bhh1  = (const float*)d_in[25];
  const float* Wout  = (const float*)d_in[26];
  const float* bout  = (const float*)d_in[27];
  (void)in_sizes; (void)n_in; (void)out_size; (void)ws_size;

  float* ws = (float*)d_ws;
  size_t off = 0;
  auto alloc = [&](size_t nf){ float* p = ws + off; off += nf; return p; };
  float* pA     = alloc((size_t)8*64*256);
  float* p1x    = alloc((size_t)64*512);
  float* pP2    = alloc((size_t)4*64*256);
  float* x0     = alloc(64*832);
  float* ctxb   = alloc((size_t)64*1024);
  float* h1     = alloc((size_t)64*1024);
  float* h2b    = alloc((size_t)64*1024);
  float* pO     = alloc((size_t)8*64*160);
  float* paw    = alloc(64*49 + 15);
  int*   lo_w   = (int*)alloc(64);
  int*   wl_w   = (int*)alloc(64);
  float* WencT  = alloc((size_t)256*512);
  float* encw   = alloc((size_t)64*WMAX*512);
  float* pE     = alloc((size_t)2*1216*256);
  float* pL0    = alloc(6*SLOT);   // slots 0-1: Whh0 (KS=2), slots 2-5: Wih0 (KS=4)
  float* pL1    = alloc(6*SLOT);   // slots 0-1: Whh1 (KS=2), slots 2-5: Wih1 (KS=4)
  float* out    = (float*)d_out;

  // K1: front (0-63) | Wdec (64-95) | pre1 (96-103) | WencT (104-135) | Whh1 (136-263)
  k_front3<<<264,256,0,stream>>>(prev, lens, enc, indec, spkr,
                                 Wpre1, bpre1, hid, Wdec, Wenc, Whh1,
                                 lo_w, wl_w, encw, paw, x0, pA, p1x, WencT, pL1);
  // K2: enc MFMA KS=2 (0-151) | pre2 (152-167) | Whh0*hid0 (168-295)
  k_gemmB<<<296,256,0,stream>>>(encw, WencT, pE, p1x, Wpre2, pP2,
                                hid, Whh0, pL0);
  // K3: attention (0-63) | pre2 combine (64-79)
  k_att2<<<80,256,0,stream>>>(pE, pA, benc, convw, Wproj, spkr, Wspkr,
                              paw, wl_w, encw, pP2, bpre2, x0, ctxb);
  // K4: Wih0 * x0 (K=832) -> pL0 slots 2-5
  k_lstmI<<<256,256,0,stream>>>(x0, 832, Wih0, pL0 + 2*SLOT, 4, 832);
  // K5: combine layer 0 -> h1 (6 slots)
  k_comb<<<256,256,0,stream>>>(pL0, 6, bih0, bhh0, cell, h1);
  // K6: Wih1 * h1 (K=1024) -> pL1 slots 2-5
  k_lstmI<<<256,256,0,stream>>>(h1, 1024, Wih1, pL1 + 2*SLOT, 4, 1024);
  // K7: combine layer 1 -> h2b (6 slots)
  k_comb<<<256,256,0,stream>>>(pL1, 6, bih1, bhh1, cell + 64*1024, h2b);
  // K8: out GEMM (tiled, Wout read once) -> partials
  k_gemmA<<<1*3*8,256,0,stream>>>(h2b, 1024, ctxb, 1024, Wout,
                                  pO, 1536, 160, 1, 3, 8);
  // K9: output combine
  k_comb_out<<<40,256,0,stream>>>(pO, bout, out);
}

// Round 11
// 112.069 us; speedup vs baseline: 1.4260x; 1.0891x over previous
//
#include <hip/hip_runtime.h>
#include <math.h>

#define N_    64
#define T_    1024
#define E_    512
#define A_    256
#define S_    64
#define O_    80
#define HID_  1024
#define WMAX  19
#define SLOT  ((size_t)64*4096)

typedef __attribute__((ext_vector_type(8))) short bh8;
typedef __attribute__((ext_vector_type(4))) float fx4;

__device__ __forceinline__ float sigmoidf_(float x){ return 1.f/(1.f+expf(-x)); }
__device__ __forceinline__ unsigned pk2_(float a, float b){
  unsigned ua = __float_as_uint(a), ub = __float_as_uint(b);
  ua = (ua + 0x7fffu + ((ua>>16)&1u)) >> 16;
  ub = (ub + 0x7fffu + ((ub>>16)&1u)) >> 16;
  return ua | (ub<<16);
}

// =================== generic tiled GEMM body (fp32) ===================
struct GemmS { float x_s[2][64][68]; float w_s[2][64][68]; };

__device__ void gemm_body(const float* __restrict__ X, int xStride,
                          const float* __restrict__ X2, int Ksplit,
                          const float* __restrict__ W,
                          float* __restrict__ partial,
                          int K, int C, int nMt, int nCt, int KS,
                          int bid, int t, GemmS& sm){
  int mt = bid % nMt; int rest = bid / nMt;
  int ct = rest % nCt; int ks = rest / nCt;
  int m0 = mt << 6; int c0 = ct << 6;
  int M = nMt << 6;
  int nch = (K + 63) >> 6;
  int ch0 = (ks*nch)/KS, ch1 = ((ks+1)*nch)/KS;
  int bi = t >> 4, j = t & 15;
  float4 px[4], pw[4];

  auto ld = [&](int ch){
    int k0 = ch << 6;
    #pragma unroll
    for (int i=0;i<4;i++){
      int lin = i*256+t; int bl = lin>>4, kq = lin&15;
      int k = k0 + (kq<<2);
      float4 v = make_float4(0.f,0.f,0.f,0.f);
      if (k < K){
        if (X2 != nullptr && k >= Ksplit){
          v = *(const float4*)&X2[(size_t)bl*1024 + (k - Ksplit)];
        } else {
          v = *(const float4*)&X[(size_t)(m0+bl)*xStride + k];
        }
      }
      px[i] = v;
    }
    #pragma unroll
    for (int i=0;i<4;i++){
      int lin = i*256+t; int kk = lin>>4, cq = lin&15;
      int k = k0 + kk, c = c0 + (cq<<2);
      float4 v = make_float4(0.f,0.f,0.f,0.f);
      if (k < K && c < C) v = *(const float4*)&W[(size_t)k*C + c];
      pw[i] = v;
    }
  };
  auto st = [&](int buf){
    #pragma unroll
    for (int i=0;i<4;i++){
      int lin = i*256+t; int bl = lin>>4, kq = lin&15;
      *(float4*)&sm.x_s[buf][bl][kq<<2] = px[i];
    }
    #pragma unroll
    for (int i=0;i<4;i++){
      int lin = i*256+t; int kk = lin>>4, cq = lin&15;
      *(float4*)&sm.w_s[buf][kk][cq<<2] = pw[i];
    }
  };

  float4 acc[4];
  #pragma unroll
  for (int m=0;m<4;m++) acc[m] = make_float4(0.f,0.f,0.f,0.f);

  ld(ch0); st(0); __syncthreads();
  int buf = 0;
  for (int ch = ch0; ch < ch1; ++ch){
    if (ch+1 < ch1) ld(ch+1);
    #pragma unroll
    for (int kq=0;kq<16;kq++){
      float4 xv[4], wv[4];
      #pragma unroll
      for (int bb=0;bb<4;bb++) xv[bb] = *(const float4*)&sm.x_s[buf][(bi<<2)+bb][kq<<2];
      #pragma unroll
      for (int kk=0;kk<4;kk++) wv[kk] = *(const float4*)&sm.w_s[buf][(kq<<2)+kk][j<<2];
      #pragma unroll
      for (int bb=0;bb<4;bb++){
        float s0=xv[bb].x, s1=xv[bb].y, s2=xv[bb].z, s3=xv[bb].w;
        acc[bb].x += s0*wv[0].x + s1*wv[1].x + s2*wv[2].x + s3*wv[3].x;
        acc[bb].y += s0*wv[0].y + s1*wv[1].y + s2*wv[2].y + s3*wv[3].y;
        acc[bb].z += s0*wv[0].z + s1*wv[1].z + s2*wv[2].z + s3*wv[3].z;
        acc[bb].w += s0*wv[0].w + s1*wv[1].w + s2*wv[2].w + s3*wv[3].w;
      }
    }
    if (ch+1 < ch1){ st(buf^1); __syncthreads(); }
    buf ^= 1;
  }
  int c = c0 + (j<<2);
  if (c < C){
    #pragma unroll
    for (int bb=0;bb<4;bb++){
      int bl = (bi<<2)+bb;
      *(float4*)&partial[(size_t)(ks*M + m0 + bl)*C + c] = acc[bb];
    }
  }
}

__global__ __launch_bounds__(256) void k_gemmA(const float* __restrict__ X, int xStride,
                                               const float* __restrict__ X2, int Ksplit,
                                               const float* __restrict__ W,
                                               float* __restrict__ partial,
                                               int K, int C, int nMt, int nCt, int KS){
  __shared__ GemmS sm;
  gemm_body(X,xStride,X2,Ksplit,W,partial,K,C,nMt,nCt,KS,blockIdx.x,threadIdx.x,sm);
}

// =================== LSTM gates GEMM body (bf16 MFMA) ===================
struct LstmS { uint4 WlA[2][512]; uint4 XlA[2][512]; float outb[64][68]; };

__device__ void lstm_body(const float* __restrict__ xA, int KxA,
                          const float* __restrict__ xB,
                          const float* __restrict__ Wih,
                          const float* __restrict__ Whh,
                          float* __restrict__ partial, int KS, int Klen,
                          int bid, int t, LstmS& sm){
  int Mblk = bid & 63;
  int ks = bid >> 6;
  int r0 = Mblk << 6;
  int nch = Klen >> 6;
  int ch0 = (ks*nch)/KS, ch1 = ((ks+1)*nch)/KS;
  int wid = t >> 6, lane = t & 63;

  float4 rw[2][2], rx[2][2];
  auto ld = [&](int ch){
    int k0 = ch << 6;
    #pragma unroll
    for (int u=0;u<2;u++){
      int g = t + (u<<8); int row = g>>3; int k = k0 + ((g&7)<<3);
      const float* sw;
      const float* sx;
      if (k < KxA){ sw = &Wih[(size_t)(r0+row)*KxA + k]; sx = &xA[(size_t)row*KxA + k]; }
      else        { sw = &Whh[((size_t)(r0+row)<<10) + (k - KxA)]; sx = &xB[((size_t)row<<10) + (k - KxA)]; }
      rw[u][0] = *(const float4*)sw; rw[u][1] = *(const float4*)(sw+4);
      rx[u][0] = *(const float4*)sx; rx[u][1] = *(const float4*)(sx+4);
    }
  };
  auto cvst = [&](int buf){
    #pragma unroll
    for (int u=0;u<2;u++){
      int g = t + (u<<8); int row = g>>3, gk = g&7;
      int byte = row*128 + ((gk ^ (row&7))<<4);
      uint4 vw, vx;
      vw.x = pk2_(rw[u][0].x, rw[u][0].y); vw.y = pk2_(rw[u][0].z, rw[u][0].w);
      vw.z = pk2_(rw[u][1].x, rw[u][1].y); vw.w = pk2_(rw[u][1].z, rw[u][1].w);
      vx.x = pk2_(rx[u][0].x, rx[u][0].y); vx.y = pk2_(rx[u][0].z, rx[u][0].w);
      vx.z = pk2_(rx[u][1].x, rx[u][1].y); vx.w = pk2_(rx[u][1].z, rx[u][1].w);
      *(uint4*)((char*)&sm.WlA[buf][0] + byte) = vw;
      *(uint4*)((char*)&sm.XlA[buf][0] + byte) = vx;
    }
  };

  fx4 acc[4];
  #pragma unroll
  for (int nt=0;nt<4;nt++) acc[nt] = (fx4){0.f,0.f,0.f,0.f};

  ld(ch0); cvst(0); __syncthreads();
  int buf = 0;
  for (int ch = ch0; ch < ch1; ++ch){
    if (ch+1 < ch1) ld(ch+1);
    int rowA = (wid<<4) + (lane&15);
    #pragma unroll
    for (int s=0;s<2;s++){
      int gA = (s<<2) + (lane>>4);
      bh8 a = *(bh8*)((char*)&sm.WlA[buf][0] + rowA*128 + ((gA ^ (rowA&7))<<4));
      #pragma unroll
      for (int nt=0;nt<4;nt++){
        int rowB = (nt<<4) + (lane&15);
        bh8 bf = *(bh8*)((char*)&sm.XlA[buf][0] + rowB*128 + ((gA ^ (rowB&7))<<4));
        acc[nt] = __builtin_amdgcn_mfma_f32_16x16x32_bf16(a, bf, acc[nt], 0, 0, 0);
      }
    }
    if (ch+1 < ch1){ cvst(buf^1); __syncthreads(); }
    buf ^= 1;
  }
  __syncthreads();
  #pragma unroll
  for (int nt=0;nt<4;nt++){
    #pragma unroll
    for (int q=0;q<4;q++)
      sm.outb[(nt<<4)+(lane&15)][(wid<<4)+((lane>>4)<<2)+q] = acc[nt][q];
  }
  __syncthreads();
  #pragma unroll
  for (int i=0;i<4;i++){
    int idx = i*256+t; int b = idx>>4; int r4 = (idx&15)<<2;
    float4 o = *(const float4*)&sm.outb[b][r4];
    *(float4*)&partial[(size_t)((ks<<6)+b)*4096 + r0 + r4] = o;
  }
}

// =================== M-tiled MFMA GEMM: out[m][c] = X[m][k]·WT[c][k] ===================
__device__ void mfma_mt_body(const float* __restrict__ X, int xStride,
                             const float* __restrict__ WT, int wStride,
                             float* __restrict__ partial, int M, int Cout,
                             int nMt, int nRt, int KS, int Klen,
                             int bid, int t, LstmS& sm){
  int mt = bid % nMt; int rest = bid / nMt;
  int rt = rest % nRt; int ks = rest / nRt;
  int m0 = mt << 6; int r0 = rt << 6;
  int nch = Klen >> 6;
  int ch0 = (ks*nch)/KS, ch1 = ((ks+1)*nch)/KS;
  int wid = t >> 6, lane = t & 63;

  float4 rw[2][2], rx[2][2];
  auto ld = [&](int ch){
    int k0 = ch << 6;
    #pragma unroll
    for (int u=0;u<2;u++){
      int g = t + (u<<8); int row = g>>3; int k = k0 + ((g&7)<<3);
      const float* sw = &WT[(size_t)(r0+row)*wStride + k];
      const float* sx = &X[(size_t)(m0+row)*xStride + k];
      rw[u][0] = *(const float4*)sw; rw[u][1] = *(const float4*)(sw+4);
      rx[u][0] = *(const float4*)sx; rx[u][1] = *(const float4*)(sx+4);
    }
  };
  auto cvst = [&](int buf){
    #pragma unroll
    for (int u=0;u<2;u++){
      int g = t + (u<<8); int row = g>>3, gk = g&7;
      int byte = row*128 + ((gk ^ (row&7))<<4);
      uint4 vw, vx;
      vw.x = pk2_(rw[u][0].x, rw[u][0].y); vw.y = pk2_(rw[u][0].z, rw[u][0].w);
      vw.z = pk2_(rw[u][1].x, rw[u][1].y); vw.w = pk2_(rw[u][1].z, rw[u][1].w);
      vx.x = pk2_(rx[u][0].x, rx[u][0].y); vx.y = pk2_(rx[u][0].z, rx[u][0].w);
      vx.z = pk2_(rx[u][1].x, rx[u][1].y); vx.w = pk2_(rx[u][1].z, rx[u][1].w);
      *(uint4*)((char*)&sm.WlA[buf][0] + byte) = vw;
      *(uint4*)((char*)&sm.XlA[buf][0] + byte) = vx;
    }
  };

  fx4 acc[4];
  #pragma unroll
  for (int nt=0;nt<4;nt++) acc[nt] = (fx4){0.f,0.f,0.f,0.f};

  ld(ch0); cvst(0); __syncthreads();
  int buf = 0;
  for (int ch = ch0; ch < ch1; ++ch){
    if (ch+1 < ch1) ld(ch+1);
    int rowA = (wid<<4) + (lane&15);
    #pragma unroll
    for (int s=0;s<2;s++){
      int gA = (s<<2) + (lane>>4);
      bh8 a = *(bh8*)((char*)&sm.WlA[buf][0] + rowA*128 + ((gA ^ (rowA&7))<<4));
      #pragma unroll
      for (int nt=0;nt<4;nt++){
        int rowB = (nt<<4) + (lane&15);
        bh8 bf = *(bh8*)((char*)&sm.XlA[buf][0] + rowB*128 + ((gA ^ (rowB&7))<<4));
        acc[nt] = __builtin_amdgcn_mfma_f32_16x16x32_bf16(a, bf, acc[nt], 0, 0, 0);
      }
    }
    if (ch+1 < ch1){ cvst(buf^1); __syncthreads(); }
    buf ^= 1;
  }
  __syncthreads();
  #pragma unroll
  for (int nt=0;nt<4;nt++){
    #pragma unroll
    for (int q=0;q<4;q++)
      sm.outb[(nt<<4)+(lane&15)][(wid<<4)+((lane>>4)<<2)+q] = acc[nt][q];
  }
  __syncthreads();
  #pragma unroll
  for (int i=0;i<4;i++){
    int idx = i*256+t; int b = idx>>4; int r4 = (idx&15)<<2;
    float4 o = *(const float4*)&sm.outb[b][r4];
    *(float4*)&partial[(size_t)(ks*M + m0 + b)*Cout + r0 + r4] = o;
  }
}

// I-part standalone kernel (Wih * x only)
__global__ __launch_bounds__(256) void k_lstmI(const float* __restrict__ xA, int KxA,
                                               const float* __restrict__ Wih,
                                               float* __restrict__ partial,
                                               int KS, int Klen){
  __shared__ LstmS sm;
  lstm_body(xA, KxA, nullptr, Wih, nullptr, partial, KS, Klen,
            blockIdx.x, threadIdx.x, sm);
}

// =================== K1: argmax+gather | Wdec GEMM | pre1 | WencT transpose | Whh1 rider ===================
__global__ __launch_bounds__(256) void k_front3(
    const float* __restrict__ prev, const int* __restrict__ lens,
    const float* __restrict__ enc, const float* __restrict__ indec,
    const float* __restrict__ spkr,
    const float* __restrict__ W1, const float* __restrict__ b1,
    const float* __restrict__ hid, const float* __restrict__ Wdec,
    const float* __restrict__ Wenc, const float* __restrict__ Whh1,
    int* __restrict__ lo_out, int* __restrict__ wl_out,
    float* __restrict__ encw, float* __restrict__ paw,
    float* __restrict__ x0, float* __restrict__ pA,
    float* __restrict__ p1x, float* __restrict__ WencT,
    float* __restrict__ pL1){
  __shared__ __align__(16) char smem_raw[sizeof(GemmS)];
  int bid = blockIdx.x, t = threadIdx.x;

  if (bid < 64){
    int n = bid;
    float* sv = (float*)smem_raw;
    int*   si = (int*)(smem_raw + 1024);
    int*   meta = (int*)(smem_raw + 2048);
    const float* p = prev + n*T_;
    float bv = -1e30f; int bi2 = 0x7fffffff;
    #pragma unroll
    for (int i=0;i<4;i++){
      int idx = t + (i<<8);
      float v = p[idx];
      if (v > bv || (v == bv && idx < bi2)){ bv = v; bi2 = idx; }
    }
    sv[t]=bv; si[t]=bi2; __syncthreads();
    for (int s=128; s>0; s>>=1){
      if (t < s){
        float v2 = sv[t+s]; int i2 = si[t+s];
        if (v2 > sv[t] || (v2 == sv[t] && i2 < si[t])){ sv[t]=v2; si[t]=i2; }
      }
      __syncthreads();
    }
    if (t==0){
      int len = lens[n]; len = len < 1 ? 1 : (len > T_ ? T_ : len);
      int idx = si[0];
      int lo = idx - 9; lo = lo < 0 ? 0 : lo; if (lo > len-1) lo = len-1;
      int hi = idx + 9; hi = hi < 0 ? 0 : hi; if (hi > len-1) hi = len-1;
      meta[0] = lo; meta[1] = hi - lo + 1;
      lo_out[n] = lo; wl_out[n] = hi - lo + 1;
    }
    __syncthreads();
    int lo = meta[0], wl = meta[1];
    #pragma unroll
    for (int i=0;i<10;i++){
      int lin = i*256 + t;
      int r = lin >> 7, e4 = (lin & 127) << 2;
      if (r < WMAX){
        float4 v = make_float4(0.f,0.f,0.f,0.f);
        if (r < wl) v = *(const float4*)&enc[(size_t)((n<<10)+lo+r)*E_ + e4];
        *(float4*)&encw[(size_t)(n*WMAX + r)*E_ + e4] = v;
      }
    }
    if (t < 49){
      int tt = lo - 15 + t;
      paw[n*49 + t] = (tt >= 0 && tt < T_) ? prev[(n<<10)+tt] : 0.f;
    }
    if (t < 16)
      *(float4*)&x0[n*832 + 768 + (t<<2)] = *(const float4*)&spkr[(n<<6) + (t<<2)];

  } else if (bid < 128){
    // Wdec GEMM: KS=16, 64 blocks
    gemm_body(hid, 1024, hid + 64*1024, 1024, Wdec,
              pA, 2048, 256, 1, 4, 16, bid - 64, t, *(GemmS*)smem_raw);

  } else if (bid < 136){
    // pre1 GEMM (8 blocks)
    int d = bid - 128;
    float* xs = (float*)smem_raw;
    #pragma unroll
    for (int i=0;i<9;i++){
      int q = i*256 + t;
      if (q < 2304){
        int b = q/36; int k4 = (q - b*36) << 2;
        float4 v;
        if (k4 < O_) v = *(const float4*)&indec[b*O_ + k4];
        else         v = *(const float4*)&spkr[(b<<6) + (k4-O_)];
        *(float4*)&xs[b*144 + k4] = v;
      }
    }
    __syncthreads();
    int bi = t >> 4, j = t & 15;
    int c0 = (d<<6) + (j<<2);
    float4 acc[4];
    #pragma unroll
    for (int rr=0;rr<4;rr++) acc[rr] = make_float4(0.f,0.f,0.f,0.f);
    #pragma unroll 4
    for (int k=0;k<144;k++){
      float4 wv = *(const float4*)&W1[(size_t)k*512 + c0];
      #pragma unroll
      for (int rr=0;rr<4;rr++){
        float xv = xs[((bi<<2)+rr)*144 + k];
        acc[rr].x += xv*wv.x; acc[rr].y += xv*wv.y; acc[rr].z += xv*wv.z; acc[rr].w += xv*wv.w;
      }
    }
    float4 bv = *(const float4*)&b1[c0];
    #pragma unroll
    for (int rr=0;rr<4;rr++){
      float4 o;
      o.x = fmaxf(acc[rr].x + bv.x, 0.f);
      o.y = fmaxf(acc[rr].y + bv.y, 0.f);
      o.z = fmaxf(acc[rr].z + bv.z, 0.f);
      o.w = fmaxf(acc[rr].w + bv.w, 0.f);
      *(float4*)&p1x[(size_t)((bi<<2)+rr)*512 + c0] = o;
    }

  } else if (bid < 168){
    // WencT transpose: Wenc [512][256] -> WencT [256][512]  (32 blocks of 64x64 tiles)
    int ti = bid - 136;
    int kt = ti & 7, ct = ti >> 3;
    int k0 = kt<<6, c0 = ct<<6;
    float* tile = (float*)smem_raw;   // [64][65]
    #pragma unroll
    for (int i=0;i<16;i++){
      int lin = i*256+t; int kk = lin>>6, cc = lin&63;
      tile[kk*65+cc] = Wenc[(size_t)(k0+kk)*256 + c0+cc];
    }
    __syncthreads();
    #pragma unroll
    for (int i=0;i<16;i++){
      int lin = i*256+t; int cc = lin>>6, kk = lin&63;
      WencT[(size_t)(c0+cc)*512 + k0+kk] = tile[kk*65+cc];
    }

  } else {
    // Whh1 * hid1 rider (128 blocks, KS=2 -> pL1 slots 0-1)
    lstm_body(nullptr, 0, hid + 64*1024, nullptr, Whh1,
              pL1, 2, 1024, bid - 168, t, *(LstmS*)smem_raw);
  }
}

// =================== K2: enc MFMA GEMM (KS=2) | pre2 GEMM | Whh0 rider ===================
__global__ __launch_bounds__(256) void k_gemmB(const float* __restrict__ encw,
                                               const float* __restrict__ WencT,
                                               float* __restrict__ pE,
                                               const float* __restrict__ p1x,
                                               const float* __restrict__ W2,
                                               float* __restrict__ pP2,
                                               const float* __restrict__ hid,
                                               const float* __restrict__ Whh0,
                                               float* __restrict__ pL0){
  __shared__ __align__(16) char smem_raw[sizeof(GemmS)];
  int bid = blockIdx.x, t = threadIdx.x;
  if (bid < 152)
    mfma_mt_body(encw, 512, WencT, 512, pE, 1216, 256, 19, 4, 2, 512,
                 bid, t, *(LstmS*)smem_raw);
  else if (bid < 168)
    gemm_body(p1x, 512, nullptr, 0, W2, pP2, 512, 256, 1, 4, 4,
              bid - 152, t, *(GemmS*)smem_raw);
  else
    lstm_body(nullptr, 0, hid, nullptr, Whh0,
              pL0, 2, 1024, bid - 168, t, *(LstmS*)smem_raw);
}

// =================== K3: attention epilogue+softmax+ctx | pre2 combine ===================
__global__ __launch_bounds__(256) void k_att2(const float* __restrict__ pE,
    const float* __restrict__ pA, const float* __restrict__ benc,
    const float* __restrict__ convw, const float* __restrict__ Wproj,
    const float* __restrict__ spkr, const float* __restrict__ Wspkr,
    const float* __restrict__ paw, const int* __restrict__ wl_w,
    const float* __restrict__ encw,
    const float* __restrict__ pP2, const float* __restrict__ b2,
    float* __restrict__ x0, float* __restrict__ ctxb){
  __shared__ float cw_s[256*31];
  __shared__ float cv_s[WMAX*256];
  __shared__ float attb_s[256];
  __shared__ float pa_s[49];
  __shared__ float wlog_s[WMAX];
  __shared__ float w_s[WMAX];
  int t = threadIdx.x;

  if (blockIdx.x >= 64){
    int idx = (blockIdx.x - 64)*256 + t;
    int b = idx >> 6; int c4 = (idx & 63) << 2;
    float4 v = *(const float4*)&b2[c4];
    #pragma unroll
    for (int p=0;p<4;p++){
      float4 u = *(const float4*)&pP2[(size_t)((p<<6)+b)*A_ + c4];
      v.x+=u.x; v.y+=u.y; v.z+=u.z; v.w+=u.w;
    }
    v.x=fmaxf(v.x,0.f); v.y=fmaxf(v.y,0.f); v.z=fmaxf(v.z,0.f); v.w=fmaxf(v.w,0.f);
    *(float4*)&x0[b*832 + c4] = v;
    return;
  }

  int n = blockIdx.x;
  int wl = wl_w[n];
  for (int lin = t; lin < 256*31; lin += 256) cw_s[lin] = convw[lin];
  if (t < 49) pa_s[t] = paw[n*49 + t];
  {
    float v = 0.f;
    #pragma unroll
    for (int p=0;p<16;p++) v += pA[(size_t)((p<<6)+n)*A_ + t];
    float sd = 0.f;
    #pragma unroll 16
    for (int s=0;s<S_;s++) sd += spkr[(n<<6)+s]*Wspkr[(s<<8)+t];
    attb_s[t] = v + sd/(1.f+fabsf(sd));
  }
  __syncthreads();
  for (int r=0; r<wl; ++r){
    float cv = 0.f;
    #pragma unroll
    for (int k=0;k<31;k++) cv += cw_s[t*31+k]*pa_s[r+k];
    cv_s[(r<<8)+t] = cv;
  }
  __syncthreads();
  int wid = t>>6, lane = t&63, a0 = lane<<2;
  float4 be4 = *(const float4*)&benc[a0];
  float4 wp4 = *(const float4*)&Wproj[a0];
  float4 ab4 = *(const float4*)&attb_s[a0];
  for (int r = wid; r < wl; r += 4){
    float4 sv = make_float4(0.f,0.f,0.f,0.f);
    #pragma unroll
    for (int ks=0;ks<2;ks++){
      const float4 u = *(const float4*)&pE[(size_t)(ks*1216 + n*WMAX + r)*A_ + a0];
      sv.x+=u.x; sv.y+=u.y; sv.z+=u.z; sv.w+=u.w;
    }
    sv.x += be4.x; sv.y += be4.y; sv.z += be4.z; sv.w += be4.w;
    const float4 cv4 = *(const float4*)&cv_s[(r<<8)+a0];
    float e0 = sv.x/(1.f+fabsf(sv.x)) + ab4.x + cv4.x;
    float e1 = sv.y/(1.f+fabsf(sv.y)) + ab4.y + cv4.y;
    float e2 = sv.z/(1.f+fabsf(sv.z)) + ab4.z + cv4.z;
    float e3 = sv.w/(1.f+fabsf(sv.w)) + ab4.w + cv4.w;
    float vv = tanhf(e0)*wp4.x + tanhf(e1)*wp4.y + tanhf(e2)*wp4.z + tanhf(e3)*wp4.w;
    #pragma unroll
    for (int off=32; off; off >>= 1) vv += __shfl_xor(vv, off, 64);
    if (lane == 0) wlog_s[r] = vv;
  }
  __syncthreads();
  if (t < 32){
    float l = (t < wl) ? wlog_s[t] : -1e30f;
    float mx = l;
    #pragma unroll
    for (int off=16; off; off >>= 1) mx = fmaxf(mx, __shfl_xor(mx, off, 32));
    float ex = (t < wl) ? expf(l - mx) : 0.f;
    float sm = ex;
    #pragma unroll
    for (int off=16; off; off >>= 1) sm += __shfl_xor(sm, off, 32);
    if (t < wl) w_s[t] = ex / sm;
  }
  __syncthreads();
  if (t < 128){
    float4 a = make_float4(0.f,0.f,0.f,0.f);
    for (int r=0; r<wl; ++r){
      float wv = w_s[r];
      const float4 ev = *(const float4*)&encw[(size_t)(n*WMAX + r)*E_ + (t<<2)];
      a.x += wv*ev.x; a.y += wv*ev.y; a.z += wv*ev.z; a.w += wv*ev.w;
    }
    *(float4*)&x0[n*832 + 256 + (t<<2)] = a;
    *(float4*)&ctxb[(n<<10) + (t<<2)] = a;
  }
}

// =================== LSTM combine: gates -> h (256 blocks) ===================
__global__ __launch_bounds__(256) void k_comb(const float* __restrict__ pL, int NS,
                                              const float* __restrict__ bih,
                                              const float* __restrict__ bhh,
                                              const float* __restrict__ cprev,
                                              float* __restrict__ dst){
  int bid = blockIdx.x, t = threadIdx.x;
  int b = bid >> 2; int u = ((bid & 3) << 8) + t;
  float g[4];
  #pragma unroll
  for (int gi=0; gi<4; ++gi){
    int col = (gi<<10) + u;
    float s = bih[col] + bhh[col];
    for (int q=0; q<NS; ++q) s += pL[(size_t)((q<<6)+b)*4096 + col];
    g[gi] = s;
  }
  float c = cprev[(b<<10)+u];
  float cn = sigmoidf_(g[1])*c + sigmoidf_(g[0])*tanhf(g[2]);
  dst[(b<<10)+u] = sigmoidf_(g[3])*tanhf(cn);
}

// =================== output combine ===================
__global__ __launch_bounds__(256) void k_comb_out(const float* __restrict__ pO,
                                                  const float* __restrict__ bout,
                                                  float* __restrict__ out){
  int idx = blockIdx.x*256 + threadIdx.x;
  int b = idx / 160; int c = idx - b*160;
  float s = bout[c];
  #pragma unroll
  for (int ks=0; ks<16; ++ks) s += pO[(size_t)((ks<<6)+b)*160 + c];
  out[idx] = s;
}

extern "C" void kernel_launch(void* const* d_in, const int* in_sizes, int n_in,
                              void* d_out, int out_size, void* d_ws, size_t ws_size,
                              hipStream_t stream){
  const float* enc   = (const float*)d_in[0];
  const float* indec = (const float*)d_in[1];
  const float* spkr  = (const float*)d_in[2];
  const float* prev  = (const float*)d_in[3];
  const float* hid   = (const float*)d_in[4];
  const float* cell  = (const float*)d_in[5];
  const int*   lens  = (const int*)d_in[6];
  const float* Wenc  = (const float*)d_in[7];
  const float* benc  = (const float*)d_in[8];
  const float* Wspkr = (const float*)d_in[9];
  const float* convw = (const float*)d_in[10];
  const float* Wdec  = (const float*)d_in[11];
  const float* Wproj = (const float*)d_in[12];
  /* d_in[13] = b_proj: uniform shift, cancels in normalized attention weights */
  const float* Wpre1 = (const float*)d_in[14];
  const float* bpre1 = (const float*)d_in[15];
  const float* Wpre2 = (const float*)d_in[16];
  const float* bpre2 = (const float*)d_in[17];
  const float* Wih0  = (const float*)d_in[18];
  const float* Whh0  = (const float*)d_in[19];
  const float* bih0  = (const float*)d_in[20];
  const float* bhh0  = (const float*)d_in[21];
  const float* Wih1  = (const float*)d_in[22];
  const float* Whh1  = (const float*)d_in[23];
  const float* bih1  = (const float*)d_in[24];
  const float* bhh1  = (const float*)d_in[25];
  const float* Wout  = (const float*)d_in[26];
  const float* bout  = (const float*)d_in[27];
  (void)in_sizes; (void)n_in; (void)out_size; (void)ws_size;

  float* ws = (float*)d_ws;
  size_t off = 0;
  auto alloc = [&](size_t nf){ float* p = ws + off; off += nf; return p; };
  float* pA     = alloc((size_t)16*64*256);
  float* p1x    = alloc((size_t)64*512);
  float* pP2    = alloc((size_t)4*64*256);
  float* x0     = alloc(64*832);
  float* ctxb   = alloc((size_t)64*1024);
  float* h1     = alloc((size_t)64*1024);
  float* h2b    = alloc((size_t)64*1024);
  float* pO     = alloc((size_t)16*64*160);
  float* paw    = alloc(64*49 + 15);
  int*   lo_w   = (int*)alloc(64);
  int*   wl_w   = (int*)alloc(64);
  float* WencT  = alloc((size_t)256*512);
  float* encw   = alloc((size_t)64*WMAX*512);
  float* pE     = alloc((size_t)2*1216*256);
  float* pL0    = alloc(6*SLOT);   // slots 0-1: Whh0 (KS=2), slots 2-5: Wih0 (KS=4)
  float* pL1    = alloc(6*SLOT);   // slots 0-1: Whh1 (KS=2), slots 2-5: Wih1 (KS=4)
  float* out    = (float*)d_out;

  // K1: front (0-63) | Wdec KS=16 (64-127) | pre1 (128-135) | WencT (136-167) | Whh1 (168-295)
  k_front3<<<296,256,0,stream>>>(prev, lens, enc, indec, spkr,
                                 Wpre1, bpre1, hid, Wdec, Wenc, Whh1,
                                 lo_w, wl_w, encw, paw, x0, pA, p1x, WencT, pL1);
  // K2: enc MFMA KS=2 (0-151) | pre2 (152-167) | Whh0*hid0 (168-295)
  k_gemmB<<<296,256,0,stream>>>(encw, WencT, pE, p1x, Wpre2, pP2,
                                hid, Whh0, pL0);
  // K3: attention (0-63) | pre2 combine (64-79)
  k_att2<<<80,256,0,stream>>>(pE, pA, benc, convw, Wproj, spkr, Wspkr,
                              paw, wl_w, encw, pP2, bpre2, x0, ctxb);
  // K4: Wih0 * x0 (K=832) -> pL0 slots 2-5
  k_lstmI<<<256,256,0,stream>>>(x0, 832, Wih0, pL0 + 2*SLOT, 4, 832);
  // K5: combine layer 0 -> h1 (6 slots)
  k_comb<<<256,256,0,stream>>>(pL0, 6, bih0, bhh0, cell, h1);
  // K6: Wih1 * h1 (K=1024) -> pL1 slots 2-5
  k_lstmI<<<256,256,0,stream>>>(h1, 1024, Wih1, pL1 + 2*SLOT, 4, 1024);
  // K7: combine layer 1 -> h2b (6 slots)
  k_comb<<<256,256,0,stream>>>(pL1, 6, bih1, bhh1, cell + 64*1024, h2b);
  // K8: out GEMM (KS=16, 48 blocks) -> partials
  k_gemmA<<<1*3*16,256,0,stream>>>(h2b, 1024, ctxb, 1024, Wout,
                                   pO, 1536, 160, 1, 3, 16);
  // K9: output combine (16 slots)
  k_comb_out<<<40,256,0,stream>>>(pO, bout, out);
}

// Round 12
// 107.393 us; speedup vs baseline: 1.4881x; 1.0435x over previous
//
#include <hip/hip_runtime.h>
#include <math.h>

#define N_    64
#define T_    1024
#define E_    512
#define A_    256
#define S_    64
#define O_    80
#define HID_  1024
#define WMAX  19
#define SLOT  ((size_t)64*4096)

typedef __attribute__((ext_vector_type(8))) short bh8;
typedef __attribute__((ext_vector_type(4))) float fx4;

__device__ __forceinline__ float sigmoidf_(float x){ return 1.f/(1.f+expf(-x)); }
__device__ __forceinline__ unsigned pk2_(float a, float b){
  unsigned ua = __float_as_uint(a), ub = __float_as_uint(b);
  ua = (ua + 0x7fffu + ((ua>>16)&1u)) >> 16;
  ub = (ub + 0x7fffu + ((ub>>16)&1u)) >> 16;
  return ua | (ub<<16);
}

// =================== generic tiled GEMM body (fp32) — used only by K8 ===================
struct GemmS { float x_s[2][64][68]; float w_s[2][64][68]; };

__device__ void gemm_body(const float* __restrict__ X, int xStride,
                          const float* __restrict__ X2, int Ksplit,
                          const float* __restrict__ W,
                          float* __restrict__ partial,
                          int K, int C, int nMt, int nCt, int KS,
                          int bid, int t, GemmS& sm){
  int mt = bid % nMt; int rest = bid / nMt;
  int ct = rest % nCt; int ks = rest / nCt;
  int m0 = mt << 6; int c0 = ct << 6;
  int M = nMt << 6;
  int nch = (K + 63) >> 6;
  int ch0 = (ks*nch)/KS, ch1 = ((ks+1)*nch)/KS;
  int bi = t >> 4, j = t & 15;
  float4 px[4], pw[4];

  auto ld = [&](int ch){
    int k0 = ch << 6;
    #pragma unroll
    for (int i=0;i<4;i++){
      int lin = i*256+t; int bl = lin>>4, kq = lin&15;
      int k = k0 + (kq<<2);
      float4 v = make_float4(0.f,0.f,0.f,0.f);
      if (k < K){
        if (X2 != nullptr && k >= Ksplit){
          v = *(const float4*)&X2[(size_t)bl*1024 + (k - Ksplit)];
        } else {
          v = *(const float4*)&X[(size_t)(m0+bl)*xStride + k];
        }
      }
      px[i] = v;
    }
    #pragma unroll
    for (int i=0;i<4;i++){
      int lin = i*256+t; int kk = lin>>4, cq = lin&15;
      int k = k0 + kk, c = c0 + (cq<<2);
      float4 v = make_float4(0.f,0.f,0.f,0.f);
      if (k < K && c < C) v = *(const float4*)&W[(size_t)k*C + c];
      pw[i] = v;
    }
  };
  auto st = [&](int buf){
    #pragma unroll
    for (int i=0;i<4;i++){
      int lin = i*256+t; int bl = lin>>4, kq = lin&15;
      *(float4*)&sm.x_s[buf][bl][kq<<2] = px[i];
    }
    #pragma unroll
    for (int i=0;i<4;i++){
      int lin = i*256+t; int kk = lin>>4, cq = lin&15;
      *(float4*)&sm.w_s[buf][kk][cq<<2] = pw[i];
    }
  };

  float4 acc[4];
  #pragma unroll
  for (int m=0;m<4;m++) acc[m] = make_float4(0.f,0.f,0.f,0.f);

  ld(ch0); st(0); __syncthreads();
  int buf = 0;
  for (int ch = ch0; ch < ch1; ++ch){
    if (ch+1 < ch1) ld(ch+1);
    #pragma unroll
    for (int kq=0;kq<16;kq++){
      float4 xv[4], wv[4];
      #pragma unroll
      for (int bb=0;bb<4;bb++) xv[bb] = *(const float4*)&sm.x_s[buf][(bi<<2)+bb][kq<<2];
      #pragma unroll
      for (int kk=0;kk<4;kk++) wv[kk] = *(const float4*)&sm.w_s[buf][(kq<<2)+kk][j<<2];
      #pragma unroll
      for (int bb=0;bb<4;bb++){
        float s0=xv[bb].x, s1=xv[bb].y, s2=xv[bb].z, s3=xv[bb].w;
        acc[bb].x += s0*wv[0].x + s1*wv[1].x + s2*wv[2].x + s3*wv[3].x;
        acc[bb].y += s0*wv[0].y + s1*wv[1].y + s2*wv[2].y + s3*wv[3].y;
        acc[bb].z += s0*wv[0].z + s1*wv[1].z + s2*wv[2].z + s3*wv[3].z;
        acc[bb].w += s0*wv[0].w + s1*wv[1].w + s2*wv[2].w + s3*wv[3].w;
      }
    }
    if (ch+1 < ch1){ st(buf^1); __syncthreads(); }
    buf ^= 1;
  }
  int c = c0 + (j<<2);
  if (c < C){
    #pragma unroll
    for (int bb=0;bb<4;bb++){
      int bl = (bi<<2)+bb;
      *(float4*)&partial[(size_t)(ks*M + m0 + bl)*C + c] = acc[bb];
    }
  }
}

__global__ __launch_bounds__(256) void k_gemmA(const float* __restrict__ X, int xStride,
                                               const float* __restrict__ X2, int Ksplit,
                                               const float* __restrict__ W,
                                               float* __restrict__ partial,
                                               int K, int C, int nMt, int nCt, int KS){
  __shared__ GemmS sm;
  gemm_body(X,xStride,X2,Ksplit,W,partial,K,C,nMt,nCt,KS,blockIdx.x,threadIdx.x,sm);
}

// =================== LSTM gates GEMM body (bf16 MFMA) ===================
struct LstmS { uint4 WlA[2][512]; uint4 XlA[2][512]; float outb[64][68]; };

__device__ void lstm_body(const float* __restrict__ xA, int KxA,
                          const float* __restrict__ xB,
                          const float* __restrict__ Wih,
                          const float* __restrict__ Whh,
                          float* __restrict__ partial, int KS, int Klen,
                          int bid, int t, LstmS& sm){
  int Mblk = bid & 63;
  int ks = bid >> 6;
  int r0 = Mblk << 6;
  int nch = Klen >> 6;
  int ch0 = (ks*nch)/KS, ch1 = ((ks+1)*nch)/KS;
  int wid = t >> 6, lane = t & 63;

  float4 rw[2][2], rx[2][2];
  auto ld = [&](int ch){
    int k0 = ch << 6;
    #pragma unroll
    for (int u=0;u<2;u++){
      int g = t + (u<<8); int row = g>>3; int k = k0 + ((g&7)<<3);
      const float* sw;
      const float* sx;
      if (k < KxA){ sw = &Wih[(size_t)(r0+row)*KxA + k]; sx = &xA[(size_t)row*KxA + k]; }
      else        { sw = &Whh[((size_t)(r0+row)<<10) + (k - KxA)]; sx = &xB[((size_t)row<<10) + (k - KxA)]; }
      rw[u][0] = *(const float4*)sw; rw[u][1] = *(const float4*)(sw+4);
      rx[u][0] = *(const float4*)sx; rx[u][1] = *(const float4*)(sx+4);
    }
  };
  auto cvst = [&](int buf){
    #pragma unroll
    for (int u=0;u<2;u++){
      int g = t + (u<<8); int row = g>>3, gk = g&7;
      int byte = row*128 + ((gk ^ (row&7))<<4);
      uint4 vw, vx;
      vw.x = pk2_(rw[u][0].x, rw[u][0].y); vw.y = pk2_(rw[u][0].z, rw[u][0].w);
      vw.z = pk2_(rw[u][1].x, rw[u][1].y); vw.w = pk2_(rw[u][1].z, rw[u][1].w);
      vx.x = pk2_(rx[u][0].x, rx[u][0].y); vx.y = pk2_(rx[u][0].z, rx[u][0].w);
      vx.z = pk2_(rx[u][1].x, rx[u][1].y); vx.w = pk2_(rx[u][1].z, rx[u][1].w);
      *(uint4*)((char*)&sm.WlA[buf][0] + byte) = vw;
      *(uint4*)((char*)&sm.XlA[buf][0] + byte) = vx;
    }
  };

  fx4 acc[4];
  #pragma unroll
  for (int nt=0;nt<4;nt++) acc[nt] = (fx4){0.f,0.f,0.f,0.f};

  ld(ch0); cvst(0); __syncthreads();
  int buf = 0;
  for (int ch = ch0; ch < ch1; ++ch){
    if (ch+1 < ch1) ld(ch+1);
    int rowA = (wid<<4) + (lane&15);
    #pragma unroll
    for (int s=0;s<2;s++){
      int gA = (s<<2) + (lane>>4);
      bh8 a = *(bh8*)((char*)&sm.WlA[buf][0] + rowA*128 + ((gA ^ (rowA&7))<<4));
      #pragma unroll
      for (int nt=0;nt<4;nt++){
        int rowB = (nt<<4) + (lane&15);
        bh8 bf = *(bh8*)((char*)&sm.XlA[buf][0] + rowB*128 + ((gA ^ (rowB&7))<<4));
        acc[nt] = __builtin_amdgcn_mfma_f32_16x16x32_bf16(a, bf, acc[nt], 0, 0, 0);
      }
    }
    if (ch+1 < ch1){ cvst(buf^1); __syncthreads(); }
    buf ^= 1;
  }
  __syncthreads();
  #pragma unroll
  for (int nt=0;nt<4;nt++){
    #pragma unroll
    for (int q=0;q<4;q++)
      sm.outb[(nt<<4)+(lane&15)][(wid<<4)+((lane>>4)<<2)+q] = acc[nt][q];
  }
  __syncthreads();
  #pragma unroll
  for (int i=0;i<4;i++){
    int idx = i*256+t; int b = idx>>4; int r4 = (idx&15)<<2;
    float4 o = *(const float4*)&sm.outb[b][r4];
    *(float4*)&partial[(size_t)((ks<<6)+b)*4096 + r0 + r4] = o;
  }
}

// =================== M-tiled MFMA GEMM: out[m][c] = X[m][k]·WT[c][k] ===================
__device__ void mfma_mt_body(const float* __restrict__ X, int xStride,
                             const float* __restrict__ WT, int wStride,
                             float* __restrict__ partial, int M, int Cout,
                             int nMt, int nRt, int KS, int Klen,
                             int bid, int t, LstmS& sm){
  int mt = bid % nMt; int rest = bid / nMt;
  int rt = rest % nRt; int ks = rest / nRt;
  int m0 = mt << 6; int r0 = rt << 6;
  int nch = Klen >> 6;
  int ch0 = (ks*nch)/KS, ch1 = ((ks+1)*nch)/KS;
  int wid = t >> 6, lane = t & 63;

  float4 rw[2][2], rx[2][2];
  auto ld = [&](int ch){
    int k0 = ch << 6;
    #pragma unroll
    for (int u=0;u<2;u++){
      int g = t + (u<<8); int row = g>>3; int k = k0 + ((g&7)<<3);
      const float* sw = &WT[(size_t)(r0+row)*wStride + k];
      const float* sx = &X[(size_t)(m0+row)*xStride + k];
      rw[u][0] = *(const float4*)sw; rw[u][1] = *(const float4*)(sw+4);
      rx[u][0] = *(const float4*)sx; rx[u][1] = *(const float4*)(sx+4);
    }
  };
  auto cvst = [&](int buf){
    #pragma unroll
    for (int u=0;u<2;u++){
      int g = t + (u<<8); int row = g>>3, gk = g&7;
      int byte = row*128 + ((gk ^ (row&7))<<4);
      uint4 vw, vx;
      vw.x = pk2_(rw[u][0].x, rw[u][0].y); vw.y = pk2_(rw[u][0].z, rw[u][0].w);
      vw.z = pk2_(rw[u][1].x, rw[u][1].y); vw.w = pk2_(rw[u][1].z, rw[u][1].w);
      vx.x = pk2_(rx[u][0].x, rx[u][0].y); vx.y = pk2_(rx[u][0].z, rx[u][0].w);
      vx.z = pk2_(rx[u][1].x, rx[u][1].y); vx.w = pk2_(rx[u][1].z, rx[u][1].w);
      *(uint4*)((char*)&sm.WlA[buf][0] + byte) = vw;
      *(uint4*)((char*)&sm.XlA[buf][0] + byte) = vx;
    }
  };

  fx4 acc[4];
  #pragma unroll
  for (int nt=0;nt<4;nt++) acc[nt] = (fx4){0.f,0.f,0.f,0.f};

  ld(ch0); cvst(0); __syncthreads();
  int buf = 0;
  for (int ch = ch0; ch < ch1; ++ch){
    if (ch+1 < ch1) ld(ch+1);
    int rowA = (wid<<4) + (lane&15);
    #pragma unroll
    for (int s=0;s<2;s++){
      int gA = (s<<2) + (lane>>4);
      bh8 a = *(bh8*)((char*)&sm.WlA[buf][0] + rowA*128 + ((gA ^ (rowA&7))<<4));
      #pragma unroll
      for (int nt=0;nt<4;nt++){
        int rowB = (nt<<4) + (lane&15);
        bh8 bf = *(bh8*)((char*)&sm.XlA[buf][0] + rowB*128 + ((gA ^ (rowB&7))<<4));
        acc[nt] = __builtin_amdgcn_mfma_f32_16x16x32_bf16(a, bf, acc[nt], 0, 0, 0);
      }
    }
    if (ch+1 < ch1){ cvst(buf^1); __syncthreads(); }
    buf ^= 1;
  }
  __syncthreads();
  #pragma unroll
  for (int nt=0;nt<4;nt++){
    #pragma unroll
    for (int q=0;q<4;q++)
      sm.outb[(nt<<4)+(lane&15)][(wid<<4)+((lane>>4)<<2)+q] = acc[nt][q];
  }
  __syncthreads();
  #pragma unroll
  for (int i=0;i<4;i++){
    int idx = i*256+t; int b = idx>>4; int r4 = (idx&15)<<2;
    float4 o = *(const float4*)&sm.outb[b][r4];
    *(float4*)&partial[(size_t)(ks*M + m0 + b)*Cout + r0 + r4] = o;
  }
}

// I-part standalone kernel (Wih * x only)
__global__ __launch_bounds__(256) void k_lstmI(const float* __restrict__ xA, int KxA,
                                               const float* __restrict__ Wih,
                                               float* __restrict__ partial,
                                               int KS, int Klen){
  __shared__ LstmS sm;
  lstm_body(xA, KxA, nullptr, Wih, nullptr, partial, KS, Klen,
            blockIdx.x, threadIdx.x, sm);
}

// =================== K1: front | pre1 | WencT | WdecT | Wpre2T | Whh1 rider ===================
__global__ __launch_bounds__(256) void k_front3(
    const float* __restrict__ prev, const int* __restrict__ lens,
    const float* __restrict__ enc, const float* __restrict__ indec,
    const float* __restrict__ spkr,
    const float* __restrict__ W1, const float* __restrict__ b1,
    const float* __restrict__ hid,
    const float* __restrict__ Wenc, const float* __restrict__ Wdec,
    const float* __restrict__ W2, const float* __restrict__ Whh1,
    int* __restrict__ lo_out, int* __restrict__ wl_out,
    float* __restrict__ encw, float* __restrict__ paw,
    float* __restrict__ x0,
    float* __restrict__ p1x, float* __restrict__ WencT,
    float* __restrict__ WdecT, float* __restrict__ Wpre2T,
    float* __restrict__ pL1){
  __shared__ __align__(16) char smem_raw[sizeof(LstmS)];
  int bid = blockIdx.x, t = threadIdx.x;

  if (bid < 64){
    int n = bid;
    float* sv = (float*)smem_raw;
    int*   si = (int*)(smem_raw + 1024);
    int*   meta = (int*)(smem_raw + 2048);
    const float* p = prev + n*T_;
    float bv = -1e30f; int bi2 = 0x7fffffff;
    #pragma unroll
    for (int i=0;i<4;i++){
      int idx = t + (i<<8);
      float v = p[idx];
      if (v > bv || (v == bv && idx < bi2)){ bv = v; bi2 = idx; }
    }
    sv[t]=bv; si[t]=bi2; __syncthreads();
    for (int s=128; s>0; s>>=1){
      if (t < s){
        float v2 = sv[t+s]; int i2 = si[t+s];
        if (v2 > sv[t] || (v2 == sv[t] && i2 < si[t])){ sv[t]=v2; si[t]=i2; }
      }
      __syncthreads();
    }
    if (t==0){
      int len = lens[n]; len = len < 1 ? 1 : (len > T_ ? T_ : len);
      int idx = si[0];
      int lo = idx - 9; lo = lo < 0 ? 0 : lo; if (lo > len-1) lo = len-1;
      int hi = idx + 9; hi = hi < 0 ? 0 : hi; if (hi > len-1) hi = len-1;
      meta[0] = lo; meta[1] = hi - lo + 1;
      lo_out[n] = lo; wl_out[n] = hi - lo + 1;
    }
    __syncthreads();
    int lo = meta[0], wl = meta[1];
    #pragma unroll
    for (int i=0;i<10;i++){
      int lin = i*256 + t;
      int r = lin >> 7, e4 = (lin & 127) << 2;
      if (r < WMAX){
        float4 v = make_float4(0.f,0.f,0.f,0.f);
        if (r < wl) v = *(const float4*)&enc[(size_t)((n<<10)+lo+r)*E_ + e4];
        *(float4*)&encw[(size_t)(n*WMAX + r)*E_ + e4] = v;
      }
    }
    if (t < 49){
      int tt = lo - 15 + t;
      paw[n*49 + t] = (tt >= 0 && tt < T_) ? prev[(n<<10)+tt] : 0.f;
    }
    if (t < 16)
      *(float4*)&x0[n*832 + 768 + (t<<2)] = *(const float4*)&spkr[(n<<6) + (t<<2)];

  } else if (bid < 72){
    // pre1 GEMM (8 blocks)
    int d = bid - 64;
    float* xs = (float*)smem_raw;
    #pragma unroll
    for (int i=0;i<9;i++){
      int q = i*256 + t;
      if (q < 2304){
        int b = q/36; int k4 = (q - b*36) << 2;
        float4 v;
        if (k4 < O_) v = *(const float4*)&indec[b*O_ + k4];
        else         v = *(const float4*)&spkr[(b<<6) + (k4-O_)];
        *(float4*)&xs[b*144 + k4] = v;
      }
    }
    __syncthreads();
    int bi = t >> 4, j = t & 15;
    int c0 = (d<<6) + (j<<2);
    float4 acc[4];
    #pragma unroll
    for (int rr=0;rr<4;rr++) acc[rr] = make_float4(0.f,0.f,0.f,0.f);
    #pragma unroll 4
    for (int k=0;k<144;k++){
      float4 wv = *(const float4*)&W1[(size_t)k*512 + c0];
      #pragma unroll
      for (int rr=0;rr<4;rr++){
        float xv = xs[((bi<<2)+rr)*144 + k];
        acc[rr].x += xv*wv.x; acc[rr].y += xv*wv.y; acc[rr].z += xv*wv.z; acc[rr].w += xv*wv.w;
      }
    }
    float4 bv = *(const float4*)&b1[c0];
    #pragma unroll
    for (int rr=0;rr<4;rr++){
      float4 o;
      o.x = fmaxf(acc[rr].x + bv.x, 0.f);
      o.y = fmaxf(acc[rr].y + bv.y, 0.f);
      o.z = fmaxf(acc[rr].z + bv.z, 0.f);
      o.w = fmaxf(acc[rr].w + bv.w, 0.f);
      *(float4*)&p1x[(size_t)((bi<<2)+rr)*512 + c0] = o;
    }

  } else if (bid < 104){
    // WencT: Wenc [512][256] -> WencT [256][512]  (32 tiles)
    int ti = bid - 72;
    int kt = ti & 7, ct = ti >> 3;
    int k0 = kt<<6, c0 = ct<<6;
    float* tile = (float*)smem_raw;   // [64][65]
    #pragma unroll
    for (int i=0;i<16;i++){
      int lin = i*256+t; int kk = lin>>6, cc = lin&63;
      tile[kk*65+cc] = Wenc[(size_t)(k0+kk)*256 + c0+cc];
    }
    __syncthreads();
    #pragma unroll
    for (int i=0;i<16;i++){
      int lin = i*256+t; int cc = lin>>6, kk = lin&63;
      WencT[(size_t)(c0+cc)*512 + k0+kk] = tile[kk*65+cc];
    }

  } else if (bid < 168){
    // WdecT: Wdec [2048][256] -> WdecT [256][2048]  (128 tiles, 64 blocks x2)
    int base = (bid - 104) << 1;
    float* tile = (float*)smem_raw;
    for (int rep=0; rep<2; rep++){
      int ti = base + rep;
      int kt = ti & 31, ct = ti >> 5;
      int k0 = kt<<6, c0 = ct<<6;
      __syncthreads();
      #pragma unroll
      for (int i=0;i<16;i++){
        int lin = i*256+t; int kk = lin>>6, cc = lin&63;
        tile[kk*65+cc] = Wdec[(size_t)(k0+kk)*256 + c0+cc];
      }
      __syncthreads();
      #pragma unroll
      for (int i=0;i<16;i++){
        int lin = i*256+t; int cc = lin>>6, kk = lin&63;
        WdecT[(size_t)(c0+cc)*2048 + k0+kk] = tile[kk*65+cc];
      }
    }

  } else if (bid < 200){
    // Wpre2T: W2 [512][256] -> Wpre2T [256][512]  (32 tiles)
    int ti = bid - 168;
    int kt = ti & 7, ct = ti >> 3;
    int k0 = kt<<6, c0 = ct<<6;
    float* tile = (float*)smem_raw;
    #pragma unroll
    for (int i=0;i<16;i++){
      int lin = i*256+t; int kk = lin>>6, cc = lin&63;
      tile[kk*65+cc] = W2[(size_t)(k0+kk)*256 + c0+cc];
    }
    __syncthreads();
    #pragma unroll
    for (int i=0;i<16;i++){
      int lin = i*256+t; int cc = lin>>6, kk = lin&63;
      Wpre2T[(size_t)(c0+cc)*512 + k0+kk] = tile[kk*65+cc];
    }

  } else {
    // Whh1 * hid1 rider (256 blocks, KS=4 -> pL1 slots 0-3)
    lstm_body(nullptr, 0, hid + 64*1024, nullptr, Whh1,
              pL1, 4, 1024, bid - 200, t, *(LstmS*)smem_raw);
  }
}

// =================== K2: enc MFMA | pre2 MFMA | Wdec MFMA | Whh0 rider ===================
__global__ __launch_bounds__(256) void k_gemmB(const float* __restrict__ encw,
                                               const float* __restrict__ WencT,
                                               float* __restrict__ pE,
                                               const float* __restrict__ p1x,
                                               const float* __restrict__ Wpre2T,
                                               float* __restrict__ pP2,
                                               const float* __restrict__ hid,
                                               const float* __restrict__ WdecT,
                                               float* __restrict__ pA,
                                               const float* __restrict__ Whh0,
                                               float* __restrict__ pL0){
  __shared__ LstmS sm;
  int bid = blockIdx.x, t = threadIdx.x;
  if (bid < 152){
    mfma_mt_body(encw, 512, WencT, 512, pE, 1216, 256, 19, 4, 2, 512,
                 bid, t, sm);
  } else if (bid < 160){
    mfma_mt_body(p1x, 512, Wpre2T, 512, pP2, 64, 256, 1, 4, 2, 512,
                 bid - 152, t, sm);
  } else if (bid < 176){
    int sub = bid - 160;
    int half = sub >> 3; sub &= 7;
    mfma_mt_body(hid + (size_t)half*64*1024, 1024, WdecT + (size_t)half*1024, 2048,
                 pA + (size_t)half*2*64*256, 64, 256, 1, 4, 2, 1024,
                 sub, t, sm);
  } else {
    lstm_body(nullptr, 0, hid, nullptr, Whh0,
              pL0, 4, 1024, bid - 176, t, sm);
  }
}

// =================== K3: attention epilogue+softmax+ctx | pre2 combine ===================
__global__ __launch_bounds__(256) void k_att2(const float* __restrict__ pE,
    const float* __restrict__ pA, const float* __restrict__ benc,
    const float* __restrict__ convw, const float* __restrict__ Wproj,
    const float* __restrict__ spkr, const float* __restrict__ Wspkr,
    const float* __restrict__ paw, const int* __restrict__ wl_w,
    const float* __restrict__ encw,
    const float* __restrict__ pP2, const float* __restrict__ b2,
    float* __restrict__ x0, float* __restrict__ ctxb){
  __shared__ float cw_s[256*31];
  __shared__ float cv_s[WMAX*256];
  __shared__ float attb_s[256];
  __shared__ float pa_s[49];
  __shared__ float wlog_s[WMAX];
  __shared__ float w_s[WMAX];
  int t = threadIdx.x;

  if (blockIdx.x >= 64){
    int idx = (blockIdx.x - 64)*256 + t;
    int b = idx >> 6; int c4 = (idx & 63) << 2;
    float4 v = *(const float4*)&b2[c4];
    #pragma unroll
    for (int p=0;p<2;p++){
      float4 u = *(const float4*)&pP2[(size_t)((p<<6)+b)*A_ + c4];
      v.x+=u.x; v.y+=u.y; v.z+=u.z; v.w+=u.w;
    }
    v.x=fmaxf(v.x,0.f); v.y=fmaxf(v.y,0.f); v.z=fmaxf(v.z,0.f); v.w=fmaxf(v.w,0.f);
    *(float4*)&x0[b*832 + c4] = v;
    return;
  }

  int n = blockIdx.x;
  int wl = wl_w[n];
  for (int lin = t; lin < 256*31; lin += 256) cw_s[lin] = convw[lin];
  if (t < 49) pa_s[t] = paw[n*49 + t];
  {
    float v = 0.f;
    #pragma unroll
    for (int p=0;p<4;p++) v += pA[(size_t)((p<<6)+n)*A_ + t];
    float sd = 0.f;
    #pragma unroll 16
    for (int s=0;s<S_;s++) sd += spkr[(n<<6)+s]*Wspkr[(s<<8)+t];
    attb_s[t] = v + sd/(1.f+fabsf(sd));
  }
  __syncthreads();
  for (int r=0; r<wl; ++r){
    float cv = 0.f;
    #pragma unroll
    for (int k=0;k<31;k++) cv += cw_s[t*31+k]*pa_s[r+k];
    cv_s[(r<<8)+t] = cv;
  }
  __syncthreads();
  int wid = t>>6, lane = t&63, a0 = lane<<2;
  float4 be4 = *(const float4*)&benc[a0];
  float4 wp4 = *(const float4*)&Wproj[a0];
  float4 ab4 = *(const float4*)&attb_s[a0];
  for (int r = wid; r < wl; r += 4){
    float4 sv = make_float4(0.f,0.f,0.f,0.f);
    #pragma unroll
    for (int ks=0;ks<2;ks++){
      const float4 u = *(const float4*)&pE[(size_t)(ks*1216 + n*WMAX + r)*A_ + a0];
      sv.x+=u.x; sv.y+=u.y; sv.z+=u.z; sv.w+=u.w;
    }
    sv.x += be4.x; sv.y += be4.y; sv.z += be4.z; sv.w += be4.w;
    const float4 cv4 = *(const float4*)&cv_s[(r<<8)+a0];
    float e0 = sv.x/(1.f+fabsf(sv.x)) + ab4.x + cv4.x;
    float e1 = sv.y/(1.f+fabsf(sv.y)) + ab4.y + cv4.y;
    float e2 = sv.z/(1.f+fabsf(sv.z)) + ab4.z + cv4.z;
    float e3 = sv.w/(1.f+fabsf(sv.w)) + ab4.w + cv4.w;
    float vv = tanhf(e0)*wp4.x + tanhf(e1)*wp4.y + tanhf(e2)*wp4.z + tanhf(e3)*wp4.w;
    #pragma unroll
    for (int off=32; off; off >>= 1) vv += __shfl_xor(vv, off, 64);
    if (lane == 0) wlog_s[r] = vv;
  }
  __syncthreads();
  if (t < 32){
    float l = (t < wl) ? wlog_s[t] : -1e30f;
    float mx = l;
    #pragma unroll
    for (int off=16; off; off >>= 1) mx = fmaxf(mx, __shfl_xor(mx, off, 32));
    float ex = (t < wl) ? expf(l - mx) : 0.f;
    float sm = ex;
    #pragma unroll
    for (int off=16; off; off >>= 1) sm += __shfl_xor(sm, off, 32);
    if (t < wl) w_s[t] = ex / sm;
  }
  __syncthreads();
  if (t < 128){
    float4 a = make_float4(0.f,0.f,0.f,0.f);
    for (int r=0; r<wl; ++r){
      float wv = w_s[r];
      const float4 ev = *(const float4*)&encw[(size_t)(n*WMAX + r)*E_ + (t<<2)];
      a.x += wv*ev.x; a.y += wv*ev.y; a.z += wv*ev.z; a.w += wv*ev.w;
    }
    *(float4*)&x0[n*832 + 256 + (t<<2)] = a;
    *(float4*)&ctxb[(n<<10) + (t<<2)] = a;
  }
}

// =================== LSTM combine: gates -> h (256 blocks) ===================
__global__ __launch_bounds__(256) void k_comb(const float* __restrict__ pL, int NS,
                                              const float* __restrict__ bih,
                                              const float* __restrict__ bhh,
                                              const float* __restrict__ cprev,
                                              float* __restrict__ dst){
  int bid = blockIdx.x, t = threadIdx.x;
  int b = bid >> 2; int u = ((bid & 3) << 8) + t;
  float g[4];
  #pragma unroll
  for (int gi=0; gi<4; ++gi){
    int col = (gi<<10) + u;
    float s = bih[col] + bhh[col];
    for (int q=0; q<NS; ++q) s += pL[(size_t)((q<<6)+b)*4096 + col];
    g[gi] = s;
  }
  float c = cprev[(b<<10)+u];
  float cn = sigmoidf_(g[1])*c + sigmoidf_(g[0])*tanhf(g[2]);
  dst[(b<<10)+u] = sigmoidf_(g[3])*tanhf(cn);
}

// =================== output combine ===================
__global__ __launch_bounds__(256) void k_comb_out(const float* __restrict__ pO,
                                                  const float* __restrict__ bout,
                                                  float* __restrict__ out){
  int idx = blockIdx.x*256 + threadIdx.x;
  int b = idx / 160; int c = idx - b*160;
  float s = bout[c];
  #pragma unroll
  for (int ks=0; ks<16; ++ks) s += pO[(size_t)((ks<<6)+b)*160 + c];
  out[idx] = s;
}

extern "C" void kernel_launch(void* const* d_in, const int* in_sizes, int n_in,
                              void* d_out, int out_size, void* d_ws, size_t ws_size,
                              hipStream_t stream){
  const float* enc   = (const float*)d_in[0];
  const float* indec = (const float*)d_in[1];
  const float* spkr  = (const float*)d_in[2];
  const float* prev  = (const float*)d_in[3];
  const float* hid   = (const float*)d_in[4];
  const float* cell  = (const float*)d_in[5];
  const int*   lens  = (const int*)d_in[6];
  const float* Wenc  = (const float*)d_in[7];
  const float* benc  = (const float*)d_in[8];
  const float* Wspkr = (const float*)d_in[9];
  const float* convw = (const float*)d_in[10];
  const float* Wdec  = (const float*)d_in[11];
  const float* Wproj = (const float*)d_in[12];
  /* d_in[13] = b_proj: uniform shift, cancels in normalized attention weights */
  const float* Wpre1 = (const float*)d_in[14];
  const float* bpre1 = (const float*)d_in[15];
  const float* Wpre2 = (const float*)d_in[16];
  const float* bpre2 = (const float*)d_in[17];
  const float* Wih0  = (const float*)d_in[18];
  const float* Whh0  = (const float*)d_in[19];
  const float* bih0  = (const float*)d_in[20];
  const float* bhh0  = (const float*)d_in[21];
  const float* Wih1  = (const float*)d_in[22];
  const float* Whh1  = (const float*)d_in[23];
  const float* bih1  = (const float*)d_in[24];
  const float* bhh1  = (const float*)d_in[25];
  const float* Wout  = (const float*)d_in[26];
  const float* bout  = (const float*)d_in[27];
  (void)in_sizes; (void)n_in; (void)out_size; (void)ws_size;

  float* ws = (float*)d_ws;
  size_t off = 0;
  auto alloc = [&](size_t nf){ float* p = ws + off; off += nf; return p; };
  float* pA     = alloc((size_t)4*64*256);
  float* p1x    = alloc((size_t)64*512);
  float* pP2    = alloc((size_t)2*64*256);
  float* x0     = alloc(64*832);
  float* ctxb   = alloc((size_t)64*1024);
  float* h1     = alloc((size_t)64*1024);
  float* h2b    = alloc((size_t)64*1024);
  float* pO     = alloc((size_t)16*64*160);
  float* paw    = alloc(64*49 + 15);
  int*   lo_w   = (int*)alloc(64);
  int*   wl_w   = (int*)alloc(64);
  float* WencT  = alloc((size_t)256*512);
  float* WdecT  = alloc((size_t)256*2048);
  float* Wpre2T = alloc((size_t)256*512);
  float* encw   = alloc((size_t)64*WMAX*512);
  float* pE     = alloc((size_t)2*1216*256);
  float* pL0    = alloc(8*SLOT);   // slots 0-3: Whh0 (KS=4), slots 4-7: Wih0 (KS=4)
  float* pL1    = alloc(8*SLOT);   // slots 0-3: Whh1 (KS=4), slots 4-7: Wih1 (KS=4)
  float* out    = (float*)d_out;

  // K1: front (0-63) | pre1 (64-71) | WencT (72-103) | WdecT (104-167) | Wpre2T (168-199) | Whh1 (200-455)
  k_front3<<<456,256,0,stream>>>(prev, lens, enc, indec, spkr,
                                 Wpre1, bpre1, hid, Wenc, Wdec, Wpre2, Whh1,
                                 lo_w, wl_w, encw, paw, x0, p1x,
                                 WencT, WdecT, Wpre2T, pL1);
  // K2: enc MFMA (0-151) | pre2 MFMA (152-159) | Wdec MFMA (160-175) | Whh0 (176-431)
  k_gemmB<<<432,256,0,stream>>>(encw, WencT, pE, p1x, Wpre2T, pP2,
                                hid, WdecT, pA, Whh0, pL0);
  // K3: attention (0-63) | pre2 combine (64-79)
  k_att2<<<80,256,0,stream>>>(pE, pA, benc, convw, Wproj, spkr, Wspkr,
                              paw, wl_w, encw, pP2, bpre2, x0, ctxb);
  // K4: Wih0 * x0 (K=832) -> pL0 slots 4-7
  k_lstmI<<<256,256,0,stream>>>(x0, 832, Wih0, pL0 + 4*SLOT, 4, 832);
  // K5: combine layer 0 -> h1 (8 slots)
  k_comb<<<256,256,0,stream>>>(pL0, 8, bih0, bhh0, cell, h1);
  // K6: Wih1 * h1 (K=1024) -> pL1 slots 4-7
  k_lstmI<<<256,256,0,stream>>>(h1, 1024, Wih1, pL1 + 4*SLOT, 4, 1024);
  // K7: combine layer 1 -> h2b (8 slots)
  k_comb<<<256,256,0,stream>>>(pL1, 8, bih1, bhh1, cell + 64*1024, h2b);
  // K8: out GEMM (KS=16, 48 blocks) -> partials
  k_gemmA<<<1*3*16,256,0,stream>>>(h2b, 1024, ctxb, 1024, Wout,
                                   pO, 1536, 160, 1, 3, 16);
  // K9: output combine (16 slots)
  k_comb_out<<<40,256,0,stream>>>(pO, bout, out);
}

// Round 13
// 106.396 us; speedup vs baseline: 1.5020x; 1.0094x over previous
//
#include <hip/hip_runtime.h>
#include <math.h>

#define N_    64
#define T_    1024
#define E_    512
#define A_    256
#define S_    64
#define O_    80
#define HID_  1024
#define WMAX  19
#define SLOTU ((size_t)64*4096)   // one LSTM partial slot, in bf16 elements

typedef __attribute__((ext_vector_type(8))) short bh8;
typedef __attribute__((ext_vector_type(4))) float fx4;

__device__ __forceinline__ float sigmoidf_(float x){ return 1.f/(1.f+expf(-x)); }
__device__ __forceinline__ unsigned pk2_(float a, float b){
  unsigned ua = __float_as_uint(a), ub = __float_as_uint(b);
  ua = (ua + 0x7fffu + ((ua>>16)&1u)) >> 16;
  ub = (ub + 0x7fffu + ((ub>>16)&1u)) >> 16;
  return ua | (ub<<16);
}

// =================== generic tiled GEMM body (fp32) — used only by K8 ===================
struct GemmS { float x_s[2][64][68]; float w_s[2][64][68]; };

__device__ void gemm_body(const float* __restrict__ X, int xStride,
                          const float* __restrict__ X2, int Ksplit,
                          const float* __restrict__ W,
                          float* __restrict__ partial,
                          int K, int C, int nMt, int nCt, int KS,
                          int bid, int t, GemmS& sm){
  int mt = bid % nMt; int rest = bid / nMt;
  int ct = rest % nCt; int ks = rest / nCt;
  int m0 = mt << 6; int c0 = ct << 6;
  int M = nMt << 6;
  int nch = (K + 63) >> 6;
  int ch0 = (ks*nch)/KS, ch1 = ((ks+1)*nch)/KS;
  int bi = t >> 4, j = t & 15;
  float4 px[4], pw[4];

  auto ld = [&](int ch){
    int k0 = ch << 6;
    #pragma unroll
    for (int i=0;i<4;i++){
      int lin = i*256+t; int bl = lin>>4, kq = lin&15;
      int k = k0 + (kq<<2);
      float4 v = make_float4(0.f,0.f,0.f,0.f);
      if (k < K){
        if (X2 != nullptr && k >= Ksplit){
          v = *(const float4*)&X2[(size_t)bl*1024 + (k - Ksplit)];
        } else {
          v = *(const float4*)&X[(size_t)(m0+bl)*xStride + k];
        }
      }
      px[i] = v;
    }
    #pragma unroll
    for (int i=0;i<4;i++){
      int lin = i*256+t; int kk = lin>>4, cq = lin&15;
      int k = k0 + kk, c = c0 + (cq<<2);
      float4 v = make_float4(0.f,0.f,0.f,0.f);
      if (k < K && c < C) v = *(const float4*)&W[(size_t)k*C + c];
      pw[i] = v;
    }
  };
  auto st = [&](int buf){
    #pragma unroll
    for (int i=0;i<4;i++){
      int lin = i*256+t; int bl = lin>>4, kq = lin&15;
      *(float4*)&sm.x_s[buf][bl][kq<<2] = px[i];
    }
    #pragma unroll
    for (int i=0;i<4;i++){
      int lin = i*256+t; int kk = lin>>4, cq = lin&15;
      *(float4*)&sm.w_s[buf][kk][cq<<2] = pw[i];
    }
  };

  float4 acc[4];
  #pragma unroll
  for (int m=0;m<4;m++) acc[m] = make_float4(0.f,0.f,0.f,0.f);

  ld(ch0); st(0); __syncthreads();
  int buf = 0;
  for (int ch = ch0; ch < ch1; ++ch){
    if (ch+1 < ch1) ld(ch+1);
    #pragma unroll
    for (int kq=0;kq<16;kq++){
      float4 xv[4], wv[4];
      #pragma unroll
      for (int bb=0;bb<4;bb++) xv[bb] = *(const float4*)&sm.x_s[buf][(bi<<2)+bb][kq<<2];
      #pragma unroll
      for (int kk=0;kk<4;kk++) wv[kk] = *(const float4*)&sm.w_s[buf][(kq<<2)+kk][j<<2];
      #pragma unroll
      for (int bb=0;bb<4;bb++){
        float s0=xv[bb].x, s1=xv[bb].y, s2=xv[bb].z, s3=xv[bb].w;
        acc[bb].x += s0*wv[0].x + s1*wv[1].x + s2*wv[2].x + s3*wv[3].x;
        acc[bb].y += s0*wv[0].y + s1*wv[1].y + s2*wv[2].y + s3*wv[3].y;
        acc[bb].z += s0*wv[0].z + s1*wv[1].z + s2*wv[2].z + s3*wv[3].z;
        acc[bb].w += s0*wv[0].w + s1*wv[1].w + s2*wv[2].w + s3*wv[3].w;
      }
    }
    if (ch+1 < ch1){ st(buf^1); __syncthreads(); }
    buf ^= 1;
  }
  int c = c0 + (j<<2);
  if (c < C){
    #pragma unroll
    for (int bb=0;bb<4;bb++){
      int bl = (bi<<2)+bb;
      *(float4*)&partial[(size_t)(ks*M + m0 + bl)*C + c] = acc[bb];
    }
  }
}

__global__ __launch_bounds__(256) void k_gemmA(const float* __restrict__ X, int xStride,
                                               const float* __restrict__ X2, int Ksplit,
                                               const float* __restrict__ W,
                                               float* __restrict__ partial,
                                               int K, int C, int nMt, int nCt, int KS){
  __shared__ GemmS sm;
  gemm_body(X,xStride,X2,Ksplit,W,partial,K,C,nMt,nCt,KS,blockIdx.x,threadIdx.x,sm);
}

// =================== LSTM gates GEMM body (bf16 MFMA, bf16 partial out) ===================
struct LstmS { uint4 WlA[2][512]; uint4 XlA[2][512]; float outb[64][68]; };

__device__ void lstm_body(const float* __restrict__ xA, int KxA,
                          const float* __restrict__ xB,
                          const float* __restrict__ Wih,
                          const float* __restrict__ Whh,
                          unsigned short* __restrict__ partial, int KS, int Klen,
                          int bid, int t, LstmS& sm){
  int Mblk = bid & 63;
  int ks = bid >> 6;
  int r0 = Mblk << 6;
  int nch = Klen >> 6;
  int ch0 = (ks*nch)/KS, ch1 = ((ks+1)*nch)/KS;
  int wid = t >> 6, lane = t & 63;

  float4 rw[2][2], rx[2][2];
  auto ld = [&](int ch){
    int k0 = ch << 6;
    #pragma unroll
    for (int u=0;u<2;u++){
      int g = t + (u<<8); int row = g>>3; int k = k0 + ((g&7)<<3);
      const float* sw;
      const float* sx;
      if (k < KxA){ sw = &Wih[(size_t)(r0+row)*KxA + k]; sx = &xA[(size_t)row*KxA + k]; }
      else        { sw = &Whh[((size_t)(r0+row)<<10) + (k - KxA)]; sx = &xB[((size_t)row<<10) + (k - KxA)]; }
      rw[u][0] = *(const float4*)sw; rw[u][1] = *(const float4*)(sw+4);
      rx[u][0] = *(const float4*)sx; rx[u][1] = *(const float4*)(sx+4);
    }
  };
  auto cvst = [&](int buf){
    #pragma unroll
    for (int u=0;u<2;u++){
      int g = t + (u<<8); int row = g>>3, gk = g&7;
      int byte = row*128 + ((gk ^ (row&7))<<4);
      uint4 vw, vx;
      vw.x = pk2_(rw[u][0].x, rw[u][0].y); vw.y = pk2_(rw[u][0].z, rw[u][0].w);
      vw.z = pk2_(rw[u][1].x, rw[u][1].y); vw.w = pk2_(rw[u][1].z, rw[u][1].w);
      vx.x = pk2_(rx[u][0].x, rx[u][0].y); vx.y = pk2_(rx[u][0].z, rx[u][0].w);
      vx.z = pk2_(rx[u][1].x, rx[u][1].y); vx.w = pk2_(rx[u][1].z, rx[u][1].w);
      *(uint4*)((char*)&sm.WlA[buf][0] + byte) = vw;
      *(uint4*)((char*)&sm.XlA[buf][0] + byte) = vx;
    }
  };

  fx4 acc[4];
  #pragma unroll
  for (int nt=0;nt<4;nt++) acc[nt] = (fx4){0.f,0.f,0.f,0.f};

  ld(ch0); cvst(0); __syncthreads();
  int buf = 0;
  for (int ch = ch0; ch < ch1; ++ch){
    if (ch+1 < ch1) ld(ch+1);
    int rowA = (wid<<4) + (lane&15);
    #pragma unroll
    for (int s=0;s<2;s++){
      int gA = (s<<2) + (lane>>4);
      bh8 a = *(bh8*)((char*)&sm.WlA[buf][0] + rowA*128 + ((gA ^ (rowA&7))<<4));
      #pragma unroll
      for (int nt=0;nt<4;nt++){
        int rowB = (nt<<4) + (lane&15);
        bh8 bf = *(bh8*)((char*)&sm.XlA[buf][0] + rowB*128 + ((gA ^ (rowB&7))<<4));
        acc[nt] = __builtin_amdgcn_mfma_f32_16x16x32_bf16(a, bf, acc[nt], 0, 0, 0);
      }
    }
    if (ch+1 < ch1){ cvst(buf^1); __syncthreads(); }
    buf ^= 1;
  }
  __syncthreads();
  #pragma unroll
  for (int nt=0;nt<4;nt++){
    #pragma unroll
    for (int q=0;q<4;q++)
      sm.outb[(nt<<4)+(lane&15)][(wid<<4)+((lane>>4)<<2)+q] = acc[nt][q];
  }
  __syncthreads();
  #pragma unroll
  for (int i=0;i<4;i++){
    int idx = i*256+t; int b = idx>>4; int r4 = (idx&15)<<2;
    float4 o = *(const float4*)&sm.outb[b][r4];
    uint2 pk; pk.x = pk2_(o.x, o.y); pk.y = pk2_(o.z, o.w);
    *(uint2*)&partial[(size_t)((ks<<6)+b)*4096 + r0 + r4] = pk;
  }
}

// =================== M-tiled MFMA GEMM: out[m][c] = X[m][k]·WT[c][k] (fp32 out) ===================
__device__ void mfma_mt_body(const float* __restrict__ X, int xStride,
                             const float* __restrict__ WT, int wStride,
                             float* __restrict__ partial, int M, int Cout,
                             int nMt, int nRt, int KS, int Klen,
                             int bid, int t, LstmS& sm){
  int mt = bid % nMt; int rest = bid / nMt;
  int rt = rest % nRt; int ks = rest / nRt;
  int m0 = mt << 6; int r0 = rt << 6;
  int nch = Klen >> 6;
  int ch0 = (ks*nch)/KS, ch1 = ((ks+1)*nch)/KS;
  int wid = t >> 6, lane = t & 63;

  float4 rw[2][2], rx[2][2];
  auto ld = [&](int ch){
    int k0 = ch << 6;
    #pragma unroll
    for (int u=0;u<2;u++){
      int g = t + (u<<8); int row = g>>3; int k = k0 + ((g&7)<<3);
      const float* sw = &WT[(size_t)(r0+row)*wStride + k];
      const float* sx = &X[(size_t)(m0+row)*xStride + k];
      rw[u][0] = *(const float4*)sw; rw[u][1] = *(const float4*)(sw+4);
      rx[u][0] = *(const float4*)sx; rx[u][1] = *(const float4*)(sx+4);
    }
  };
  auto cvst = [&](int buf){
    #pragma unroll
    for (int u=0;u<2;u++){
      int g = t + (u<<8); int row = g>>3, gk = g&7;
      int byte = row*128 + ((gk ^ (row&7))<<4);
      uint4 vw, vx;
      vw.x = pk2_(rw[u][0].x, rw[u][0].y); vw.y = pk2_(rw[u][0].z, rw[u][0].w);
      vw.z = pk2_(rw[u][1].x, rw[u][1].y); vw.w = pk2_(rw[u][1].z, rw[u][1].w);
      vx.x = pk2_(rx[u][0].x, rx[u][0].y); vx.y = pk2_(rx[u][0].z, rx[u][0].w);
      vx.z = pk2_(rx[u][1].x, rx[u][1].y); vx.w = pk2_(rx[u][1].z, rx[u][1].w);
      *(uint4*)((char*)&sm.WlA[buf][0] + byte) = vw;
      *(uint4*)((char*)&sm.XlA[buf][0] + byte) = vx;
    }
  };

  fx4 acc[4];
  #pragma unroll
  for (int nt=0;nt<4;nt++) acc[nt] = (fx4){0.f,0.f,0.f,0.f};

  ld(ch0); cvst(0); __syncthreads();
  int buf = 0;
  for (int ch = ch0; ch < ch1; ++ch){
    if (ch+1 < ch1) ld(ch+1);
    int rowA = (wid<<4) + (lane&15);
    #pragma unroll
    for (int s=0;s<2;s++){
      int gA = (s<<2) + (lane>>4);
      bh8 a = *(bh8*)((char*)&sm.WlA[buf][0] + rowA*128 + ((gA ^ (rowA&7))<<4));
      #pragma unroll
      for (int nt=0;nt<4;nt++){
        int rowB = (nt<<4) + (lane&15);
        bh8 bf = *(bh8*)((char*)&sm.XlA[buf][0] + rowB*128 + ((gA ^ (rowB&7))<<4));
        acc[nt] = __builtin_amdgcn_mfma_f32_16x16x32_bf16(a, bf, acc[nt], 0, 0, 0);
      }
    }
    if (ch+1 < ch1){ cvst(buf^1); __syncthreads(); }
    buf ^= 1;
  }
  __syncthreads();
  #pragma unroll
  for (int nt=0;nt<4;nt++){
    #pragma unroll
    for (int q=0;q<4;q++)
      sm.outb[(nt<<4)+(lane&15)][(wid<<4)+((lane>>4)<<2)+q] = acc[nt][q];
  }
  __syncthreads();
  #pragma unroll
  for (int i=0;i<4;i++){
    int idx = i*256+t; int b = idx>>4; int r4 = (idx&15)<<2;
    float4 o = *(const float4*)&sm.outb[b][r4];
    *(float4*)&partial[(size_t)(ks*M + m0 + b)*Cout + r0 + r4] = o;
  }
}

// I-part standalone kernel (Wih * x only)
__global__ __launch_bounds__(256) void k_lstmI(const float* __restrict__ xA, int KxA,
                                               const float* __restrict__ Wih,
                                               unsigned short* __restrict__ partial,
                                               int KS, int Klen){
  __shared__ LstmS sm;
  lstm_body(xA, KxA, nullptr, Wih, nullptr, partial, KS, Klen,
            blockIdx.x, threadIdx.x, sm);
}

// =================== K1: front | pre1 | WencT | WdecT | Wpre2T | Whh1 rider ===================
__global__ __launch_bounds__(256) void k_front3(
    const float* __restrict__ prev, const int* __restrict__ lens,
    const float* __restrict__ enc, const float* __restrict__ indec,
    const float* __restrict__ spkr,
    const float* __restrict__ W1, const float* __restrict__ b1,
    const float* __restrict__ hid,
    const float* __restrict__ Wenc, const float* __restrict__ Wdec,
    const float* __restrict__ W2, const float* __restrict__ Whh1,
    int* __restrict__ lo_out, int* __restrict__ wl_out,
    float* __restrict__ encw, float* __restrict__ paw,
    float* __restrict__ x0,
    float* __restrict__ p1x, float* __restrict__ WencT,
    float* __restrict__ WdecT, float* __restrict__ Wpre2T,
    unsigned short* __restrict__ pL1){
  __shared__ __align__(16) char smem_raw[sizeof(LstmS)];
  int bid = blockIdx.x, t = threadIdx.x;

  if (bid < 64){
    int n = bid;
    float* sv = (float*)smem_raw;
    int*   si = (int*)(smem_raw + 1024);
    int*   meta = (int*)(smem_raw + 2048);
    const float* p = prev + n*T_;
    float bv = -1e30f; int bi2 = 0x7fffffff;
    #pragma unroll
    for (int i=0;i<4;i++){
      int idx = t + (i<<8);
      float v = p[idx];
      if (v > bv || (v == bv && idx < bi2)){ bv = v; bi2 = idx; }
    }
    sv[t]=bv; si[t]=bi2; __syncthreads();
    for (int s=128; s>0; s>>=1){
      if (t < s){
        float v2 = sv[t+s]; int i2 = si[t+s];
        if (v2 > sv[t] || (v2 == sv[t] && i2 < si[t])){ sv[t]=v2; si[t]=i2; }
      }
      __syncthreads();
    }
    if (t==0){
      int len = lens[n]; len = len < 1 ? 1 : (len > T_ ? T_ : len);
      int idx = si[0];
      int lo = idx - 9; lo = lo < 0 ? 0 : lo; if (lo > len-1) lo = len-1;
      int hi = idx + 9; hi = hi < 0 ? 0 : hi; if (hi > len-1) hi = len-1;
      meta[0] = lo; meta[1] = hi - lo + 1;
      lo_out[n] = lo; wl_out[n] = hi - lo + 1;
    }
    __syncthreads();
    int lo = meta[0], wl = meta[1];
    #pragma unroll
    for (int i=0;i<10;i++){
      int lin = i*256 + t;
      int r = lin >> 7, e4 = (lin & 127) << 2;
      if (r < WMAX){
        float4 v = make_float4(0.f,0.f,0.f,0.f);
        if (r < wl) v = *(const float4*)&enc[(size_t)((n<<10)+lo+r)*E_ + e4];
        *(float4*)&encw[(size_t)(n*WMAX + r)*E_ + e4] = v;
      }
    }
    if (t < 49){
      int tt = lo - 15 + t;
      paw[n*49 + t] = (tt >= 0 && tt < T_) ? prev[(n<<10)+tt] : 0.f;
    }
    if (t < 16)
      *(float4*)&x0[n*832 + 768 + (t<<2)] = *(const float4*)&spkr[(n<<6) + (t<<2)];

  } else if (bid < 72){
    // pre1 GEMM (8 blocks)
    int d = bid - 64;
    float* xs = (float*)smem_raw;
    #pragma unroll
    for (int i=0;i<9;i++){
      int q = i*256 + t;
      if (q < 2304){
        int b = q/36; int k4 = (q - b*36) << 2;
        float4 v;
        if (k4 < O_) v = *(const float4*)&indec[b*O_ + k4];
        else         v = *(const float4*)&spkr[(b<<6) + (k4-O_)];
        *(float4*)&xs[b*144 + k4] = v;
      }
    }
    __syncthreads();
    int bi = t >> 4, j = t & 15;
    int c0 = (d<<6) + (j<<2);
    float4 acc[4];
    #pragma unroll
    for (int rr=0;rr<4;rr++) acc[rr] = make_float4(0.f,0.f,0.f,0.f);
    #pragma unroll 4
    for (int k=0;k<144;k++){
      float4 wv = *(const float4*)&W1[(size_t)k*512 + c0];
      #pragma unroll
      for (int rr=0;rr<4;rr++){
        float xv = xs[((bi<<2)+rr)*144 + k];
        acc[rr].x += xv*wv.x; acc[rr].y += xv*wv.y; acc[rr].z += xv*wv.z; acc[rr].w += xv*wv.w;
      }
    }
    float4 bv = *(const float4*)&b1[c0];
    #pragma unroll
    for (int rr=0;rr<4;rr++){
      float4 o;
      o.x = fmaxf(acc[rr].x + bv.x, 0.f);
      o.y = fmaxf(acc[rr].y + bv.y, 0.f);
      o.z = fmaxf(acc[rr].z + bv.z, 0.f);
      o.w = fmaxf(acc[rr].w + bv.w, 0.f);
      *(float4*)&p1x[(size_t)((bi<<2)+rr)*512 + c0] = o;
    }

  } else if (bid < 104){
    // WencT: Wenc [512][256] -> WencT [256][512]  (32 tiles)
    int ti = bid - 72;
    int kt = ti & 7, ct = ti >> 3;
    int k0 = kt<<6, c0 = ct<<6;
    float* tile = (float*)smem_raw;   // [64][65]
    #pragma unroll
    for (int i=0;i<16;i++){
      int lin = i*256+t; int kk = lin>>6, cc = lin&63;
      tile[kk*65+cc] = Wenc[(size_t)(k0+kk)*256 + c0+cc];
    }
    __syncthreads();
    #pragma unroll
    for (int i=0;i<16;i++){
      int lin = i*256+t; int cc = lin>>6, kk = lin&63;
      WencT[(size_t)(c0+cc)*512 + k0+kk] = tile[kk*65+cc];
    }

  } else if (bid < 168){
    // WdecT: Wdec [2048][256] -> WdecT [256][2048]  (128 tiles, 64 blocks x2)
    int base = (bid - 104) << 1;
    float* tile = (float*)smem_raw;
    for (int rep=0; rep<2; rep++){
      int ti = base + rep;
      int kt = ti & 31, ct = ti >> 5;
      int k0 = kt<<6, c0 = ct<<6;
      __syncthreads();
      #pragma unroll
      for (int i=0;i<16;i++){
        int lin = i*256+t; int kk = lin>>6, cc = lin&63;
        tile[kk*65+cc] = Wdec[(size_t)(k0+kk)*256 + c0+cc];
      }
      __syncthreads();
      #pragma unroll
      for (int i=0;i<16;i++){
        int lin = i*256+t; int cc = lin>>6, kk = lin&63;
        WdecT[(size_t)(c0+cc)*2048 + k0+kk] = tile[kk*65+cc];
      }
    }

  } else if (bid < 200){
    // Wpre2T: W2 [512][256] -> Wpre2T [256][512]  (32 tiles)
    int ti = bid - 168;
    int kt = ti & 7, ct = ti >> 3;
    int k0 = kt<<6, c0 = ct<<6;
    float* tile = (float*)smem_raw;
    #pragma unroll
    for (int i=0;i<16;i++){
      int lin = i*256+t; int kk = lin>>6, cc = lin&63;
      tile[kk*65+cc] = W2[(size_t)(k0+kk)*256 + c0+cc];
    }
    __syncthreads();
    #pragma unroll
    for (int i=0;i<16;i++){
      int lin = i*256+t; int cc = lin>>6, kk = lin&63;
      Wpre2T[(size_t)(c0+cc)*512 + k0+kk] = tile[kk*65+cc];
    }

  } else {
    // Whh1 * hid1 rider (256 blocks, KS=4 -> pL1 slots 0-3)
    lstm_body(nullptr, 0, hid + 64*1024, nullptr, Whh1,
              pL1, 4, 1024, bid - 200, t, *(LstmS*)smem_raw);
  }
}

// =================== K2: enc MFMA | pre2 MFMA | Wdec MFMA | Whh0 rider ===================
__global__ __launch_bounds__(256) void k_gemmB(const float* __restrict__ encw,
                                               const float* __restrict__ WencT,
                                               float* __restrict__ pE,
                                               const float* __restrict__ p1x,
                                               const float* __restrict__ Wpre2T,
                                               float* __restrict__ pP2,
                                               const float* __restrict__ hid,
                                               const float* __restrict__ WdecT,
                                               float* __restrict__ pA,
                                               const float* __restrict__ Whh0,
                                               unsigned short* __restrict__ pL0){
  __shared__ LstmS sm;
  int bid = blockIdx.x, t = threadIdx.x;
  if (bid < 152){
    mfma_mt_body(encw, 512, WencT, 512, pE, 1216, 256, 19, 4, 2, 512,
                 bid, t, sm);
  } else if (bid < 160){
    mfma_mt_body(p1x, 512, Wpre2T, 512, pP2, 64, 256, 1, 4, 2, 512,
                 bid - 152, t, sm);
  } else if (bid < 176){
    int sub = bid - 160;
    int half = sub >> 3; sub &= 7;
    mfma_mt_body(hid + (size_t)half*64*1024, 1024, WdecT + (size_t)half*1024, 2048,
                 pA + (size_t)half*2*64*256, 64, 256, 1, 4, 2, 1024,
                 sub, t, sm);
  } else {
    lstm_body(nullptr, 0, hid, nullptr, Whh0,
              pL0, 4, 1024, bid - 176, t, sm);
  }
}

// =================== K3: attention epilogue+softmax+ctx | pre2 combine ===================
__global__ __launch_bounds__(256) void k_att2(const float* __restrict__ pE,
    const float* __restrict__ pA, const float* __restrict__ benc,
    const float* __restrict__ convw, const float* __restrict__ Wproj,
    const float* __restrict__ spkr, const float* __restrict__ Wspkr,
    const float* __restrict__ paw, const int* __restrict__ wl_w,
    const float* __restrict__ encw,
    const float* __restrict__ pP2, const float* __restrict__ b2,
    float* __restrict__ x0, float* __restrict__ ctxb){
  __shared__ float cw_s[256*31];
  __shared__ float cv_s[WMAX*256];
  __shared__ float attb_s[256];
  __shared__ float pa_s[49];
  __shared__ float wlog_s[WMAX];
  __shared__ float w_s[WMAX];
  int t = threadIdx.x;

  if (blockIdx.x >= 64){
    int idx = (blockIdx.x - 64)*256 + t;
    int b = idx >> 6; int c4 = (idx & 63) << 2;
    float4 v = *(const float4*)&b2[c4];
    #pragma unroll
    for (int p=0;p<2;p++){
      float4 u = *(const float4*)&pP2[(size_t)((p<<6)+b)*A_ + c4];
      v.x+=u.x; v.y+=u.y; v.z+=u.z; v.w+=u.w;
    }
    v.x=fmaxf(v.x,0.f); v.y=fmaxf(v.y,0.f); v.z=fmaxf(v.z,0.f); v.w=fmaxf(v.w,0.f);
    *(float4*)&x0[b*832 + c4] = v;
    return;
  }

  int n = blockIdx.x;
  int wl = wl_w[n];
  for (int lin = t; lin < 256*31; lin += 256) cw_s[lin] = convw[lin];
  if (t < 49) pa_s[t] = paw[n*49 + t];
  {
    float v = 0.f;
    #pragma unroll
    for (int p=0;p<4;p++) v += pA[(size_t)((p<<6)+n)*A_ + t];
    float sd = 0.f;
    #pragma unroll 16
    for (int s=0;s<S_;s++) sd += spkr[(n<<6)+s]*Wspkr[(s<<8)+t];
    attb_s[t] = v + sd/(1.f+fabsf(sd));
  }
  __syncthreads();
  for (int r=0; r<wl; ++r){
    float cv = 0.f;
    #pragma unroll
    for (int k=0;k<31;k++) cv += cw_s[t*31+k]*pa_s[r+k];
    cv_s[(r<<8)+t] = cv;
  }
  __syncthreads();
  int wid = t>>6, lane = t&63, a0 = lane<<2;
  float4 be4 = *(const float4*)&benc[a0];
  float4 wp4 = *(const float4*)&Wproj[a0];
  float4 ab4 = *(const float4*)&attb_s[a0];
  for (int r = wid; r < wl; r += 4){
    float4 sv = make_float4(0.f,0.f,0.f,0.f);
    #pragma unroll
    for (int ks=0;ks<2;ks++){
      const float4 u = *(const float4*)&pE[(size_t)(ks*1216 + n*WMAX + r)*A_ + a0];
      sv.x+=u.x; sv.y+=u.y; sv.z+=u.z; sv.w+=u.w;
    }
    sv.x += be4.x; sv.y += be4.y; sv.z += be4.z; sv.w += be4.w;
    const float4 cv4 = *(const float4*)&cv_s[(r<<8)+a0];
    float e0 = sv.x/(1.f+fabsf(sv.x)) + ab4.x + cv4.x;
    float e1 = sv.y/(1.f+fabsf(sv.y)) + ab4.y + cv4.y;
    float e2 = sv.z/(1.f+fabsf(sv.z)) + ab4.z + cv4.z;
    float e3 = sv.w/(1.f+fabsf(sv.w)) + ab4.w + cv4.w;
    float vv = tanhf(e0)*wp4.x + tanhf(e1)*wp4.y + tanhf(e2)*wp4.z + tanhf(e3)*wp4.w;
    #pragma unroll
    for (int off=32; off; off >>= 1) vv += __shfl_xor(vv, off, 64);
    if (lane == 0) wlog_s[r] = vv;
  }
  __syncthreads();
  if (t < 32){
    float l = (t < wl) ? wlog_s[t] : -1e30f;
    float mx = l;
    #pragma unroll
    for (int off=16; off; off >>= 1) mx = fmaxf(mx, __shfl_xor(mx, off, 32));
    float ex = (t < wl) ? expf(l - mx) : 0.f;
    float sm = ex;
    #pragma unroll
    for (int off=16; off; off >>= 1) sm += __shfl_xor(sm, off, 32);
    if (t < wl) w_s[t] = ex / sm;
  }
  __syncthreads();
  if (t < 128){
    float4 a = make_float4(0.f,0.f,0.f,0.f);
    for (int r=0; r<wl; ++r){
      float wv = w_s[r];
      const float4 ev = *(const float4*)&encw[(size_t)(n*WMAX + r)*E_ + (t<<2)];
      a.x += wv*ev.x; a.y += wv*ev.y; a.z += wv*ev.z; a.w += wv*ev.w;
    }
    *(float4*)&x0[n*832 + 256 + (t<<2)] = a;
    *(float4*)&ctxb[(n<<10) + (t<<2)] = a;
  }
}

// =================== LSTM combine: bf16 partials -> h (128 blocks) ===================
__global__ __launch_bounds__(256) void k_comb(const unsigned short* __restrict__ pL, int NS,
                                              const float* __restrict__ bih,
                                              const float* __restrict__ bhh,
                                              const float* __restrict__ cprev,
                                              float* __restrict__ dst){
  int bid = blockIdx.x, t = threadIdx.x;
  int b = bid >> 1; int u = ((((bid & 1) << 8) + t) << 1);   // even col, handles u and u+1
  float g0[4], g1[4];
  #pragma unroll
  for (int gi=0; gi<4; ++gi){
    int col = (gi<<10) + u;
    float s0 = bih[col]   + bhh[col];
    float s1 = bih[col+1] + bhh[col+1];
    for (int q=0; q<NS; ++q){
      unsigned v = *(const unsigned*)&pL[(size_t)((q<<6)+b)*4096 + col];
      s0 += __uint_as_float(v << 16);
      s1 += __uint_as_float(v & 0xffff0000u);
    }
    g0[gi] = s0; g1[gi] = s1;
  }
  float c0 = cprev[(b<<10)+u], c1 = cprev[(b<<10)+u+1];
  float cn0 = sigmoidf_(g0[1])*c0 + sigmoidf_(g0[0])*tanhf(g0[2]);
  float cn1 = sigmoidf_(g1[1])*c1 + sigmoidf_(g1[0])*tanhf(g1[2]);
  dst[(b<<10)+u]   = sigmoidf_(g0[3])*tanhf(cn0);
  dst[(b<<10)+u+1] = sigmoidf_(g1[3])*tanhf(cn1);
}

// =================== output combine ===================
__global__ __launch_bounds__(256) void k_comb_out(const float* __restrict__ pO,
                                                  const float* __restrict__ bout,
                                                  float* __restrict__ out){
  int idx = blockIdx.x*256 + threadIdx.x;
  int b = idx / 160; int c = idx - b*160;
  float s = bout[c];
  #pragma unroll
  for (int ks=0; ks<16; ++ks) s += pO[(size_t)((ks<<6)+b)*160 + c];
  out[idx] = s;
}

extern "C" void kernel_launch(void* const* d_in, const int* in_sizes, int n_in,
                              void* d_out, int out_size, void* d_ws, size_t ws_size,
                              hipStream_t stream){
  const float* enc   = (const float*)d_in[0];
  const float* indec = (const float*)d_in[1];
  const float* spkr  = (const float*)d_in[2];
  const float* prev  = (const float*)d_in[3];
  const float* hid   = (const float*)d_in[4];
  const float* cell  = (const float*)d_in[5];
  const int*   lens  = (const int*)d_in[6];
  const float* Wenc  = (const float*)d_in[7];
  const float* benc  = (const float*)d_in[8];
  const float* Wspkr = (const float*)d_in[9];
  const float* convw = (const float*)d_in[10];
  const float* Wdec  = (const float*)d_in[11];
  const float* Wproj = (const float*)d_in[12];
  /* d_in[13] = b_proj: uniform shift, cancels in normalized attention weights */
  const float* Wpre1 = (const float*)d_in[14];
  const float* bpre1 = (const float*)d_in[15];
  const float* Wpre2 = (const float*)d_in[16];
  const float* bpre2 = (const float*)d_in[17];
  const float* Wih0  = (const float*)d_in[18];
  const float* Whh0  = (const float*)d_in[19];
  const float* bih0  = (const float*)d_in[20];
  const float* bhh0  = (const float*)d_in[21];
  const float* Wih1  = (const float*)d_in[22];
  const float* Whh1  = (const float*)d_in[23];
  const float* bih1  = (const float*)d_in[24];
  const float* bhh1  = (const float*)d_in[25];
  const float* Wout  = (const float*)d_in[26];
  const float* bout  = (const float*)d_in[27];
  (void)in_sizes; (void)n_in; (void)out_size; (void)ws_size;

  float* ws = (float*)d_ws;
  size_t off = 0;
  auto alloc = [&](size_t nf){ float* p = ws + off; off += nf; return p; };
  float* pA     = alloc((size_t)4*64*256);
  float* p1x    = alloc((size_t)64*512);
  float* pP2    = alloc((size_t)2*64*256);
  float* x0     = alloc(64*832);
  float* ctxb   = alloc((size_t)64*1024);
  float* h1     = alloc((size_t)64*1024);
  float* h2b    = alloc((size_t)64*1024);
  float* pO     = alloc((size_t)16*64*160);
  float* paw    = alloc(64*49 + 15);
  int*   lo_w   = (int*)alloc(64);
  int*   wl_w   = (int*)alloc(64);
  float* WencT  = alloc((size_t)256*512);
  float* WdecT  = alloc((size_t)256*2048);
  float* Wpre2T = alloc((size_t)256*512);
  float* encw   = alloc((size_t)64*WMAX*512);
  float* pE     = alloc((size_t)2*1216*256);
  unsigned short* pL0 = (unsigned short*)alloc(4*SLOTU);  // 8 bf16 slots: 0-3 Whh0, 4-7 Wih0
  unsigned short* pL1 = (unsigned short*)alloc(4*SLOTU);  // 8 bf16 slots: 0-3 Whh1, 4-7 Wih1
  float* out    = (float*)d_out;

  // K1: front (0-63) | pre1 (64-71) | WencT (72-103) | WdecT (104-167) | Wpre2T (168-199) | Whh1 (200-455)
  k_front3<<<456,256,0,stream>>>(prev, lens, enc, indec, spkr,
                                 Wpre1, bpre1, hid, Wenc, Wdec, Wpre2, Whh1,
                                 lo_w, wl_w, encw, paw, x0, p1x,
                                 WencT, WdecT, Wpre2T, pL1);
  // K2: enc MFMA (0-151) | pre2 MFMA (152-159) | Wdec MFMA (160-175) | Whh0 (176-431)
  k_gemmB<<<432,256,0,stream>>>(encw, WencT, pE, p1x, Wpre2T, pP2,
                                hid, WdecT, pA, Whh0, pL0);
  // K3: attention (0-63) | pre2 combine (64-79)
  k_att2<<<80,256,0,stream>>>(pE, pA, benc, convw, Wproj, spkr, Wspkr,
                              paw, wl_w, encw, pP2, bpre2, x0, ctxb);
  // K4: Wih0 * x0 (K=832) -> pL0 slots 4-7
  k_lstmI<<<256,256,0,stream>>>(x0, 832, Wih0, pL0 + 4*SLOTU, 4, 832);
  // K5: combine layer 0 -> h1 (8 bf16 slots)
  k_comb<<<128,256,0,stream>>>(pL0, 8, bih0, bhh0, cell, h1);
  // K6: Wih1 * h1 (K=1024) -> pL1 slots 4-7
  k_lstmI<<<256,256,0,stream>>>(h1, 1024, Wih1, pL1 + 4*SLOTU, 4, 1024);
  // K7: combine layer 1 -> h2b (8 bf16 slots)
  k_comb<<<128,256,0,stream>>>(pL1, 8, bih1, bhh1, cell + 64*1024, h2b);
  // K8: out GEMM (KS=16, 48 blocks) -> partials
  k_gemmA<<<1*3*16,256,0,stream>>>(h2b, 1024, ctxb, 1024, Wout,
                                   pO, 1536, 160, 1, 3, 16);
  // K9: output combine (16 slots)
  k_comb_out<<<40,256,0,stream>>>(pO, bout, out);
}

// Round 14
// 103.869 us; speedup vs baseline: 1.5386x; 1.0243x over previous
//
#include <hip/hip_runtime.h>
#include <math.h>

#define N_    64
#define T_    1024
#define E_    512
#define A_    256
#define S_    64
#define O_    80
#define HID_  1024
#define WMAX  19
#define SLOTU ((size_t)64*4096)   // one LSTM partial slot, in bf16 elements

typedef __attribute__((ext_vector_type(8))) short bh8;
typedef __attribute__((ext_vector_type(4))) float fx4;

__device__ __forceinline__ float sigmoidf_(float x){ return 1.f/(1.f+expf(-x)); }
__device__ __forceinline__ unsigned pk2_(float a, float b){
  unsigned ua = __float_as_uint(a), ub = __float_as_uint(b);
  ua = (ua + 0x7fffu + ((ua>>16)&1u)) >> 16;
  ub = (ub + 0x7fffu + ((ub>>16)&1u)) >> 16;
  return ua | (ub<<16);
}

// =================== LSTM gates GEMM body (bf16 MFMA, bf16 partial out) ===================
struct LstmS { uint4 WlA[2][512]; uint4 XlA[2][512]; float outb[64][68]; };

__device__ void lstm_body(const float* __restrict__ xA, int KxA,
                          const float* __restrict__ xB,
                          const float* __restrict__ Wih,
                          const float* __restrict__ Whh,
                          unsigned short* __restrict__ partial, int KS, int Klen,
                          int bid, int t, LstmS& sm){
  int Mblk = bid & 63;
  int ks = bid >> 6;
  int r0 = Mblk << 6;
  int nch = Klen >> 6;
  int ch0 = (ks*nch)/KS, ch1 = ((ks+1)*nch)/KS;
  int wid = t >> 6, lane = t & 63;

  float4 rw[2][2], rx[2][2];
  auto ld = [&](int ch){
    int k0 = ch << 6;
    #pragma unroll
    for (int u=0;u<2;u++){
      int g = t + (u<<8); int row = g>>3; int k = k0 + ((g&7)<<3);
      const float* sw;
      const float* sx;
      if (k < KxA){ sw = &Wih[(size_t)(r0+row)*KxA + k]; sx = &xA[(size_t)row*KxA + k]; }
      else        { sw = &Whh[((size_t)(r0+row)<<10) + (k - KxA)]; sx = &xB[((size_t)row<<10) + (k - KxA)]; }
      rw[u][0] = *(const float4*)sw; rw[u][1] = *(const float4*)(sw+4);
      rx[u][0] = *(const float4*)sx; rx[u][1] = *(const float4*)(sx+4);
    }
  };
  auto cvst = [&](int buf){
    #pragma unroll
    for (int u=0;u<2;u++){
      int g = t + (u<<8); int row = g>>3, gk = g&7;
      int byte = row*128 + ((gk ^ (row&7))<<4);
      uint4 vw, vx;
      vw.x = pk2_(rw[u][0].x, rw[u][0].y); vw.y = pk2_(rw[u][0].z, rw[u][0].w);
      vw.z = pk2_(rw[u][1].x, rw[u][1].y); vw.w = pk2_(rw[u][1].z, rw[u][1].w);
      vx.x = pk2_(rx[u][0].x, rx[u][0].y); vx.y = pk2_(rx[u][0].z, rx[u][0].w);
      vx.z = pk2_(rx[u][1].x, rx[u][1].y); vx.w = pk2_(rx[u][1].z, rx[u][1].w);
      *(uint4*)((char*)&sm.WlA[buf][0] + byte) = vw;
      *(uint4*)((char*)&sm.XlA[buf][0] + byte) = vx;
    }
  };

  fx4 acc[4];
  #pragma unroll
  for (int nt=0;nt<4;nt++) acc[nt] = (fx4){0.f,0.f,0.f,0.f};

  ld(ch0); cvst(0); __syncthreads();
  int buf = 0;
  for (int ch = ch0; ch < ch1; ++ch){
    if (ch+1 < ch1) ld(ch+1);
    int rowA = (wid<<4) + (lane&15);
    #pragma unroll
    for (int s=0;s<2;s++){
      int gA = (s<<2) + (lane>>4);
      bh8 a = *(bh8*)((char*)&sm.WlA[buf][0] + rowA*128 + ((gA ^ (rowA&7))<<4));
      #pragma unroll
      for (int nt=0;nt<4;nt++){
        int rowB = (nt<<4) + (lane&15);
        bh8 bf = *(bh8*)((char*)&sm.XlA[buf][0] + rowB*128 + ((gA ^ (rowB&7))<<4));
        acc[nt] = __builtin_amdgcn_mfma_f32_16x16x32_bf16(a, bf, acc[nt], 0, 0, 0);
      }
    }
    if (ch+1 < ch1){ cvst(buf^1); __syncthreads(); }
    buf ^= 1;
  }
  __syncthreads();
  #pragma unroll
  for (int nt=0;nt<4;nt++){
    #pragma unroll
    for (int q=0;q<4;q++)
      sm.outb[(nt<<4)+(lane&15)][(wid<<4)+((lane>>4)<<2)+q] = acc[nt][q];
  }
  __syncthreads();
  #pragma unroll
  for (int i=0;i<4;i++){
    int idx = i*256+t; int b = idx>>4; int r4 = (idx&15)<<2;
    float4 o = *(const float4*)&sm.outb[b][r4];
    uint2 pk; pk.x = pk2_(o.x, o.y); pk.y = pk2_(o.z, o.w);
    *(uint2*)&partial[(size_t)((ks<<6)+b)*4096 + r0 + r4] = pk;
  }
}

// =================== M-tiled MFMA GEMM: out[m][c] = X[m][k]·WT[c][k] (fp32 out) ===================
__device__ void mfma_mt_body(const float* __restrict__ X, int xStride,
                             const float* __restrict__ WT, int wStride,
                             float* __restrict__ partial, int M, int Cout,
                             int nMt, int nRt, int KS, int Klen,
                             int bid, int t, LstmS& sm){
  int mt = bid % nMt; int rest = bid / nMt;
  int rt = rest % nRt; int ks = rest / nRt;
  int m0 = mt << 6; int r0 = rt << 6;
  int nch = Klen >> 6;
  int ch0 = (ks*nch)/KS, ch1 = ((ks+1)*nch)/KS;
  int wid = t >> 6, lane = t & 63;

  float4 rw[2][2], rx[2][2];
  auto ld = [&](int ch){
    int k0 = ch << 6;
    #pragma unroll
    for (int u=0;u<2;u++){
      int g = t + (u<<8); int row = g>>3; int k = k0 + ((g&7)<<3);
      const float* sw = &WT[(size_t)(r0+row)*wStride + k];
      const float* sx = &X[(size_t)(m0+row)*xStride + k];
      rw[u][0] = *(const float4*)sw; rw[u][1] = *(const float4*)(sw+4);
      rx[u][0] = *(const float4*)sx; rx[u][1] = *(const float4*)(sx+4);
    }
  };
  auto cvst = [&](int buf){
    #pragma unroll
    for (int u=0;u<2;u++){
      int g = t + (u<<8); int row = g>>3, gk = g&7;
      int byte = row*128 + ((gk ^ (row&7))<<4);
      uint4 vw, vx;
      vw.x = pk2_(rw[u][0].x, rw[u][0].y); vw.y = pk2_(rw[u][0].z, rw[u][0].w);
      vw.z = pk2_(rw[u][1].x, rw[u][1].y); vw.w = pk2_(rw[u][1].z, rw[u][1].w);
      vx.x = pk2_(rx[u][0].x, rx[u][0].y); vx.y = pk2_(rx[u][0].z, rx[u][0].w);
      vx.z = pk2_(rx[u][1].x, rx[u][1].y); vx.w = pk2_(rx[u][1].z, rx[u][1].w);
      *(uint4*)((char*)&sm.WlA[buf][0] + byte) = vw;
      *(uint4*)((char*)&sm.XlA[buf][0] + byte) = vx;
    }
  };

  fx4 acc[4];
  #pragma unroll
  for (int nt=0;nt<4;nt++) acc[nt] = (fx4){0.f,0.f,0.f,0.f};

  ld(ch0); cvst(0); __syncthreads();
  int buf = 0;
  for (int ch = ch0; ch < ch1; ++ch){
    if (ch+1 < ch1) ld(ch+1);
    int rowA = (wid<<4) + (lane&15);
    #pragma unroll
    for (int s=0;s<2;s++){
      int gA = (s<<2) + (lane>>4);
      bh8 a = *(bh8*)((char*)&sm.WlA[buf][0] + rowA*128 + ((gA ^ (rowA&7))<<4));
      #pragma unroll
      for (int nt=0;nt<4;nt++){
        int rowB = (nt<<4) + (lane&15);
        bh8 bf = *(bh8*)((char*)&sm.XlA[buf][0] + rowB*128 + ((gA ^ (rowB&7))<<4));
        acc[nt] = __builtin_amdgcn_mfma_f32_16x16x32_bf16(a, bf, acc[nt], 0, 0, 0);
      }
    }
    if (ch+1 < ch1){ cvst(buf^1); __syncthreads(); }
    buf ^= 1;
  }
  __syncthreads();
  #pragma unroll
  for (int nt=0;nt<4;nt++){
    #pragma unroll
    for (int q=0;q<4;q++)
      sm.outb[(nt<<4)+(lane&15)][(wid<<4)+((lane>>4)<<2)+q] = acc[nt][q];
  }
  __syncthreads();
  #pragma unroll
  for (int i=0;i<4;i++){
    int idx = i*256+t; int b = idx>>4; int r4 = (idx&15)<<2;
    float4 o = *(const float4*)&sm.outb[b][r4];
    *(float4*)&partial[(size_t)(ks*M + m0 + b)*Cout + r0 + r4] = o;
  }
}

// =================== out GEMM via MFMA: X = [h2b | ctxb], WT = WoutT[192][1536] ===================
__global__ __launch_bounds__(256) void k_out_mfma(const float* __restrict__ h2b,
                                                  const float* __restrict__ ctxb,
                                                  const float* __restrict__ WoutT,
                                                  float* __restrict__ pO){
  __shared__ LstmS sm;
  int bid = blockIdx.x, t = threadIdx.x;
  int rt = bid % 3; int ks = bid / 3;      // 12 blocks: 3 col-tiles x KS=4
  int r0 = rt << 6;
  int ch0 = ks*6, ch1 = ch0 + 6;           // Klen=1536 -> 24 chunks
  int wid = t >> 6, lane = t & 63;

  float4 rw[2][2], rx[2][2];
  auto ld = [&](int ch){
    int k0 = ch << 6;
    #pragma unroll
    for (int u=0;u<2;u++){
      int g = t + (u<<8); int row = g>>3; int k = k0 + ((g&7)<<3);
      const float* sw = &WoutT[(size_t)(r0+row)*1536 + k];
      const float* sx = (k < 1024) ? &h2b[(size_t)row*1024 + k]
                                   : &ctxb[(size_t)row*1024 + (k - 1024)];
      rw[u][0] = *(const float4*)sw; rw[u][1] = *(const float4*)(sw+4);
      rx[u][0] = *(const float4*)sx; rx[u][1] = *(const float4*)(sx+4);
    }
  };
  auto cvst = [&](int buf){
    #pragma unroll
    for (int u=0;u<2;u++){
      int g = t + (u<<8); int row = g>>3, gk = g&7;
      int byte = row*128 + ((gk ^ (row&7))<<4);
      uint4 vw, vx;
      vw.x = pk2_(rw[u][0].x, rw[u][0].y); vw.y = pk2_(rw[u][0].z, rw[u][0].w);
      vw.z = pk2_(rw[u][1].x, rw[u][1].y); vw.w = pk2_(rw[u][1].z, rw[u][1].w);
      vx.x = pk2_(rx[u][0].x, rx[u][0].y); vx.y = pk2_(rx[u][0].z, rx[u][0].w);
      vx.z = pk2_(rx[u][1].x, rx[u][1].y); vx.w = pk2_(rx[u][1].z, rx[u][1].w);
      *(uint4*)((char*)&sm.WlA[buf][0] + byte) = vw;
      *(uint4*)((char*)&sm.XlA[buf][0] + byte) = vx;
    }
  };

  fx4 acc[4];
  #pragma unroll
  for (int nt=0;nt<4;nt++) acc[nt] = (fx4){0.f,0.f,0.f,0.f};

  ld(ch0); cvst(0); __syncthreads();
  int buf = 0;
  for (int ch = ch0; ch < ch1; ++ch){
    if (ch+1 < ch1) ld(ch+1);
    int rowA = (wid<<4) + (lane&15);
    #pragma unroll
    for (int s=0;s<2;s++){
      int gA = (s<<2) + (lane>>4);
      bh8 a = *(bh8*)((char*)&sm.WlA[buf][0] + rowA*128 + ((gA ^ (rowA&7))<<4));
      #pragma unroll
      for (int nt=0;nt<4;nt++){
        int rowB = (nt<<4) + (lane&15);
        bh8 bf = *(bh8*)((char*)&sm.XlA[buf][0] + rowB*128 + ((gA ^ (rowB&7))<<4));
        acc[nt] = __builtin_amdgcn_mfma_f32_16x16x32_bf16(a, bf, acc[nt], 0, 0, 0);
      }
    }
    if (ch+1 < ch1){ cvst(buf^1); __syncthreads(); }
    buf ^= 1;
  }
  __syncthreads();
  #pragma unroll
  for (int nt=0;nt<4;nt++){
    #pragma unroll
    for (int q=0;q<4;q++)
      sm.outb[(nt<<4)+(lane&15)][(wid<<4)+((lane>>4)<<2)+q] = acc[nt][q];
  }
  __syncthreads();
  #pragma unroll
  for (int i=0;i<4;i++){
    int idx = i*256+t; int b = idx>>4; int r4 = (idx&15)<<2;
    float4 o = *(const float4*)&sm.outb[b][r4];
    *(float4*)&pO[(size_t)((ks<<6)+b)*192 + r0 + r4] = o;
  }
}

// I-part standalone kernel (Wih * x only)
__global__ __launch_bounds__(256) void k_lstmI(const float* __restrict__ xA, int KxA,
                                               const float* __restrict__ Wih,
                                               unsigned short* __restrict__ partial,
                                               int KS, int Klen){
  __shared__ LstmS sm;
  lstm_body(xA, KxA, nullptr, Wih, nullptr, partial, KS, Klen,
            blockIdx.x, threadIdx.x, sm);
}

// =================== K1: front | pre1 | WencT | WdecT | Wpre2T | Whh1 | WoutT ===================
__global__ __launch_bounds__(256) void k_front3(
    const float* __restrict__ prev, const int* __restrict__ lens,
    const float* __restrict__ enc, const float* __restrict__ indec,
    const float* __restrict__ spkr,
    const float* __restrict__ W1, const float* __restrict__ b1,
    const float* __restrict__ hid,
    const float* __restrict__ Wenc, const float* __restrict__ Wdec,
    const float* __restrict__ W2, const float* __restrict__ Whh1,
    const float* __restrict__ Wout,
    int* __restrict__ lo_out, int* __restrict__ wl_out,
    float* __restrict__ encw, float* __restrict__ paw,
    float* __restrict__ x0,
    float* __restrict__ p1x, float* __restrict__ WencT,
    float* __restrict__ WdecT, float* __restrict__ Wpre2T,
    float* __restrict__ WoutT,
    unsigned short* __restrict__ pL1){
  __shared__ __align__(16) char smem_raw[sizeof(LstmS)];
  int bid = blockIdx.x, t = threadIdx.x;

  if (bid < 64){
    int n = bid;
    float* sv = (float*)smem_raw;
    int*   si = (int*)(smem_raw + 1024);
    int*   meta = (int*)(smem_raw + 2048);
    const float* p = prev + n*T_;
    float bv = -1e30f; int bi2 = 0x7fffffff;
    #pragma unroll
    for (int i=0;i<4;i++){
      int idx = t + (i<<8);
      float v = p[idx];
      if (v > bv || (v == bv && idx < bi2)){ bv = v; bi2 = idx; }
    }
    sv[t]=bv; si[t]=bi2; __syncthreads();
    for (int s=128; s>0; s>>=1){
      if (t < s){
        float v2 = sv[t+s]; int i2 = si[t+s];
        if (v2 > sv[t] || (v2 == sv[t] && i2 < si[t])){ sv[t]=v2; si[t]=i2; }
      }
      __syncthreads();
    }
    if (t==0){
      int len = lens[n]; len = len < 1 ? 1 : (len > T_ ? T_ : len);
      int idx = si[0];
      int lo = idx - 9; lo = lo < 0 ? 0 : lo; if (lo > len-1) lo = len-1;
      int hi = idx + 9; hi = hi < 0 ? 0 : hi; if (hi > len-1) hi = len-1;
      meta[0] = lo; meta[1] = hi - lo + 1;
      lo_out[n] = lo; wl_out[n] = hi - lo + 1;
    }
    __syncthreads();
    int lo = meta[0], wl = meta[1];
    #pragma unroll
    for (int i=0;i<10;i++){
      int lin = i*256 + t;
      int r = lin >> 7, e4 = (lin & 127) << 2;
      if (r < WMAX){
        float4 v = make_float4(0.f,0.f,0.f,0.f);
        if (r < wl) v = *(const float4*)&enc[(size_t)((n<<10)+lo+r)*E_ + e4];
        *(float4*)&encw[(size_t)(n*WMAX + r)*E_ + e4] = v;
      }
    }
    if (t < 49){
      int tt = lo - 15 + t;
      paw[n*49 + t] = (tt >= 0 && tt < T_) ? prev[(n<<10)+tt] : 0.f;
    }
    if (t < 16)
      *(float4*)&x0[n*832 + 768 + (t<<2)] = *(const float4*)&spkr[(n<<6) + (t<<2)];

  } else if (bid < 72){
    // pre1 GEMM (8 blocks)
    int d = bid - 64;
    float* xs = (float*)smem_raw;
    #pragma unroll
    for (int i=0;i<9;i++){
      int q = i*256 + t;
      if (q < 2304){
        int b = q/36; int k4 = (q - b*36) << 2;
        float4 v;
        if (k4 < O_) v = *(const float4*)&indec[b*O_ + k4];
        else         v = *(const float4*)&spkr[(b<<6) + (k4-O_)];
        *(float4*)&xs[b*144 + k4] = v;
      }
    }
    __syncthreads();
    int bi = t >> 4, j = t & 15;
    int c0 = (d<<6) + (j<<2);
    float4 acc[4];
    #pragma unroll
    for (int rr=0;rr<4;rr++) acc[rr] = make_float4(0.f,0.f,0.f,0.f);
    #pragma unroll 4
    for (int k=0;k<144;k++){
      float4 wv = *(const float4*)&W1[(size_t)k*512 + c0];
      #pragma unroll
      for (int rr=0;rr<4;rr++){
        float xv = xs[((bi<<2)+rr)*144 + k];
        acc[rr].x += xv*wv.x; acc[rr].y += xv*wv.y; acc[rr].z += xv*wv.z; acc[rr].w += xv*wv.w;
      }
    }
    float4 bv = *(const float4*)&b1[c0];
    #pragma unroll
    for (int rr=0;rr<4;rr++){
      float4 o;
      o.x = fmaxf(acc[rr].x + bv.x, 0.f);
      o.y = fmaxf(acc[rr].y + bv.y, 0.f);
      o.z = fmaxf(acc[rr].z + bv.z, 0.f);
      o.w = fmaxf(acc[rr].w + bv.w, 0.f);
      *(float4*)&p1x[(size_t)((bi<<2)+rr)*512 + c0] = o;
    }

  } else if (bid < 104){
    // WencT: Wenc [512][256] -> WencT [256][512]  (32 tiles)
    int ti = bid - 72;
    int kt = ti & 7, ct = ti >> 3;
    int k0 = kt<<6, c0 = ct<<6;
    float* tile = (float*)smem_raw;   // [64][65]
    #pragma unroll
    for (int i=0;i<16;i++){
      int lin = i*256+t; int kk = lin>>6, cc = lin&63;
      tile[kk*65+cc] = Wenc[(size_t)(k0+kk)*256 + c0+cc];
    }
    __syncthreads();
    #pragma unroll
    for (int i=0;i<16;i++){
      int lin = i*256+t; int cc = lin>>6, kk = lin&63;
      WencT[(size_t)(c0+cc)*512 + k0+kk] = tile[kk*65+cc];
    }

  } else if (bid < 168){
    // WdecT: Wdec [2048][256] -> WdecT [256][2048]  (128 tiles, 64 blocks x2)
    int base = (bid - 104) << 1;
    float* tile = (float*)smem_raw;
    for (int rep=0; rep<2; rep++){
      int ti = base + rep;
      int kt = ti & 31, ct = ti >> 5;
      int k0 = kt<<6, c0 = ct<<6;
      __syncthreads();
      #pragma unroll
      for (int i=0;i<16;i++){
        int lin = i*256+t; int kk = lin>>6, cc = lin&63;
        tile[kk*65+cc] = Wdec[(size_t)(k0+kk)*256 + c0+cc];
      }
      __syncthreads();
      #pragma unroll
      for (int i=0;i<16;i++){
        int lin = i*256+t; int cc = lin>>6, kk = lin&63;
        WdecT[(size_t)(c0+cc)*2048 + k0+kk] = tile[kk*65+cc];
      }
    }

  } else if (bid < 200){
    // Wpre2T: W2 [512][256] -> Wpre2T [256][512]  (32 tiles)
    int ti = bid - 168;
    int kt = ti & 7, ct = ti >> 3;
    int k0 = kt<<6, c0 = ct<<6;
    float* tile = (float*)smem_raw;
    #pragma unroll
    for (int i=0;i<16;i++){
      int lin = i*256+t; int kk = lin>>6, cc = lin&63;
      tile[kk*65+cc] = W2[(size_t)(k0+kk)*256 + c0+cc];
    }
    __syncthreads();
    #pragma unroll
    for (int i=0;i<16;i++){
      int lin = i*256+t; int cc = lin>>6, kk = lin&63;
      Wpre2T[(size_t)(c0+cc)*512 + k0+kk] = tile[kk*65+cc];
    }

  } else if (bid < 456){
    // Whh1 * hid1 rider (256 blocks, KS=4 -> pL1 slots 0-3)
    lstm_body(nullptr, 0, hid + 64*1024, nullptr, Whh1,
              pL1, 4, 1024, bid - 200, t, *(LstmS*)smem_raw);

  } else {
    // WoutT: Wout [1536][160] -> WoutT [192][1536], rows 160-191 zeroed (36 blocks x2 tiles)
    int base = (bid - 456) << 1;
    float* tile = (float*)smem_raw;
    for (int rep=0; rep<2; rep++){
      int ti = base + rep;                 // 0..71
      int kt = ti % 24, ct = ti / 24;
      int k0 = kt<<6, c0 = ct<<6;
      __syncthreads();
      #pragma unroll
      for (int i=0;i<16;i++){
        int lin = i*256+t; int kk = lin>>6, cc = lin&63;
        int c = c0+cc;
        tile[kk*65+cc] = (c < 160) ? Wout[(size_t)(k0+kk)*160 + c] : 0.f;
      }
      __syncthreads();
      #pragma unroll
      for (int i=0;i<16;i++){
        int lin = i*256+t; int cc = lin>>6, kk = lin&63;
        WoutT[(size_t)(c0+cc)*1536 + k0+kk] = tile[kk*65+cc];
      }
    }
  }
}

// =================== K2: enc MFMA | pre2 MFMA | Wdec MFMA | Whh0 rider ===================
__global__ __launch_bounds__(256) void k_gemmB(const float* __restrict__ encw,
                                               const float* __restrict__ WencT,
                                               float* __restrict__ pE,
                                               const float* __restrict__ p1x,
                                               const float* __restrict__ Wpre2T,
                                               float* __restrict__ pP2,
                                               const float* __restrict__ hid,
                                               const float* __restrict__ WdecT,
                                               float* __restrict__ pA,
                                               const float* __restrict__ Whh0,
                                               unsigned short* __restrict__ pL0){
  __shared__ LstmS sm;
  int bid = blockIdx.x, t = threadIdx.x;
  if (bid < 152){
    mfma_mt_body(encw, 512, WencT, 512, pE, 1216, 256, 19, 4, 2, 512,
                 bid, t, sm);
  } else if (bid < 160){
    mfma_mt_body(p1x, 512, Wpre2T, 512, pP2, 64, 256, 1, 4, 2, 512,
                 bid - 152, t, sm);
  } else if (bid < 176){
    int sub = bid - 160;
    int half = sub >> 3; sub &= 7;
    mfma_mt_body(hid + (size_t)half*64*1024, 1024, WdecT + (size_t)half*1024, 2048,
                 pA + (size_t)half*2*64*256, 64, 256, 1, 4, 2, 1024,
                 sub, t, sm);
  } else {
    lstm_body(nullptr, 0, hid, nullptr, Whh0,
              pL0, 4, 1024, bid - 176, t, sm);
  }
}

// =================== K3: attention epilogue+softmax+ctx | pre2 combine ===================
__global__ __launch_bounds__(256) void k_att2(const float* __restrict__ pE,
    const float* __restrict__ pA, const float* __restrict__ benc,
    const float* __restrict__ convw, const float* __restrict__ Wproj,
    const float* __restrict__ spkr, const float* __restrict__ Wspkr,
    const float* __restrict__ paw, const int* __restrict__ wl_w,
    const float* __restrict__ encw,
    const float* __restrict__ pP2, const float* __restrict__ b2,
    float* __restrict__ x0, float* __restrict__ ctxb){
  __shared__ float cw_s[256*31];
  __shared__ float cv_s[WMAX*256];
  __shared__ float attb_s[256];
  __shared__ float pa_s[49];
  __shared__ float wlog_s[WMAX];
  __shared__ float w_s[WMAX];
  int t = threadIdx.x;

  if (blockIdx.x >= 64){
    int idx = (blockIdx.x - 64)*256 + t;
    int b = idx >> 6; int c4 = (idx & 63) << 2;
    float4 v = *(const float4*)&b2[c4];
    #pragma unroll
    for (int p=0;p<2;p++){
      float4 u = *(const float4*)&pP2[(size_t)((p<<6)+b)*A_ + c4];
      v.x+=u.x; v.y+=u.y; v.z+=u.z; v.w+=u.w;
    }
    v.x=fmaxf(v.x,0.f); v.y=fmaxf(v.y,0.f); v.z=fmaxf(v.z,0.f); v.w=fmaxf(v.w,0.f);
    *(float4*)&x0[b*832 + c4] = v;
    return;
  }

  int n = blockIdx.x;
  int wl = wl_w[n];
  for (int lin = t; lin < 256*31; lin += 256) cw_s[lin] = convw[lin];
  if (t < 49) pa_s[t] = paw[n*49 + t];
  {
    float v = 0.f;
    #pragma unroll
    for (int p=0;p<4;p++) v += pA[(size_t)((p<<6)+n)*A_ + t];
    float sd = 0.f;
    #pragma unroll 16
    for (int s=0;s<S_;s++) sd += spkr[(n<<6)+s]*Wspkr[(s<<8)+t];
    attb_s[t] = v + sd/(1.f+fabsf(sd));
  }
  __syncthreads();
  for (int r=0; r<wl; ++r){
    float cv = 0.f;
    #pragma unroll
    for (int k=0;k<31;k++) cv += cw_s[t*31+k]*pa_s[r+k];
    cv_s[(r<<8)+t] = cv;
  }
  __syncthreads();
  int wid = t>>6, lane = t&63, a0 = lane<<2;
  float4 be4 = *(const float4*)&benc[a0];
  float4 wp4 = *(const float4*)&Wproj[a0];
  float4 ab4 = *(const float4*)&attb_s[a0];
  for (int r = wid; r < wl; r += 4){
    float4 sv = make_float4(0.f,0.f,0.f,0.f);
    #pragma unroll
    for (int ks=0;ks<2;ks++){
      const float4 u = *(const float4*)&pE[(size_t)(ks*1216 + n*WMAX + r)*A_ + a0];
      sv.x+=u.x; sv.y+=u.y; sv.z+=u.z; sv.w+=u.w;
    }
    sv.x += be4.x; sv.y += be4.y; sv.z += be4.z; sv.w += be4.w;
    const float4 cv4 = *(const float4*)&cv_s[(r<<8)+a0];
    float e0 = sv.x/(1.f+fabsf(sv.x)) + ab4.x + cv4.x;
    float e1 = sv.y/(1.f+fabsf(sv.y)) + ab4.y + cv4.y;
    float e2 = sv.z/(1.f+fabsf(sv.z)) + ab4.z + cv4.z;
    float e3 = sv.w/(1.f+fabsf(sv.w)) + ab4.w + cv4.w;
    float vv = tanhf(e0)*wp4.x + tanhf(e1)*wp4.y + tanhf(e2)*wp4.z + tanhf(e3)*wp4.w;
    #pragma unroll
    for (int off=32; off; off >>= 1) vv += __shfl_xor(vv, off, 64);
    if (lane == 0) wlog_s[r] = vv;
  }
  __syncthreads();
  if (t < 32){
    float l = (t < wl) ? wlog_s[t] : -1e30f;
    float mx = l;
    #pragma unroll
    for (int off=16; off; off >>= 1) mx = fmaxf(mx, __shfl_xor(mx, off, 32));
    float ex = (t < wl) ? expf(l - mx) : 0.f;
    float sm = ex;
    #pragma unroll
    for (int off=16; off; off >>= 1) sm += __shfl_xor(sm, off, 32);
    if (t < wl) w_s[t] = ex / sm;
  }
  __syncthreads();
  if (t < 128){
    float4 a = make_float4(0.f,0.f,0.f,0.f);
    for (int r=0; r<wl; ++r){
      float wv = w_s[r];
      const float4 ev = *(const float4*)&encw[(size_t)(n*WMAX + r)*E_ + (t<<2)];
      a.x += wv*ev.x; a.y += wv*ev.y; a.z += wv*ev.z; a.w += wv*ev.w;
    }
    *(float4*)&x0[n*832 + 256 + (t<<2)] = a;
    *(float4*)&ctxb[(n<<10) + (t<<2)] = a;
  }
}

// =================== LSTM combine: bf16 partials -> h (128 blocks) ===================
__global__ __launch_bounds__(256) void k_comb(const unsigned short* __restrict__ pL, int NS,
                                              const float* __restrict__ bih,
                                              const float* __restrict__ bhh,
                                              const float* __restrict__ cprev,
                                              float* __restrict__ dst){
  int bid = blockIdx.x, t = threadIdx.x;
  int b = bid >> 1; int u = ((((bid & 1) << 8) + t) << 1);   // even col, handles u and u+1
  float g0[4], g1[4];
  #pragma unroll
  for (int gi=0; gi<4; ++gi){
    int col = (gi<<10) + u;
    float s0 = bih[col]   + bhh[col];
    float s1 = bih[col+1] + bhh[col+1];
    for (int q=0; q<NS; ++q){
      unsigned v = *(const unsigned*)&pL[(size_t)((q<<6)+b)*4096 + col];
      s0 += __uint_as_float(v << 16);
      s1 += __uint_as_float(v & 0xffff0000u);
    }
    g0[gi] = s0; g1[gi] = s1;
  }
  float c0 = cprev[(b<<10)+u], c1 = cprev[(b<<10)+u+1];
  float cn0 = sigmoidf_(g0[1])*c0 + sigmoidf_(g0[0])*tanhf(g0[2]);
  float cn1 = sigmoidf_(g1[1])*c1 + sigmoidf_(g1[0])*tanhf(g1[2]);
  dst[(b<<10)+u]   = sigmoidf_(g0[3])*tanhf(cn0);
  dst[(b<<10)+u+1] = sigmoidf_(g1[3])*tanhf(cn1);
}

// =================== output combine (4 slots, 192-col padded pO) ===================
__global__ __launch_bounds__(256) void k_comb_out(const float* __restrict__ pO,
                                                  const float* __restrict__ bout,
                                                  float* __restrict__ out){
  int idx = blockIdx.x*256 + threadIdx.x;
  int b = idx / 160; int c = idx - b*160;
  float s = bout[c];
  #pragma unroll
  for (int ks=0; ks<4; ++ks) s += pO[(size_t)((ks<<6)+b)*192 + c];
  out[idx] = s;
}

extern "C" void kernel_launch(void* const* d_in, const int* in_sizes, int n_in,
                              void* d_out, int out_size, void* d_ws, size_t ws_size,
                              hipStream_t stream){
  const float* enc   = (const float*)d_in[0];
  const float* indec = (const float*)d_in[1];
  const float* spkr  = (const float*)d_in[2];
  const float* prev  = (const float*)d_in[3];
  const float* hid   = (const float*)d_in[4];
  const float* cell  = (const float*)d_in[5];
  const int*   lens  = (const int*)d_in[6];
  const float* Wenc  = (const float*)d_in[7];
  const float* benc  = (const float*)d_in[8];
  const float* Wspkr = (const float*)d_in[9];
  const float* convw = (const float*)d_in[10];
  const float* Wdec  = (const float*)d_in[11];
  const float* Wproj = (const float*)d_in[12];
  /* d_in[13] = b_proj: uniform shift, cancels in normalized attention weights */
  const float* Wpre1 = (const float*)d_in[14];
  const float* bpre1 = (const float*)d_in[15];
  const float* Wpre2 = (const float*)d_in[16];
  const float* bpre2 = (const float*)d_in[17];
  const float* Wih0  = (const float*)d_in[18];
  const float* Whh0  = (const float*)d_in[19];
  const float* bih0  = (const float*)d_in[20];
  const float* bhh0  = (const float*)d_in[21];
  const float* Wih1  = (const float*)d_in[22];
  const float* Whh1  = (const float*)d_in[23];
  const float* bih1  = (const float*)d_in[24];
  const float* bhh1  = (const float*)d_in[25];
  const float* Wout  = (const float*)d_in[26];
  const float* bout  = (const float*)d_in[27];
  (void)in_sizes; (void)n_in; (void)out_size; (void)ws_size;

  float* ws = (float*)d_ws;
  size_t off = 0;
  auto alloc = [&](size_t nf){ float* p = ws + off; off += nf; return p; };
  float* pA     = alloc((size_t)4*64*256);
  float* p1x    = alloc((size_t)64*512);
  float* pP2    = alloc((size_t)2*64*256);
  float* x0     = alloc(64*832);
  float* ctxb   = alloc((size_t)64*1024);
  float* h1     = alloc((size_t)64*1024);
  float* h2b    = alloc((size_t)64*1024);
  float* pO     = alloc((size_t)4*64*192);
  float* paw    = alloc(64*49 + 15);
  int*   lo_w   = (int*)alloc(64);
  int*   wl_w   = (int*)alloc(64);
  float* WencT  = alloc((size_t)256*512);
  float* WdecT  = alloc((size_t)256*2048);
  float* Wpre2T = alloc((size_t)256*512);
  float* WoutT  = alloc((size_t)192*1536);
  float* encw   = alloc((size_t)64*WMAX*512);
  float* pE     = alloc((size_t)2*1216*256);
  unsigned short* pL0 = (unsigned short*)alloc(4*SLOTU);  // 8 bf16 slots: 0-3 Whh0, 4-7 Wih0
  unsigned short* pL1 = (unsigned short*)alloc(4*SLOTU);  // 8 bf16 slots: 0-3 Whh1, 4-7 Wih1
  float* out    = (float*)d_out;

  // K1: front (0-63) | pre1 (64-71) | WencT (72-103) | WdecT (104-167) | Wpre2T (168-199)
  //     | Whh1 (200-455) | WoutT (456-491)
  k_front3<<<492,256,0,stream>>>(prev, lens, enc, indec, spkr,
                                 Wpre1, bpre1, hid, Wenc, Wdec, Wpre2, Whh1, Wout,
                                 lo_w, wl_w, encw, paw, x0, p1x,
                                 WencT, WdecT, Wpre2T, WoutT, pL1);
  // K2: enc MFMA (0-151) | pre2 MFMA (152-159) | Wdec MFMA (160-175) | Whh0 (176-431)
  k_gemmB<<<432,256,0,stream>>>(encw, WencT, pE, p1x, Wpre2T, pP2,
                                hid, WdecT, pA, Whh0, pL0);
  // K3: attention (0-63) | pre2 combine (64-79)
  k_att2<<<80,256,0,stream>>>(pE, pA, benc, convw, Wproj, spkr, Wspkr,
                              paw, wl_w, encw, pP2, bpre2, x0, ctxb);
  // K4: Wih0 * x0 (K=832) -> pL0 slots 4-7
  k_lstmI<<<256,256,0,stream>>>(x0, 832, Wih0, pL0 + 4*SLOTU, 4, 832);
  // K5: combine layer 0 -> h1 (8 bf16 slots)
  k_comb<<<128,256,0,stream>>>(pL0, 8, bih0, bhh0, cell, h1);
  // K6: Wih1 * h1 (K=1024) -> pL1 slots 4-7
  k_lstmI<<<256,256,0,stream>>>(h1, 1024, Wih1, pL1 + 4*SLOTU, 4, 1024);
  // K7: combine layer 1 -> h2b (8 bf16 slots)
  k_comb<<<128,256,0,stream>>>(pL1, 8, bih1, bhh1, cell + 64*1024, h2b);
  // K8: out GEMM via MFMA (12 blocks, KS=4) -> pO [4][64][192]
  k_out_mfma<<<12,256,0,stream>>>(h2b, ctxb, WoutT, pO);
  // K9: output combine (4 slots)
  k_comb_out<<<40,256,0,stream>>>(pO, bout, out);
}